// Round 6
// baseline (346.192 us; speedup 1.0000x reference)
//
#include <hip/hip_runtime.h>
#include <hip/hip_bf16.h>

#define SEQL 4096
#define DCH  1024
#define BATCH 4
#define KH   4097        // stored half-spectrum entries per channel

typedef float2 cf;
__device__ __forceinline__ cf mkc(float x, float y){ return make_float2(x,y); }
__device__ __forceinline__ cf cadd(cf a, cf b){ return mkc(a.x+b.x, a.y+b.y); }
__device__ __forceinline__ cf csub(cf a, cf b){ return mkc(a.x-b.x, a.y-b.y); }
__device__ __forceinline__ cf cmul(cf a, cf b){ return mkc(a.x*b.x - a.y*b.y, a.x*b.y + a.y*b.x); }
__device__ __forceinline__ cf cconjf(cf a){ return mkc(a.x, -a.y); }
__device__ __forceinline__ cf addi(cf a, cf b){ return mkc(a.x - b.y, a.y + b.x); }  // a + i*b
__device__ __forceinline__ cf subi(cf a, cf b){ return mkc(a.x + b.y, a.y - b.x); }  // a - i*b

// LDS swizzle: XOR bits1-3 with bits4-6 (bijective; keeps pairs intact)
__device__ __forceinline__ int phi(int c){ return c ^ (((c>>4)&7)<<1); }
// base-16 digit reversal of 3 digits
__device__ __forceinline__ int drev16(int i){ return ((i&15)<<8) | (i&0xF0) | (i>>8); }

// ---------------- radix-16 butterflies (2 layers of radix-4) ----------------
__device__ __forceinline__ void radix16_fwd(cf* v){
    cf t[16];
#pragma unroll
    for (int a = 0; a < 4; ++a) {
        cf x0 = v[a], x1 = v[a+4], x2 = v[a+8], x3 = v[a+12];
        cf b0 = cadd(x0,x2), b1 = csub(x0,x2);
        cf b2 = cadd(x1,x3), b3 = csub(x1,x3);
        t[a*4+0] = cadd(b0,b2);
        t[a*4+1] = subi(b1,b3);
        t[a*4+2] = csub(b0,b2);
        t[a*4+3] = addi(b1,b3);
    }
    // mid twiddles W16^{r*a}
    t[5]  = cmul(t[5],  mkc( 0.92387953f, -0.38268343f));
    t[6]  = cmul(t[6],  mkc( 0.70710678f, -0.70710678f));
    t[7]  = cmul(t[7],  mkc( 0.38268343f, -0.92387953f));
    t[9]  = cmul(t[9],  mkc( 0.70710678f, -0.70710678f));
    t[10] = mkc(t[10].y, -t[10].x);                      // * -i
    t[11] = cmul(t[11], mkc(-0.70710678f, -0.70710678f));
    t[13] = cmul(t[13], mkc( 0.38268343f, -0.92387953f));
    t[14] = cmul(t[14], mkc(-0.70710678f, -0.70710678f));
    t[15] = cmul(t[15], mkc(-0.92387953f,  0.38268343f));
#pragma unroll
    for (int r = 0; r < 4; ++r) {
        cf x0 = t[r], x1 = t[4+r], x2 = t[8+r], x3 = t[12+r];
        cf b0 = cadd(x0,x2), b1 = csub(x0,x2);
        cf b2 = cadd(x1,x3), b3 = csub(x1,x3);
        v[0+r]  = cadd(b0,b2);
        v[4+r]  = subi(b1,b3);
        v[8+r]  = csub(b0,b2);
        v[12+r] = addi(b1,b3);
    }
}
__device__ __forceinline__ void radix16_inv(cf* v){
    cf t[16];
#pragma unroll
    for (int a = 0; a < 4; ++a) {
        cf x0 = v[a], x1 = v[a+4], x2 = v[a+8], x3 = v[a+12];
        cf b0 = cadd(x0,x2), b1 = csub(x0,x2);
        cf b2 = cadd(x1,x3), b3 = csub(x1,x3);
        t[a*4+0] = cadd(b0,b2);
        t[a*4+1] = addi(b1,b3);
        t[a*4+2] = csub(b0,b2);
        t[a*4+3] = subi(b1,b3);
    }
    t[5]  = cmul(t[5],  mkc( 0.92387953f,  0.38268343f));
    t[6]  = cmul(t[6],  mkc( 0.70710678f,  0.70710678f));
    t[7]  = cmul(t[7],  mkc( 0.38268343f,  0.92387953f));
    t[9]  = cmul(t[9],  mkc( 0.70710678f,  0.70710678f));
    t[10] = mkc(-t[10].y, t[10].x);                      // * +i
    t[11] = cmul(t[11], mkc(-0.70710678f,  0.70710678f));
    t[13] = cmul(t[13], mkc( 0.38268343f,  0.92387953f));
    t[14] = cmul(t[14], mkc(-0.70710678f,  0.70710678f));
    t[15] = cmul(t[15], mkc(-0.92387953f, -0.38268343f));
#pragma unroll
    for (int r = 0; r < 4; ++r) {
        cf x0 = t[r], x1 = t[4+r], x2 = t[8+r], x3 = t[12+r];
        cf b0 = cadd(x0,x2), b1 = csub(x0,x2);
        cf b2 = cadd(x1,x3), b3 = csub(x1,x3);
        v[0+r]  = cadd(b0,b2);
        v[4+r]  = addi(b1,b3);
        v[8+r]  = csub(b0,b2);
        v[12+r] = subi(b1,b3);
    }
}

// ---------------- twiddle tables ----------------
__global__ __launch_bounds__(256) void twiddle_init(cf* __restrict__ tw4, cf* __restrict__ tw8){
    int i = blockIdx.x*256 + threadIdx.x;   // 4096 total
    const double TWO_PI = 6.283185307179586476925286766559;
    double a4 = -TWO_PI * (double)i / 4096.0;
    double a8 = -TWO_PI * (double)i / 8192.0;
    tw4[i] = mkc((float)cos(a4), (float)sin(a4));
    tw8[i] = mkc((float)cos(a8), (float)sin(a8));
}

// ---------------- MLP: h[l][16] ----------------
__global__ __launch_bounds__(256) void mlp_kernel(
        const float* __restrict__ z, const float* __restrict__ w1,
        const float* __restrict__ b1, float* __restrict__ h) {
    int l = blockIdx.x * blockDim.x + threadIdx.x;
    if (l >= SEQL) return;
    float pe0 = z[l * 3 + 0], pe1 = z[l * 3 + 1], pe2 = z[l * 3 + 2];
#pragma unroll
    for (int j = 0; j < 16; ++j) {
        float v = pe0 * w1[j * 3 + 0] + pe1 * w1[j * 3 + 1] + pe2 * w1[j * 3 + 2] + b1[j];
        h[l * 16 + j] = v > 0.f ? v : 0.f;
    }
}

// ---------------- transpose u (B,L,D) -> ut (B,D,L) ----------------
__global__ __launch_bounds__(256) void transpose_kernel(
        const float* __restrict__ u, float* __restrict__ ut) {
    __shared__ float tile[32][33];
    int b = blockIdx.z;
    int l0 = blockIdx.x * 32;
    int d0 = blockIdx.y * 32;
    int tx = threadIdx.x, ty = threadIdx.y;  // 32 x 8
    const float* up = u + (size_t)b * SEQL * DCH;
#pragma unroll
    for (int i = 0; i < 32; i += 8)
        tile[ty + i][tx] = up[(size_t)(l0 + ty + i) * DCH + d0 + tx];
    __syncthreads();
    float* utp = ut + (size_t)b * DCH * SEQL;
#pragma unroll
    for (int i = 0; i < 32; i += 8)
        utp[(size_t)(d0 + ty + i) * SEQL + l0 + tx] = tile[tx][ty + i];
}

// ---------------- filter row -> packed FFT -> H[d][0..4096] (scaled 1/8192) ----------------
__global__ __launch_bounds__(256, 4) void filt_fft_kernel(
        const float* __restrict__ h, const float* __restrict__ w2,
        const float* __restrict__ b2, const cf* __restrict__ tw4,
        const cf* __restrict__ tw8, cf* __restrict__ kf) {
    __shared__ cf lds[4096];
    const int d = blockIdx.x;
    const int tid = threadIdx.x;
    float wv[16];
#pragma unroll
    for (int j = 0; j < 16; ++j) wv[j] = w2[d * 16 + j];
    const float bb = b2[d];
    cf v[16];
    // P1 (m=256): compute filter values for c = tid + 256j (j<8), zeros above
#pragma unroll
    for (int j = 0; j < 8; ++j) {
        int n = 2 * (tid + 256 * j);
        const float* h0 = h + (size_t)n * 16;
        float f0 = bb, f1 = bb;
#pragma unroll
        for (int i = 0; i < 16; ++i) { f0 += h0[i] * wv[i]; f1 += h0[16 + i] * wv[i]; }
        v[j] = mkc(f0, f1);
    }
#pragma unroll
    for (int j = 8; j < 16; ++j) v[j] = mkc(0.f, 0.f);
    radix16_fwd(v);
    {
        const int b0 = tid ^ (((tid >> 4) & 7) << 1);
#pragma unroll
        for (int j = 1; j < 16; ++j) v[j] = cmul(v[j], tw4[tid * j]);
#pragma unroll
        for (int j = 0; j < 16; ++j) lds[b0 + 256 * j] = v[j];
    }
    __syncthreads();
    // P2 (m=16)
    {
        const int base = ((tid >> 4) << 8) | (tid & 15);
        const int k = tid & 15;
#pragma unroll
        for (int j = 0; j < 16; ++j) v[j] = lds[(base + 16 * j) ^ ((j & 7) << 1)];
        radix16_fwd(v);
#pragma unroll
        for (int j = 1; j < 16; ++j) v[j] = cmul(v[j], tw4[16 * k * j]);
#pragma unroll
        for (int j = 0; j < 16; ++j) lds[(base + 16 * j) ^ ((j & 7) << 1)] = v[j];
    }
    __syncthreads();
    // P3 (m=1)
    {
        const int b0 = tid << 4;
        const int xr = (tid & 7) << 1;
#pragma unroll
        for (int j = 0; j < 16; ++j) v[j] = lds[b0 + (j ^ xr)];
        radix16_fwd(v);
#pragma unroll
        for (int j = 0; j < 16; ++j) lds[b0 + (j ^ xr)] = v[j];
    }
    __syncthreads();
    // unpack to real spectrum H[0..4096], scaled
    const float s = 1.f / 8192.f;
    cf* Hrow = kf + (size_t)d * KH;
    const int l = tid & 63, w = tid >> 6;
#pragma unroll
    for (int it = 0; it < 8; ++it) {
        int k = ((l & 7) << 8) + ((l >> 3) << 5) + (it << 2) + w;
        if (k == 0) {
            cf c0 = lds[0];
            Hrow[0]    = mkc((c0.x + c0.y) * s, 0.f);
            Hrow[4096] = mkc((c0.x - c0.y) * s, 0.f);
            cf c2 = lds[8];                               // phi(drev16(2048)) = 8
            Hrow[2048] = mkc(c2.x * s, -c2.y * s);
        } else {
            int kk = 4096 - k;
            cf ck  = lds[phi(drev16(k))];
            cf ckk = lds[phi(drev16(kk))];
            cf cc = cconjf(ckk);
            cf E  = mkc(0.5f*(ck.x+cc.x), 0.5f*(ck.y+cc.y));
            cf Dd = csub(ck, cc);
            cf O  = mkc(0.5f*Dd.y, -0.5f*Dd.x);
            cf wvv = tw8[k];
            cf Xk  = cadd(E, cmul(wvv, O));
            cf wp  = mkc(-wvv.x, wvv.y);
            cf Xkk = cadd(cconjf(E), cmul(wp, cconjf(O)));
            Hrow[k]  = mkc(Xk.x * s, Xk.y * s);
            Hrow[kk] = mkc(Xkk.x * s, Xkk.y * s);
        }
    }
}

// ---------------- conv: packed fwd FFT -> spectral multiply -> packed inv FFT ----------------
__global__ __launch_bounds__(256, 4) void conv_kernel(
        float* __restrict__ uty, const cf* __restrict__ tw4,
        const cf* __restrict__ tw8, const cf* __restrict__ kf) {
    __shared__ cf lds[4096];
    const int row = blockIdx.x;            // b*DCH + d
    const int d = row & (DCH - 1);
    const int tid = threadIdx.x;
    float* rp = uty + (size_t)row * SEQL;
    cf v[16];
    // P1 (m=256): fused global load, zeros in upper half
#pragma unroll
    for (int j = 0; j < 8; ++j) v[j] = *(const cf*)&rp[2 * (tid + 256 * j)];
#pragma unroll
    for (int j = 8; j < 16; ++j) v[j] = mkc(0.f, 0.f);
    radix16_fwd(v);
    {
        const int b0 = tid ^ (((tid >> 4) & 7) << 1);
#pragma unroll
        for (int j = 1; j < 16; ++j) v[j] = cmul(v[j], tw4[tid * j]);
#pragma unroll
        for (int j = 0; j < 16; ++j) lds[b0 + 256 * j] = v[j];
    }
    __syncthreads();
    // P2 (m=16)
    {
        const int base = ((tid >> 4) << 8) | (tid & 15);
        const int k = tid & 15;
#pragma unroll
        for (int j = 0; j < 16; ++j) v[j] = lds[(base + 16 * j) ^ ((j & 7) << 1)];
        radix16_fwd(v);
#pragma unroll
        for (int j = 1; j < 16; ++j) v[j] = cmul(v[j], tw4[16 * k * j]);
#pragma unroll
        for (int j = 0; j < 16; ++j) lds[(base + 16 * j) ^ ((j & 7) << 1)] = v[j];
    }
    __syncthreads();
    // P3 (m=1)
    {
        const int b0 = tid << 4;
        const int xr = (tid & 7) << 1;
#pragma unroll
        for (int j = 0; j < 16; ++j) v[j] = lds[b0 + (j ^ xr)];
        radix16_fwd(v);
#pragma unroll
        for (int j = 0; j < 16; ++j) lds[b0 + (j ^ xr)] = v[j];
    }
    __syncthreads();
    // spectral multiply (packed-real unpack * H * repack)
    const cf* Hrow = kf + (size_t)d * KH;
    {
        const int l = tid & 63, w = tid >> 6;
#pragma unroll
        for (int it = 0; it < 8; ++it) {
            int k = ((l & 7) << 8) + ((l >> 3) << 5) + (it << 2) + w;
            if (k == 0) {
                cf c0 = lds[0];
                float X0 = c0.x + c0.y, X4 = c0.x - c0.y;
                cf H0 = Hrow[0], H4 = Hrow[4096];
                cf Y0 = mkc(X0 * H0.x, X0 * H0.y);
                cf Y4 = mkc(X4 * H4.x, X4 * H4.y);
                cf S  = cadd(Y0, Y4), Dd = csub(Y0, Y4);
                lds[0] = addi(S, Dd);
                cf c2 = lds[8];                           // phi(drev16(2048)) = 8
                cf Y2 = cmul(cconjf(c2), Hrow[2048]);
                lds[8] = mkc(2.f * Y2.x, -2.f * Y2.y);
            } else {
                int kk = 4096 - k;
                int sk = phi(drev16(k)), skk = phi(drev16(kk));
                cf ck = lds[sk], ckk = lds[skk];
                cf cc = cconjf(ckk);
                cf E  = mkc(0.5f*(ck.x+cc.x), 0.5f*(ck.y+cc.y));
                cf Dd = csub(ck, cc);
                cf O  = mkc(0.5f*Dd.y, -0.5f*Dd.x);
                cf wv = tw8[k];
                cf Xk  = cadd(E, cmul(wv, O));
                cf wp  = mkc(-wv.x, wv.y);
                cf Xkk = cadd(cconjf(E), cmul(wp, cconjf(O)));
                cf Yk  = cmul(Xk,  Hrow[k]);
                cf Ykk = cmul(Xkk, Hrow[kk]);
                cf cy = cconjf(Ykk);
                cf S  = cadd(Yk, cy), D2 = csub(Yk, cy);
                cf Zk = addi(S, cmul(cconjf(wv), D2));
                cf cy2 = cconjf(Yk);
                cf S2  = cadd(Ykk, cy2), D3 = csub(Ykk, cy2);
                cf Zkk = subi(S2, cmul(wv, D3));
                lds[sk] = Zk; lds[skk] = Zkk;
            }
        }
    }
    __syncthreads();
    // A (inverse m=1)
    {
        const int b0 = tid << 4;
        const int xr = (tid & 7) << 1;
#pragma unroll
        for (int j = 0; j < 16; ++j) v[j] = lds[b0 + (j ^ xr)];
        radix16_inv(v);
#pragma unroll
        for (int j = 0; j < 16; ++j) lds[b0 + (j ^ xr)] = v[j];
    }
    __syncthreads();
    // B (inverse m=16), conj twiddles on inputs
    {
        const int base = ((tid >> 4) << 8) | (tid & 15);
        const int k = tid & 15;
#pragma unroll
        for (int j = 0; j < 16; ++j) v[j] = lds[(base + 16 * j) ^ ((j & 7) << 1)];
#pragma unroll
        for (int j = 1; j < 16; ++j) v[j] = cmul(v[j], cconjf(tw4[16 * k * j]));
        radix16_inv(v);
#pragma unroll
        for (int j = 0; j < 16; ++j) lds[(base + 16 * j) ^ ((j & 7) << 1)] = v[j];
    }
    __syncthreads();
    // C (inverse m=256), conj twiddles on inputs, fused global store (first half only)
    {
        const int b0 = tid ^ (((tid >> 4) & 7) << 1);
#pragma unroll
        for (int j = 0; j < 16; ++j) v[j] = lds[b0 + 256 * j];
#pragma unroll
        for (int j = 1; j < 16; ++j) v[j] = cmul(v[j], cconjf(tw4[tid * j]));
        radix16_inv(v);
#pragma unroll
        for (int j = 0; j < 8; ++j) *(cf*)&rp[2 * (tid + 256 * j)] = v[j];
    }
}

// ---------------- bf16 MFMA GEMM: out = y^T * (u @ pw^T + pb) + u ----------------
__device__ __forceinline__ unsigned pack2bf(float a, float b){
    unsigned r;
    asm("v_cvt_pk_bf16_f32 %0, %1, %2" : "=v"(r) : "v"(a), "v"(b));
    return r;   // lo = bf16(a), hi = bf16(b)
}

typedef __attribute__((ext_vector_type(8))) short short8;
typedef __attribute__((ext_vector_type(4))) float f32x4;

__global__ __launch_bounds__(256, 3) void gemm_mfma_kernel(
        const float* __restrict__ u, const float* __restrict__ pw,
        const float* __restrict__ pb, const float* __restrict__ y,
        float* __restrict__ out) {
    __shared__ char lds_raw[34816];
    float (*ysc)[132] = (float(*)[132])lds_raw;

    const int tid  = threadIdx.x;
    const int lane = tid & 63;
    const int wid  = tid >> 6;
    const int wr   = wid >> 1;
    const int wc   = wid & 1;
    const int m0   = blockIdx.x * 128;  // m-major grid: same-m blocks share an XCD
    const int n0   = blockIdx.y * 128;

    f32x4 acc[4][4] = {};
    float4 ra[4], rb[4];

    int s_row[4], s_f4[4];
#pragma unroll
    for (int j = 0; j < 4; ++j) {
        int idx = j * 256 + tid;
        s_row[j] = idx >> 3;
        s_f4[j]  = idx & 7;
    }

#define LOADT(kt)                                                                     \
    {                                                                                 \
        _Pragma("unroll")                                                             \
        for (int j = 0; j < 4; ++j) {                                                 \
            ra[j] = *(const float4*)&u [(size_t)(m0 + s_row[j]) * DCH + (kt) + s_f4[j] * 4]; \
            rb[j] = *(const float4*)&pw[(size_t)(n0 + s_row[j]) * DCH + (kt) + s_f4[j] * 4]; \
        }                                                                             \
    }
#define WRITET(base)                                                                  \
    {                                                                                 \
        _Pragma("unroll")                                                             \
        for (int j = 0; j < 4; ++j) {                                                 \
            int off = (base) + ((s_row[j] * 64 + s_f4[j] * 8) ^ ((s_row[j] & 3) << 4)); \
            uint2 pa, pbv2;                                                           \
            pa.x   = pack2bf(ra[j].x, ra[j].y);  pa.y   = pack2bf(ra[j].z, ra[j].w);  \
            pbv2.x = pack2bf(rb[j].x, rb[j].y);  pbv2.y = pack2bf(rb[j].z, rb[j].w);  \
            *(uint2*)(lds_raw + off)        = pa;                                     \
            *(uint2*)(lds_raw + off + 8192) = pbv2;                                   \
        }                                                                             \
    }

    LOADT(0);
    WRITET(0);
    LOADT(32);
    __syncthreads();

    for (int t = 0; t < 32; ++t) {
        const int cur = (t & 1) << 14;
        short8 af[4], bf[4];
#pragma unroll
        for (int f = 0; f < 4; ++f) {
            int rowA = wr * 64 + f * 16 + (lane & 15);
            int rowB = wc * 64 + f * 16 + (lane & 15);
            int offA = cur + ((rowA * 64 + ((lane >> 4) * 16)) ^ ((rowA & 3) << 4));
            int offB = cur + 8192 + ((rowB * 64 + ((lane >> 4) * 16)) ^ ((rowB & 3) << 4));
            af[f] = *(short8*)(lds_raw + offA);
            bf[f] = *(short8*)(lds_raw + offB);
        }
        if (t < 31) WRITET(cur ^ 16384);
        if (t < 30) LOADT((t + 2) * 32);
#pragma unroll
        for (int mf = 0; mf < 4; ++mf)
#pragma unroll
            for (int nf = 0; nf < 4; ++nf)
                acc[mf][nf] = __builtin_amdgcn_mfma_f32_16x16x32_bf16(
                    af[mf], bf[nf], acc[mf][nf], 0, 0, 0);
        __syncthreads();
    }

    const int b  = m0 >> 12;
    const int l0 = m0 & (SEQL - 1);
    float pbv[4];
#pragma unroll
    for (int nf = 0; nf < 4; ++nf)
        pbv[nf] = pb[n0 + wc * 64 + nf * 16 + (lane & 15)];

    for (int c = 0; c < 2; ++c) {
        __syncthreads();
#pragma unroll
        for (int j = 0; j < 8; ++j) {
            int idx = j * 256 + tid;
            int dn  = idx >> 4;
            int lf4 = idx & 15;
            float4 vy = *(const float4*)&y[(((size_t)(b * DCH + n0 + dn)) << 12) + l0 + c * 64 + lf4 * 4];
            ysc[lf4 * 4 + 0][dn] = vy.x;
            ysc[lf4 * 4 + 1][dn] = vy.y;
            ysc[lf4 * 4 + 2][dn] = vy.z;
            ysc[lf4 * 4 + 3][dn] = vy.w;
        }
        __syncthreads();
        if (wr == c) {
#pragma unroll
            for (int mf = 0; mf < 4; ++mf)
#pragma unroll
                for (int i = 0; i < 4; ++i) {
                    int lrow = mf * 16 + (lane >> 4) * 4 + i;
                    int m = m0 + c * 64 + lrow;
#pragma unroll
                    for (int nf = 0; nf < 4; ++nf) {
                        int nl = wc * 64 + nf * 16 + (lane & 15);
                        int n = n0 + nl;
                        float proj = acc[mf][nf][i] + pbv[nf];
                        out[(size_t)m * DCH + n] = ysc[lrow][nl] * proj + u[(size_t)m * DCH + n];
                    }
                }
        }
    }
#undef LOADT
#undef WRITET
}

extern "C" void kernel_launch(void* const* d_in, const int* in_sizes, int n_in,
                              void* d_out, int out_size, void* d_ws, size_t ws_size,
                              hipStream_t stream) {
    const float* u  = (const float*)d_in[0];
    const float* z  = (const float*)d_in[1];
    const float* w1 = (const float*)d_in[2];
    const float* b1 = (const float*)d_in[3];
    const float* w2 = (const float*)d_in[4];
    const float* b2 = (const float*)d_in[5];
    const float* pw = (const float*)d_in[6];
    const float* pb = (const float*)d_in[7];
    float* out = (float*)d_out;

    float* h   = (float*)d_ws;                           // 256 KB
    float* uty = (float*)((char*)d_ws + 262144);         // 64 MB
    // scratch inside d_out (fully overwritten by gemm at the end):
    cf* kf  = (cf*)d_out;                                // 1024*4097*8B = 33.5 MB
    cf* tw4 = (cf*)((char*)d_out + (40u << 20));         // 32 KB
    cf* tw8 = tw4 + 4096;                                // 32 KB

    twiddle_init<<<dim3(16), dim3(256), 0, stream>>>(tw4, tw8);
    mlp_kernel<<<dim3(16), dim3(256), 0, stream>>>(z, w1, b1, h);
    transpose_kernel<<<dim3(SEQL / 32, DCH / 32, BATCH), dim3(32, 8), 0, stream>>>(u, uty);
    filt_fft_kernel<<<dim3(DCH), dim3(256), 0, stream>>>(h, w2, b2, tw4, tw8, kf);
    conv_kernel<<<dim3(BATCH * DCH), dim3(256), 0, stream>>>(uty, tw4, tw8, kf);
    gemm_mfma_kernel<<<dim3(128, 8), dim3(256), 0, stream>>>(u, pw, pb, uty, out);
}

// Round 7
// 322.981 us; speedup vs baseline: 1.0719x; 1.0719x over previous
//
#include <hip/hip_runtime.h>
#include <hip/hip_bf16.h>

#define SEQL 4096
#define DCH  1024
#define BATCH 4
#define KH   4097        // stored half-spectrum entries per channel

typedef float2 cf;
__device__ __forceinline__ cf mkc(float x, float y){ return make_float2(x,y); }
__device__ __forceinline__ cf cadd(cf a, cf b){ return mkc(a.x+b.x, a.y+b.y); }
__device__ __forceinline__ cf csub(cf a, cf b){ return mkc(a.x-b.x, a.y-b.y); }
__device__ __forceinline__ cf cmul(cf a, cf b){ return mkc(a.x*b.x - a.y*b.y, a.x*b.y + a.y*b.x); }
__device__ __forceinline__ cf cconjf(cf a){ return mkc(a.x, -a.y); }
__device__ __forceinline__ cf addi(cf a, cf b){ return mkc(a.x - b.y, a.y + b.x); }  // a + i*b
__device__ __forceinline__ cf subi(cf a, cf b){ return mkc(a.x + b.y, a.y - b.x); }  // a - i*b

// LDS swizzle: XOR bits1-3 with bits4-6 (bijective; keeps pairs intact)
__device__ __forceinline__ int phi(int c){ return c ^ (((c>>4)&7)<<1); }
// base-16 digit reversal of 3 digits
__device__ __forceinline__ int drev16(int i){ return ((i&15)<<8) | (i&0xF0) | (i>>8); }

// ---------------- radix-16 butterflies (2 layers of radix-4) ----------------
__device__ __forceinline__ void radix16_fwd(cf* v){
    cf t[16];
#pragma unroll
    for (int a = 0; a < 4; ++a) {
        cf x0 = v[a], x1 = v[a+4], x2 = v[a+8], x3 = v[a+12];
        cf b0 = cadd(x0,x2), b1 = csub(x0,x2);
        cf b2 = cadd(x1,x3), b3 = csub(x1,x3);
        t[a*4+0] = cadd(b0,b2);
        t[a*4+1] = subi(b1,b3);
        t[a*4+2] = csub(b0,b2);
        t[a*4+3] = addi(b1,b3);
    }
    // mid twiddles W16^{r*a}
    t[5]  = cmul(t[5],  mkc( 0.92387953f, -0.38268343f));
    t[6]  = cmul(t[6],  mkc( 0.70710678f, -0.70710678f));
    t[7]  = cmul(t[7],  mkc( 0.38268343f, -0.92387953f));
    t[9]  = cmul(t[9],  mkc( 0.70710678f, -0.70710678f));
    t[10] = mkc(t[10].y, -t[10].x);                      // * -i
    t[11] = cmul(t[11], mkc(-0.70710678f, -0.70710678f));
    t[13] = cmul(t[13], mkc( 0.38268343f, -0.92387953f));
    t[14] = cmul(t[14], mkc(-0.70710678f, -0.70710678f));
    t[15] = cmul(t[15], mkc(-0.92387953f,  0.38268343f));
#pragma unroll
    for (int r = 0; r < 4; ++r) {
        cf x0 = t[r], x1 = t[4+r], x2 = t[8+r], x3 = t[12+r];
        cf b0 = cadd(x0,x2), b1 = csub(x0,x2);
        cf b2 = cadd(x1,x3), b3 = csub(x1,x3);
        v[0+r]  = cadd(b0,b2);
        v[4+r]  = subi(b1,b3);
        v[8+r]  = csub(b0,b2);
        v[12+r] = addi(b1,b3);
    }
}
__device__ __forceinline__ void radix16_inv(cf* v){
    cf t[16];
#pragma unroll
    for (int a = 0; a < 4; ++a) {
        cf x0 = v[a], x1 = v[a+4], x2 = v[a+8], x3 = v[a+12];
        cf b0 = cadd(x0,x2), b1 = csub(x0,x2);
        cf b2 = cadd(x1,x3), b3 = csub(x1,x3);
        t[a*4+0] = cadd(b0,b2);
        t[a*4+1] = addi(b1,b3);
        t[a*4+2] = csub(b0,b2);
        t[a*4+3] = subi(b1,b3);
    }
    t[5]  = cmul(t[5],  mkc( 0.92387953f,  0.38268343f));
    t[6]  = cmul(t[6],  mkc( 0.70710678f,  0.70710678f));
    t[7]  = cmul(t[7],  mkc( 0.38268343f,  0.92387953f));
    t[9]  = cmul(t[9],  mkc( 0.70710678f,  0.70710678f));
    t[10] = mkc(-t[10].y, t[10].x);                      // * +i
    t[11] = cmul(t[11], mkc(-0.70710678f,  0.70710678f));
    t[13] = cmul(t[13], mkc( 0.38268343f,  0.92387953f));
    t[14] = cmul(t[14], mkc(-0.70710678f,  0.70710678f));
    t[15] = cmul(t[15], mkc(-0.92387953f, -0.38268343f));
#pragma unroll
    for (int r = 0; r < 4; ++r) {
        cf x0 = t[r], x1 = t[4+r], x2 = t[8+r], x3 = t[12+r];
        cf b0 = cadd(x0,x2), b1 = csub(x0,x2);
        cf b2 = cadd(x1,x3), b3 = csub(x1,x3);
        v[0+r]  = cadd(b0,b2);
        v[4+r]  = addi(b1,b3);
        v[8+r]  = csub(b0,b2);
        v[12+r] = subi(b1,b3);
    }
}

// ---------------- twiddle tables ----------------
__global__ __launch_bounds__(256) void twiddle_init(cf* __restrict__ tw4, cf* __restrict__ tw8){
    int i = blockIdx.x*256 + threadIdx.x;   // 4096 total
    const double TWO_PI = 6.283185307179586476925286766559;
    double a4 = -TWO_PI * (double)i / 4096.0;
    double a8 = -TWO_PI * (double)i / 8192.0;
    tw4[i] = mkc((float)cos(a4), (float)sin(a4));
    tw8[i] = mkc((float)cos(a8), (float)sin(a8));
}

// ---------------- MLP: h[l][16] ----------------
__global__ __launch_bounds__(256) void mlp_kernel(
        const float* __restrict__ z, const float* __restrict__ w1,
        const float* __restrict__ b1, float* __restrict__ h) {
    int l = blockIdx.x * blockDim.x + threadIdx.x;
    if (l >= SEQL) return;
    float pe0 = z[l * 3 + 0], pe1 = z[l * 3 + 1], pe2 = z[l * 3 + 2];
#pragma unroll
    for (int j = 0; j < 16; ++j) {
        float v = pe0 * w1[j * 3 + 0] + pe1 * w1[j * 3 + 1] + pe2 * w1[j * 3 + 2] + b1[j];
        h[l * 16 + j] = v > 0.f ? v : 0.f;
    }
}

// ---------------- transpose u (B,L,D) -> ut (B,D,L) ----------------
__global__ __launch_bounds__(256) void transpose_kernel(
        const float* __restrict__ u, float* __restrict__ ut) {
    __shared__ float tile[32][33];
    int b = blockIdx.z;
    int l0 = blockIdx.x * 32;
    int d0 = blockIdx.y * 32;
    int tx = threadIdx.x, ty = threadIdx.y;  // 32 x 8
    const float* up = u + (size_t)b * SEQL * DCH;
#pragma unroll
    for (int i = 0; i < 32; i += 8)
        tile[ty + i][tx] = up[(size_t)(l0 + ty + i) * DCH + d0 + tx];
    __syncthreads();
    float* utp = ut + (size_t)b * DCH * SEQL;
#pragma unroll
    for (int i = 0; i < 32; i += 8)
        utp[(size_t)(d0 + ty + i) * SEQL + l0 + tx] = tile[tx][ty + i];
}

// ---------------- filter row -> packed FFT -> H[d][0..4096] (scaled 1/8192) ----------------
__global__ __launch_bounds__(256, 2) void filt_fft_kernel(
        const float* __restrict__ h, const float* __restrict__ w2,
        const float* __restrict__ b2, const cf* __restrict__ tw4,
        const cf* __restrict__ tw8, cf* __restrict__ kf) {
    __shared__ cf lds[4096];
    const int d = blockIdx.x;
    const int tid = threadIdx.x;
    float wv[16];
#pragma unroll
    for (int j = 0; j < 16; ++j) wv[j] = w2[d * 16 + j];
    const float bb = b2[d];
    cf v[16];
    // P1 (m=256): compute filter values for c = tid + 256j (j<8), zeros above
#pragma unroll
    for (int j = 0; j < 8; ++j) {
        int n = 2 * (tid + 256 * j);
        const float* h0 = h + (size_t)n * 16;
        float f0 = bb, f1 = bb;
#pragma unroll
        for (int i = 0; i < 16; ++i) { f0 += h0[i] * wv[i]; f1 += h0[16 + i] * wv[i]; }
        v[j] = mkc(f0, f1);
    }
#pragma unroll
    for (int j = 8; j < 16; ++j) v[j] = mkc(0.f, 0.f);
    radix16_fwd(v);
    {
        const int b0 = tid ^ (((tid >> 4) & 7) << 1);
#pragma unroll
        for (int j = 1; j < 16; ++j) v[j] = cmul(v[j], tw4[tid * j]);
#pragma unroll
        for (int j = 0; j < 16; ++j) lds[b0 + 256 * j] = v[j];
    }
    __syncthreads();
    // P2 (m=16)
    {
        const int base = ((tid >> 4) << 8) | (tid & 15);
        const int k = tid & 15;
#pragma unroll
        for (int j = 0; j < 16; ++j) v[j] = lds[(base + 16 * j) ^ ((j & 7) << 1)];
        radix16_fwd(v);
#pragma unroll
        for (int j = 1; j < 16; ++j) v[j] = cmul(v[j], tw4[16 * k * j]);
#pragma unroll
        for (int j = 0; j < 16; ++j) lds[(base + 16 * j) ^ ((j & 7) << 1)] = v[j];
    }
    __syncthreads();
    // P3 (m=1)
    {
        const int b0 = tid << 4;
        const int xr = (tid & 7) << 1;
#pragma unroll
        for (int j = 0; j < 16; ++j) v[j] = lds[b0 + (j ^ xr)];
        radix16_fwd(v);
#pragma unroll
        for (int j = 0; j < 16; ++j) lds[b0 + (j ^ xr)] = v[j];
    }
    __syncthreads();
    // unpack to real spectrum H[0..4096], scaled
    const float s = 1.f / 8192.f;
    cf* Hrow = kf + (size_t)d * KH;
    const int l = tid & 63, w = tid >> 6;
#pragma unroll
    for (int it = 0; it < 8; ++it) {
        int k = ((l & 7) << 8) + ((l >> 3) << 5) + (it << 2) + w;
        if (k == 0) {
            cf c0 = lds[0];
            Hrow[0]    = mkc((c0.x + c0.y) * s, 0.f);
            Hrow[4096] = mkc((c0.x - c0.y) * s, 0.f);
            cf c2 = lds[8];                               // phi(drev16(2048)) = 8
            Hrow[2048] = mkc(c2.x * s, -c2.y * s);
        } else {
            int kk = 4096 - k;
            cf ck  = lds[phi(drev16(k))];
            cf ckk = lds[phi(drev16(kk))];
            cf cc = cconjf(ckk);
            cf E  = mkc(0.5f*(ck.x+cc.x), 0.5f*(ck.y+cc.y));
            cf Dd = csub(ck, cc);
            cf O  = mkc(0.5f*Dd.y, -0.5f*Dd.x);
            cf wvv = tw8[k];
            cf Xk  = cadd(E, cmul(wvv, O));
            cf wp  = mkc(-wvv.x, wvv.y);
            cf Xkk = cadd(cconjf(E), cmul(wp, cconjf(O)));
            Hrow[k]  = mkc(Xk.x * s, Xk.y * s);
            Hrow[kk] = mkc(Xkk.x * s, Xkk.y * s);
        }
    }
}

// ---------------- conv: packed fwd FFT -> spectral multiply -> packed inv FFT ----------------
__global__ __launch_bounds__(256, 2) void conv_kernel(
        float* __restrict__ uty, const cf* __restrict__ tw4,
        const cf* __restrict__ tw8, const cf* __restrict__ kf) {
    __shared__ cf lds[4096];
    const int row = blockIdx.x;            // b*DCH + d
    const int d = row & (DCH - 1);
    const int tid = threadIdx.x;
    float* rp = uty + (size_t)row * SEQL;
    cf v[16];
    // P1 (m=256): fused global load, zeros in upper half
#pragma unroll
    for (int j = 0; j < 8; ++j) v[j] = *(const cf*)&rp[2 * (tid + 256 * j)];
#pragma unroll
    for (int j = 8; j < 16; ++j) v[j] = mkc(0.f, 0.f);
    radix16_fwd(v);
    {
        const int b0 = tid ^ (((tid >> 4) & 7) << 1);
#pragma unroll
        for (int j = 1; j < 16; ++j) v[j] = cmul(v[j], tw4[tid * j]);
#pragma unroll
        for (int j = 0; j < 16; ++j) lds[b0 + 256 * j] = v[j];
    }
    __syncthreads();
    // P2 (m=16)
    {
        const int base = ((tid >> 4) << 8) | (tid & 15);
        const int k = tid & 15;
#pragma unroll
        for (int j = 0; j < 16; ++j) v[j] = lds[(base + 16 * j) ^ ((j & 7) << 1)];
        radix16_fwd(v);
#pragma unroll
        for (int j = 1; j < 16; ++j) v[j] = cmul(v[j], tw4[16 * k * j]);
#pragma unroll
        for (int j = 0; j < 16; ++j) lds[(base + 16 * j) ^ ((j & 7) << 1)] = v[j];
    }
    __syncthreads();
    // P3 (m=1)
    {
        const int b0 = tid << 4;
        const int xr = (tid & 7) << 1;
#pragma unroll
        for (int j = 0; j < 16; ++j) v[j] = lds[b0 + (j ^ xr)];
        radix16_fwd(v);
#pragma unroll
        for (int j = 0; j < 16; ++j) lds[b0 + (j ^ xr)] = v[j];
    }
    __syncthreads();
    // spectral multiply (packed-real unpack * H * repack)
    const cf* Hrow = kf + (size_t)d * KH;
    {
        const int l = tid & 63, w = tid >> 6;
#pragma unroll
        for (int it = 0; it < 8; ++it) {
            int k = ((l & 7) << 8) + ((l >> 3) << 5) + (it << 2) + w;
            if (k == 0) {
                cf c0 = lds[0];
                float X0 = c0.x + c0.y, X4 = c0.x - c0.y;
                cf H0 = Hrow[0], H4 = Hrow[4096];
                cf Y0 = mkc(X0 * H0.x, X0 * H0.y);
                cf Y4 = mkc(X4 * H4.x, X4 * H4.y);
                cf S  = cadd(Y0, Y4), Dd = csub(Y0, Y4);
                lds[0] = addi(S, Dd);
                cf c2 = lds[8];                           // phi(drev16(2048)) = 8
                cf Y2 = cmul(cconjf(c2), Hrow[2048]);
                lds[8] = mkc(2.f * Y2.x, -2.f * Y2.y);
            } else {
                int kk = 4096 - k;
                int sk = phi(drev16(k)), skk = phi(drev16(kk));
                cf ck = lds[sk], ckk = lds[skk];
                cf cc = cconjf(ckk);
                cf E  = mkc(0.5f*(ck.x+cc.x), 0.5f*(ck.y+cc.y));
                cf Dd = csub(ck, cc);
                cf O  = mkc(0.5f*Dd.y, -0.5f*Dd.x);
                cf wv = tw8[k];
                cf Xk  = cadd(E, cmul(wv, O));
                cf wp  = mkc(-wv.x, wv.y);
                cf Xkk = cadd(cconjf(E), cmul(wp, cconjf(O)));
                cf Yk  = cmul(Xk,  Hrow[k]);
                cf Ykk = cmul(Xkk, Hrow[kk]);
                cf cy = cconjf(Ykk);
                cf S  = cadd(Yk, cy), D2 = csub(Yk, cy);
                cf Zk = addi(S, cmul(cconjf(wv), D2));
                cf cy2 = cconjf(Yk);
                cf S2  = cadd(Ykk, cy2), D3 = csub(Ykk, cy2);
                cf Zkk = subi(S2, cmul(wv, D3));
                lds[sk] = Zk; lds[skk] = Zkk;
            }
        }
    }
    __syncthreads();
    // A (inverse m=1)
    {
        const int b0 = tid << 4;
        const int xr = (tid & 7) << 1;
#pragma unroll
        for (int j = 0; j < 16; ++j) v[j] = lds[b0 + (j ^ xr)];
        radix16_inv(v);
#pragma unroll
        for (int j = 0; j < 16; ++j) lds[b0 + (j ^ xr)] = v[j];
    }
    __syncthreads();
    // B (inverse m=16), conj twiddles on inputs
    {
        const int base = ((tid >> 4) << 8) | (tid & 15);
        const int k = tid & 15;
#pragma unroll
        for (int j = 0; j < 16; ++j) v[j] = lds[(base + 16 * j) ^ ((j & 7) << 1)];
#pragma unroll
        for (int j = 1; j < 16; ++j) v[j] = cmul(v[j], cconjf(tw4[16 * k * j]));
        radix16_inv(v);
#pragma unroll
        for (int j = 0; j < 16; ++j) lds[(base + 16 * j) ^ ((j & 7) << 1)] = v[j];
    }
    __syncthreads();
    // C (inverse m=256), conj twiddles on inputs, fused global store (first half only)
    {
        const int b0 = tid ^ (((tid >> 4) & 7) << 1);
#pragma unroll
        for (int j = 0; j < 16; ++j) v[j] = lds[b0 + 256 * j];
#pragma unroll
        for (int j = 1; j < 16; ++j) v[j] = cmul(v[j], cconjf(tw4[tid * j]));
        radix16_inv(v);
#pragma unroll
        for (int j = 0; j < 8; ++j) *(cf*)&rp[2 * (tid + 256 * j)] = v[j];
    }
}

// ---------------- bf16 MFMA GEMM: out = y^T * (u @ pw^T + pb) + u ----------------
__device__ __forceinline__ unsigned pack2bf(float a, float b){
    unsigned r;
    asm("v_cvt_pk_bf16_f32 %0, %1, %2" : "=v"(r) : "v"(a), "v"(b));
    return r;   // lo = bf16(a), hi = bf16(b)
}

typedef __attribute__((ext_vector_type(8))) short short8;
typedef __attribute__((ext_vector_type(4))) float f32x4;

__global__ __launch_bounds__(256, 3) void gemm_mfma_kernel(
        const float* __restrict__ u, const float* __restrict__ pw,
        const float* __restrict__ pb, const float* __restrict__ y,
        float* __restrict__ out) {
    __shared__ char lds_raw[34816];
    float (*ysc)[132] = (float(*)[132])lds_raw;

    const int tid  = threadIdx.x;
    const int lane = tid & 63;
    const int wid  = tid >> 6;
    const int wr   = wid >> 1;
    const int wc   = wid & 1;
    const int m0   = blockIdx.x * 128;  // m-major grid: same-m blocks share an XCD
    const int n0   = blockIdx.y * 128;

    f32x4 acc[4][4] = {};
    float4 ra[4], rb[4];

    int s_row[4], s_f4[4];
#pragma unroll
    for (int j = 0; j < 4; ++j) {
        int idx = j * 256 + tid;
        s_row[j] = idx >> 3;
        s_f4[j]  = idx & 7;
    }

#define LOADT(kt)                                                                     \
    {                                                                                 \
        _Pragma("unroll")                                                             \
        for (int j = 0; j < 4; ++j) {                                                 \
            ra[j] = *(const float4*)&u [(size_t)(m0 + s_row[j]) * DCH + (kt) + s_f4[j] * 4]; \
            rb[j] = *(const float4*)&pw[(size_t)(n0 + s_row[j]) * DCH + (kt) + s_f4[j] * 4]; \
        }                                                                             \
    }
#define WRITET(base)                                                                  \
    {                                                                                 \
        _Pragma("unroll")                                                             \
        for (int j = 0; j < 4; ++j) {                                                 \
            int off = (base) + ((s_row[j] * 64 + s_f4[j] * 8) ^ ((s_row[j] & 3) << 4)); \
            uint2 pa, pbv2;                                                           \
            pa.x   = pack2bf(ra[j].x, ra[j].y);  pa.y   = pack2bf(ra[j].z, ra[j].w);  \
            pbv2.x = pack2bf(rb[j].x, rb[j].y);  pbv2.y = pack2bf(rb[j].z, rb[j].w);  \
            *(uint2*)(lds_raw + off)        = pa;                                     \
            *(uint2*)(lds_raw + off + 8192) = pbv2;                                   \
        }                                                                             \
    }

    LOADT(0);
    WRITET(0);
    LOADT(32);
    __syncthreads();

    for (int t = 0; t < 32; ++t) {
        const int cur = (t & 1) << 14;
        short8 af[4], bf[4];
#pragma unroll
        for (int f = 0; f < 4; ++f) {
            int rowA = wr * 64 + f * 16 + (lane & 15);
            int rowB = wc * 64 + f * 16 + (lane & 15);
            int offA = cur + ((rowA * 64 + ((lane >> 4) * 16)) ^ ((rowA & 3) << 4));
            int offB = cur + 8192 + ((rowB * 64 + ((lane >> 4) * 16)) ^ ((rowB & 3) << 4));
            af[f] = *(short8*)(lds_raw + offA);
            bf[f] = *(short8*)(lds_raw + offB);
        }
        if (t < 31) WRITET(cur ^ 16384);
        if (t < 30) LOADT((t + 2) * 32);
#pragma unroll
        for (int mf = 0; mf < 4; ++mf)
#pragma unroll
            for (int nf = 0; nf < 4; ++nf)
                acc[mf][nf] = __builtin_amdgcn_mfma_f32_16x16x32_bf16(
                    af[mf], bf[nf], acc[mf][nf], 0, 0, 0);
        __syncthreads();
    }

    const int b  = m0 >> 12;
    const int l0 = m0 & (SEQL - 1);
    float pbv[4];
#pragma unroll
    for (int nf = 0; nf < 4; ++nf)
        pbv[nf] = pb[n0 + wc * 64 + nf * 16 + (lane & 15)];

    for (int c = 0; c < 2; ++c) {
        __syncthreads();
#pragma unroll
        for (int j = 0; j < 8; ++j) {
            int idx = j * 256 + tid;
            int dn  = idx >> 4;
            int lf4 = idx & 15;
            float4 vy = *(const float4*)&y[(((size_t)(b * DCH + n0 + dn)) << 12) + l0 + c * 64 + lf4 * 4];
            ysc[lf4 * 4 + 0][dn] = vy.x;
            ysc[lf4 * 4 + 1][dn] = vy.y;
            ysc[lf4 * 4 + 2][dn] = vy.z;
            ysc[lf4 * 4 + 3][dn] = vy.w;
        }
        __syncthreads();
        if (wr == c) {
#pragma unroll
            for (int mf = 0; mf < 4; ++mf)
#pragma unroll
                for (int i = 0; i < 4; ++i) {
                    int lrow = mf * 16 + (lane >> 4) * 4 + i;
                    int m = m0 + c * 64 + lrow;
#pragma unroll
                    for (int nf = 0; nf < 4; ++nf) {
                        int nl = wc * 64 + nf * 16 + (lane & 15);
                        int n = n0 + nl;
                        float proj = acc[mf][nf][i] + pbv[nf];
                        out[(size_t)m * DCH + n] = ysc[lrow][nl] * proj + u[(size_t)m * DCH + n];
                    }
                }
        }
    }
#undef LOADT
#undef WRITET
}

extern "C" void kernel_launch(void* const* d_in, const int* in_sizes, int n_in,
                              void* d_out, int out_size, void* d_ws, size_t ws_size,
                              hipStream_t stream) {
    const float* u  = (const float*)d_in[0];
    const float* z  = (const float*)d_in[1];
    const float* w1 = (const float*)d_in[2];
    const float* b1 = (const float*)d_in[3];
    const float* w2 = (const float*)d_in[4];
    const float* b2 = (const float*)d_in[5];
    const float* pw = (const float*)d_in[6];
    const float* pb = (const float*)d_in[7];
    float* out = (float*)d_out;

    float* h   = (float*)d_ws;                           // 256 KB
    float* uty = (float*)((char*)d_ws + 262144);         // 64 MB
    // scratch inside d_out (fully overwritten by gemm at the end):
    cf* kf  = (cf*)d_out;                                // 1024*4097*8B = 33.5 MB
    cf* tw4 = (cf*)((char*)d_out + (40u << 20));         // 32 KB
    cf* tw8 = tw4 + 4096;                                // 32 KB

    twiddle_init<<<dim3(16), dim3(256), 0, stream>>>(tw4, tw8);
    mlp_kernel<<<dim3(16), dim3(256), 0, stream>>>(z, w1, b1, h);
    transpose_kernel<<<dim3(SEQL / 32, DCH / 32, BATCH), dim3(32, 8), 0, stream>>>(u, uty);
    filt_fft_kernel<<<dim3(DCH), dim3(256), 0, stream>>>(h, w2, b2, tw4, tw8, kf);
    conv_kernel<<<dim3(BATCH * DCH), dim3(256), 0, stream>>>(uty, tw4, tw8, kf);
    gemm_mfma_kernel<<<dim3(128, 8), dim3(256), 0, stream>>>(u, pw, pb, uty, out);
}

// Round 8
// 285.200 us; speedup vs baseline: 1.2139x; 1.1325x over previous
//
#include <hip/hip_runtime.h>
#include <hip/hip_bf16.h>

#define SEQL 4096
#define DCH  1024
#define BATCH 4
#define KH   4097        // stored half-spectrum entries per channel

typedef float2 cf;
__device__ __forceinline__ cf mkc(float x, float y){ return make_float2(x,y); }
__device__ __forceinline__ cf cadd(cf a, cf b){ return mkc(a.x+b.x, a.y+b.y); }
__device__ __forceinline__ cf csub(cf a, cf b){ return mkc(a.x-b.x, a.y-b.y); }
__device__ __forceinline__ cf cmul(cf a, cf b){ return mkc(a.x*b.x - a.y*b.y, a.x*b.y + a.y*b.x); }
__device__ __forceinline__ cf cconjf(cf a){ return mkc(a.x, -a.y); }
__device__ __forceinline__ cf addi(cf a, cf b){ return mkc(a.x - b.y, a.y + b.x); }  // a + i*b
__device__ __forceinline__ cf subi(cf a, cf b){ return mkc(a.x + b.y, a.y - b.x); }  // a - i*b
__device__ __forceinline__ int cpad(int i){ return i + (i >> 4); }                   // +1 cplx per 16
__device__ __forceinline__ int drev(int i){                                          // reverse 6 base-4 digits
    return ((i>>10)&3) | (((i>>8)&3)<<2) | (((i>>6)&3)<<4)
         | (((i>>4)&3)<<6) | (((i>>2)&3)<<8) | ((i&3)<<10);
}

// register-stage twiddles (compile-time constants)
__device__ __forceinline__ cf W1c(int j){   // e^{-2*pi*i*j/16}
    const float cs[4] = {1.f, 0.92387953f, 0.70710678f, 0.38268343f};
    const float sn[4] = {0.f, -0.38268343f, -0.70710678f, -0.92387953f};
    return mkc(cs[j], sn[j]);
}
__device__ __forceinline__ cf W2c(int j){   // e^{-2*pi*i*j/8}
    const float cs[4] = {1.f, 0.70710678f, 0.f, -0.70710678f};
    const float sn[4] = {0.f, -0.70710678f, -1.f, -0.70710678f};
    return mkc(cs[j], sn[j]);
}
__device__ __forceinline__ cf W3c(int j){   // e^{-2*pi*i*3j/16}
    const float cs[4] = {1.f, 0.38268343f, -0.70710678f, -0.92387953f};
    const float sn[4] = {0.f, -0.92387953f, -0.70710678f, 0.38268343f};
    return mkc(cs[j], sn[j]);
}

__device__ __forceinline__ unsigned pack2bf(float a, float b){
    unsigned r;
    asm("v_cvt_pk_bf16_f32 %0, %1, %2" : "=v"(r) : "v"(a), "v"(b));
    return r;   // lo = bf16(a), hi = bf16(b)
}
__device__ __forceinline__ float bflo(unsigned u){ return __uint_as_float(u << 16); }
__device__ __forceinline__ float bfhi(unsigned u){ return __uint_as_float(u & 0xffff0000u); }

// ---------------- twiddle tables ----------------
__global__ __launch_bounds__(256) void twiddle_init(cf* __restrict__ tw4, cf* __restrict__ tw8){
    int i = blockIdx.x*256 + threadIdx.x;   // 4096 total
    const double TWO_PI = 6.283185307179586476925286766559;
    double a4 = -TWO_PI * (double)i / 4096.0;
    double a8 = -TWO_PI * (double)i / 8192.0;
    tw4[i] = mkc((float)cos(a4), (float)sin(a4));
    tw8[i] = mkc((float)cos(a8), (float)sin(a8));
}

// ---------------- MLP: h[l][16] ----------------
__global__ __launch_bounds__(256) void mlp_kernel(
        const float* __restrict__ z, const float* __restrict__ w1,
        const float* __restrict__ b1, float* __restrict__ h) {
    int l = blockIdx.x * blockDim.x + threadIdx.x;
    if (l >= SEQL) return;
    float pe0 = z[l * 3 + 0], pe1 = z[l * 3 + 1], pe2 = z[l * 3 + 2];
#pragma unroll
    for (int j = 0; j < 16; ++j) {
        float v = pe0 * w1[j * 3 + 0] + pe1 * w1[j * 3 + 1] + pe2 * w1[j * 3 + 2] + b1[j];
        h[l * 16 + j] = v > 0.f ? v : 0.f;
    }
}

// ---------------- transpose u (B,L,D) -> ut (B,D,L) ----------------
__global__ __launch_bounds__(256) void transpose_kernel(
        const float* __restrict__ u, float* __restrict__ ut) {
    __shared__ float tile[32][33];
    int b = blockIdx.z;
    int l0 = blockIdx.x * 32;
    int d0 = blockIdx.y * 32;
    int tx = threadIdx.x, ty = threadIdx.y;  // 32 x 8
    const float* up = u + (size_t)b * SEQL * DCH;
#pragma unroll
    for (int i = 0; i < 32; i += 8)
        tile[ty + i][tx] = up[(size_t)(l0 + ty + i) * DCH + d0 + tx];
    __syncthreads();
    float* utp = ut + (size_t)b * DCH * SEQL;
#pragma unroll
    for (int i = 0; i < 32; i += 8)
        utp[(size_t)(d0 + ty + i) * SEQL + l0 + tx] = tile[tx][ty + i];
}

// ---- shared middle DIF passes (m=256,64,16), fwd chunk pass (m=4,m=1) ----
__device__ void dif_mid_and_chunk(cf* lds, const cf* __restrict__ tw){
    const int tid = threadIdx.x;
#pragma unroll
    for (int p = 1; p < 4; ++p) {
        const int lm = 10 - 2*p;          // 8,6,4
        const int m  = 1 << lm;
        const int step = 1024 >> lm;
#pragma unroll
        for (int it = 0; it < 4; ++it) {
            int j = tid + (it << 8);
            int k = j & (m-1);
            int g = j >> lm;
            int i0 = (g << (lm+2)) + k;
            cf x0 = lds[cpad(i0)];
            cf x1 = lds[cpad(i0+m)];
            cf x2 = lds[cpad(i0+2*m)];
            cf x3 = lds[cpad(i0+3*m)];
            cf b0 = cadd(x0,x2), b1 = csub(x0,x2);
            cf b2 = cadd(x1,x3), b3 = csub(x1,x3);
            cf u0 = cadd(b0,b2);
            cf u2 = csub(b0,b2);
            cf u1 = subi(b1,b3);
            cf u3 = addi(b1,b3);
            int t1 = k*step;
            lds[cpad(i0)]     = u0;
            lds[cpad(i0+m)]   = cmul(u1, tw[t1]);
            lds[cpad(i0+2*m)] = cmul(u2, tw[2*t1]);
            lds[cpad(i0+3*m)] = cmul(u3, tw[3*t1]);
        }
        __syncthreads();
    }
    // fused m=4 and m=1 register pass: 16-complex contiguous chunk per thread
    {
        int base = 17*tid;
        cf v[16];
#pragma unroll
        for (int j=0;j<16;++j) v[j] = lds[base+j];
#pragma unroll
        for (int j=0;j<4;++j){
            cf x0=v[j], x1=v[j+4], x2=v[j+8], x3=v[j+12];
            cf b0=cadd(x0,x2), b1=csub(x0,x2), b2=cadd(x1,x3), b3=csub(x1,x3);
            cf u0=cadd(b0,b2), u2=csub(b0,b2), u1=subi(b1,b3), u3=addi(b1,b3);
            v[j]    = u0;
            v[j+4]  = cmul(u1, W1c(j));
            v[j+8]  = cmul(u2, W2c(j));
            v[j+12] = cmul(u3, W3c(j));
        }
#pragma unroll
        for (int c=0;c<4;++c){
            cf x0=v[4*c], x1=v[4*c+1], x2=v[4*c+2], x3=v[4*c+3];
            cf b0=cadd(x0,x2), b1=csub(x0,x2), b2=cadd(x1,x3), b3=csub(x1,x3);
            v[4*c]   = cadd(b0,b2);
            v[4*c+1] = subi(b1,b3);
            v[4*c+2] = csub(b0,b2);
            v[4*c+3] = addi(b1,b3);
        }
#pragma unroll
        for (int j=0;j<16;++j) lds[base+j] = v[j];
        __syncthreads();
    }
}

// ---- inverse: chunk pass (m=1,m=4) + middle DIT passes (m=16,64,256) ----
__device__ void dit_chunk_and_mid(cf* lds, const cf* __restrict__ tw){
    const int tid = threadIdx.x;
    {
        int base = 17*tid;
        cf v[16];
#pragma unroll
        for (int j=0;j<16;++j) v[j] = lds[base+j];
#pragma unroll
        for (int c=0;c<4;++c){
            cf a0=v[4*c], a1=v[4*c+1], a2=v[4*c+2], a3=v[4*c+3];
            cf b0=cadd(a0,a2), b1=csub(a0,a2), b2=cadd(a1,a3), b3=csub(a1,a3);
            v[4*c]   = cadd(b0,b2);
            v[4*c+1] = addi(b1,b3);
            v[4*c+2] = csub(b0,b2);
            v[4*c+3] = subi(b1,b3);
        }
#pragma unroll
        for (int j=0;j<4;++j){
            cf a0=v[j];
            cf a1=cmul(v[j+4],  cconjf(W1c(j)));
            cf a2=cmul(v[j+8],  cconjf(W2c(j)));
            cf a3=cmul(v[j+12], cconjf(W3c(j)));
            cf b0=cadd(a0,a2), b1=csub(a0,a2), b2=cadd(a1,a3), b3=csub(a1,a3);
            v[j]    = cadd(b0,b2);
            v[j+4]  = addi(b1,b3);
            v[j+8]  = csub(b0,b2);
            v[j+12] = subi(b1,b3);
        }
#pragma unroll
        for (int j=0;j<16;++j) lds[base+j] = v[j];
        __syncthreads();
    }
#pragma unroll
    for (int p = 0; p < 3; ++p) {
        const int lm = 4 + 2*p;           // 16,64,256
        const int m  = 1 << lm;
        const int step = 1024 >> lm;
#pragma unroll
        for (int it = 0; it < 4; ++it) {
            int j = tid + (it << 8);
            int k = j & (m-1);
            int g = j >> lm;
            int i0 = (g << (lm+2)) + k;
            int t1 = k*step;
            cf a0 = lds[cpad(i0)];
            cf a1 = cmul(lds[cpad(i0+m)],   cconjf(tw[t1]));
            cf a2 = cmul(lds[cpad(i0+2*m)], cconjf(tw[2*t1]));
            cf a3 = cmul(lds[cpad(i0+3*m)], cconjf(tw[3*t1]));
            cf b0=cadd(a0,a2), b1=csub(a0,a2), b2=cadd(a1,a3), b3=csub(a1,a3);
            lds[cpad(i0)]     = cadd(b0,b2);
            lds[cpad(i0+m)]   = addi(b1,b3);
            lds[cpad(i0+2*m)] = csub(b0,b2);
            lds[cpad(i0+3*m)] = subi(b1,b3);
        }
        __syncthreads();
    }
}

// ---------------- filter row -> packed FFT -> H[d][0..4096] (scaled 1/8192) ----------------
__global__ __launch_bounds__(256) void filt_fft_kernel(
        const float* __restrict__ h, const float* __restrict__ w2,
        const float* __restrict__ b2, const cf* __restrict__ tw4,
        const cf* __restrict__ tw8, cf* __restrict__ kf) {
    __shared__ cf lds[4352];
    const int d = blockIdx.x;
    const int tid = threadIdx.x;
    float wv[16];
#pragma unroll
    for (int j = 0; j < 16; ++j) wv[j] = w2[d * 16 + j];
    const float bb = b2[d];
    // P1 fused (m=1024): x0 = c[j], x1 = c[j+1024], x2 = x3 = 0
#pragma unroll
    for (int it = 0; it < 4; ++it) {
        int j = tid + (it << 8);
        const float* h0 = h + (size_t)(2*j) * 16;
        const float* h1 = h + (size_t)(2*(j+1024)) * 16;
        float f0 = bb, f1 = bb, f2 = bb, f3 = bb;
#pragma unroll
        for (int i = 0; i < 16; ++i) {
            f0 += h0[i] * wv[i];  f1 += h0[16+i] * wv[i];
            f2 += h1[i] * wv[i];  f3 += h1[16+i] * wv[i];
        }
        cf x0 = mkc(f0, f1), x1 = mkc(f2, f3);
        cf u0 = cadd(x0,x1);
        cf u2 = csub(x0,x1);
        cf u1 = subi(x0,x1);
        cf u3 = addi(x0,x1);
        lds[cpad(j)]      = u0;
        lds[cpad(j+1024)] = cmul(u1, tw4[j]);
        lds[cpad(j+2048)] = cmul(u2, tw4[2*j]);
        lds[cpad(j+3072)] = cmul(u3, tw4[3*j]);
    }
    __syncthreads();
    dif_mid_and_chunk(lds, tw4);
    // unpack to real spectrum H[0..4096], scaled; conflict-free pairing enumeration
    const float s = 1.f / 8192.f;
    cf* Hrow = kf + (size_t)d * KH;
    const int lane  = tid & 63;
    const int kbase = ((lane & 31) << 6) | ((lane >> 5) << 5) | ((tid >> 6) << 3);
#pragma unroll
    for (int it = 0; it < 8; ++it) {
        int k = kbase + it;
        if (k == 0) {
            cf c0 = lds[cpad(0)];
            Hrow[0]    = mkc((c0.x + c0.y) * s, 0.f);
            Hrow[4096] = mkc((c0.x - c0.y) * s, 0.f);
            cf c2 = lds[cpad(drev(2048))];
            Hrow[2048] = mkc(c2.x * s, -c2.y * s);
        } else {
            int kk = 4096 - k;
            cf ck  = lds[cpad(drev(k))];
            cf ckk = lds[cpad(drev(kk))];
            cf cc = cconjf(ckk);
            cf E  = mkc(0.5f*(ck.x+cc.x), 0.5f*(ck.y+cc.y));
            cf Dd = csub(ck, cc);
            cf O  = mkc(0.5f*Dd.y, -0.5f*Dd.x);
            cf wvv = tw8[k];
            cf Xk  = cadd(E, cmul(wvv, O));
            cf wp  = mkc(-wvv.x, wvv.y);
            cf Xkk = cadd(cconjf(E), cmul(wp, cconjf(O)));
            Hrow[k]  = mkc(Xk.x * s, Xk.y * s);
            Hrow[kk] = mkc(Xkk.x * s, Xkk.y * s);
        }
    }
}

// ---------------- conv: packed fwd FFT -> spectral multiply -> packed inv FFT -> bf16 y ----------------
__global__ __launch_bounds__(256) void conv_kernel(
        float* __restrict__ uty, const cf* __restrict__ tw4,
        const cf* __restrict__ tw8, const cf* __restrict__ kf) {
    __shared__ cf lds[4352];
    const int row = blockIdx.x;            // b*DCH + d
    const int d = row & (DCH - 1);
    const int tid = threadIdx.x;
    float* rp = uty + (size_t)row * SEQL;
    // P1 fused (m=1024): x0 = c[j], x1 = c[j+1024] from global; x2 = x3 = 0
#pragma unroll
    for (int it = 0; it < 4; ++it) {
        int j = tid + (it << 8);
        cf x0 = *(const cf*)&rp[2*j];
        cf x1 = *(const cf*)&rp[2*(j+1024)];
        cf u0 = cadd(x0,x1);
        cf u2 = csub(x0,x1);
        cf u1 = subi(x0,x1);
        cf u3 = addi(x0,x1);
        lds[cpad(j)]      = u0;
        lds[cpad(j+1024)] = cmul(u1, tw4[j]);
        lds[cpad(j+2048)] = cmul(u2, tw4[2*j]);
        lds[cpad(j+3072)] = cmul(u3, tw4[3*j]);
    }
    __syncthreads();
    dif_mid_and_chunk(lds, tw4);
    // spectral multiply (packed-real unpack * H * repack), conflict-free enumeration
    const cf* Hrow = kf + (size_t)d * KH;
    {
        const int lane  = tid & 63;
        const int kbase = ((lane & 31) << 6) | ((lane >> 5) << 5) | ((tid >> 6) << 3);
#pragma unroll
        for (int it = 0; it < 8; ++it) {
            int k = kbase + it;
            if (k == 0) {
                cf c0 = lds[cpad(0)];
                float X0 = c0.x + c0.y, X4 = c0.x - c0.y;
                cf H0 = Hrow[0], H4 = Hrow[4096];
                cf Y0 = mkc(X0 * H0.x, X0 * H0.y);
                cf Y4 = mkc(X4 * H4.x, X4 * H4.y);
                cf S  = cadd(Y0, Y4), Dd = csub(Y0, Y4);
                lds[cpad(0)] = addi(S, Dd);
                int s2 = cpad(drev(2048));
                cf c2 = lds[s2];
                cf Y2 = cmul(cconjf(c2), Hrow[2048]);
                lds[s2] = mkc(2.f * Y2.x, -2.f * Y2.y);
            } else {
                int kk = 4096 - k;
                int sk = cpad(drev(k)), skk = cpad(drev(kk));
                cf ck = lds[sk], ckk = lds[skk];
                cf cc = cconjf(ckk);
                cf E  = mkc(0.5f*(ck.x+cc.x), 0.5f*(ck.y+cc.y));
                cf Dd = csub(ck, cc);
                cf O  = mkc(0.5f*Dd.y, -0.5f*Dd.x);
                cf wv = tw8[k];
                cf Xk  = cadd(E, cmul(wv, O));
                cf wp  = mkc(-wv.x, wv.y);
                cf Xkk = cadd(cconjf(E), cmul(wp, cconjf(O)));
                cf Yk  = cmul(Xk,  Hrow[k]);
                cf Ykk = cmul(Xkk, Hrow[kk]);
                cf cy = cconjf(Ykk);
                cf S  = cadd(Yk, cy), D2 = csub(Yk, cy);
                cf Zk = addi(S, cmul(cconjf(wv), D2));
                cf cy2 = cconjf(Yk);
                cf S2  = cadd(Ykk, cy2), D3 = csub(Ykk, cy2);
                cf Zkk = subi(S2, cmul(wv, D3));
                lds[sk] = Zk; lds[skk] = Zkk;
            }
        }
    }
    __syncthreads();
    dit_chunk_and_mid(lds, tw4);
    // P5' fused (m=1024): only outputs n<2048 needed; store bf16 y in place (first 8KB of row)
    unsigned short* yb = (unsigned short*)rp;
#pragma unroll
    for (int it = 0; it < 4; ++it) {
        int j = tid + (it << 8);
        cf a0 = lds[cpad(j)];
        cf a1 = cmul(lds[cpad(j+1024)], cconjf(tw4[j]));
        cf a2 = cmul(lds[cpad(j+2048)], cconjf(tw4[2*j]));
        cf a3 = cmul(lds[cpad(j+3072)], cconjf(tw4[3*j]));
        cf b0 = cadd(a0,a2), b1 = csub(a0,a2);
        cf b2 = cadd(a1,a3), b3 = csub(a1,a3);
        cf o0 = cadd(b0,b2);           // n = j       -> y[2j], y[2j+1]
        cf o1 = addi(b1,b3);           // n = j+1024  -> y[2j+2048], y[2j+2049]
        *(unsigned*)&yb[2*j]          = pack2bf(o0.x, o0.y);
        *(unsigned*)&yb[2*(j+1024)]   = pack2bf(o1.x, o1.y);
    }
}

// ---------------- bf16 MFMA GEMM: out = y^T * (u @ pw^T + pb) + u ----------------
typedef __attribute__((ext_vector_type(8))) short short8;
typedef __attribute__((ext_vector_type(4))) float f32x4;

__global__ __launch_bounds__(256, 3) void gemm_mfma_kernel(
        const float* __restrict__ u, const float* __restrict__ pw,
        const float* __restrict__ pb, const unsigned short* __restrict__ yb,
        float* __restrict__ out) {
    __shared__ char lds_raw[34816];
    float (*ysc)[132] = (float(*)[132])lds_raw;

    const int tid  = threadIdx.x;
    const int lane = tid & 63;
    const int wid  = tid >> 6;
    const int wr   = wid >> 1;
    const int wc   = wid & 1;
    const int m0   = blockIdx.x * 128;  // m-major grid: same-m blocks share an XCD
    const int n0   = blockIdx.y * 128;

    f32x4 acc[4][4] = {};
    float4 ra[4], rb[4];

    int s_row[4], s_f4[4];
#pragma unroll
    for (int j = 0; j < 4; ++j) {
        int idx = j * 256 + tid;
        s_row[j] = idx >> 3;
        s_f4[j]  = idx & 7;
    }

#define LOADT(kt)                                                                     \
    {                                                                                 \
        _Pragma("unroll")                                                             \
        for (int j = 0; j < 4; ++j) {                                                 \
            ra[j] = *(const float4*)&u [(size_t)(m0 + s_row[j]) * DCH + (kt) + s_f4[j] * 4]; \
            rb[j] = *(const float4*)&pw[(size_t)(n0 + s_row[j]) * DCH + (kt) + s_f4[j] * 4]; \
        }                                                                             \
    }
#define WRITET(base)                                                                  \
    {                                                                                 \
        _Pragma("unroll")                                                             \
        for (int j = 0; j < 4; ++j) {                                                 \
            int off = (base) + ((s_row[j] * 64 + s_f4[j] * 8) ^ ((s_row[j] & 3) << 4)); \
            uint2 pa, pbv2;                                                           \
            pa.x   = pack2bf(ra[j].x, ra[j].y);  pa.y   = pack2bf(ra[j].z, ra[j].w);  \
            pbv2.x = pack2bf(rb[j].x, rb[j].y);  pbv2.y = pack2bf(rb[j].z, rb[j].w);  \
            *(uint2*)(lds_raw + off)        = pa;                                     \
            *(uint2*)(lds_raw + off + 8192) = pbv2;                                   \
        }                                                                             \
    }

    LOADT(0);
    WRITET(0);
    LOADT(32);
    __syncthreads();

    for (int t = 0; t < 32; ++t) {
        const int cur = (t & 1) << 14;
        short8 af[4], bf[4];
#pragma unroll
        for (int f = 0; f < 4; ++f) {
            int rowA = wr * 64 + f * 16 + (lane & 15);
            int rowB = wc * 64 + f * 16 + (lane & 15);
            int offA = cur + ((rowA * 64 + ((lane >> 4) * 16)) ^ ((rowA & 3) << 4));
            int offB = cur + 8192 + ((rowB * 64 + ((lane >> 4) * 16)) ^ ((rowB & 3) << 4));
            af[f] = *(short8*)(lds_raw + offA);
            bf[f] = *(short8*)(lds_raw + offB);
        }
        if (t < 31) WRITET(cur ^ 16384);
        if (t < 30) LOADT((t + 2) * 32);
#pragma unroll
        for (int mf = 0; mf < 4; ++mf)
#pragma unroll
            for (int nf = 0; nf < 4; ++nf)
                acc[mf][nf] = __builtin_amdgcn_mfma_f32_16x16x32_bf16(
                    af[mf], bf[nf], acc[mf][nf], 0, 0, 0);
        __syncthreads();
    }

    const int b  = m0 >> 12;
    const int l0 = m0 & (SEQL - 1);
    float pbv[4];
#pragma unroll
    for (int nf = 0; nf < 4; ++nf)
        pbv[nf] = pb[n0 + wc * 64 + nf * 16 + (lane & 15)];

    for (int c = 0; c < 2; ++c) {
        __syncthreads();
        // stage ysc[l_local][n_local] from bf16 y (B,D,L layout, 4096 ushort/row region of 8192)
#pragma unroll
        for (int j = 0; j < 4; ++j) {
            int idx = j * 256 + tid;    // 1024 = 128 dn x 8 lg (8 bf16 each)
            int dn  = idx >> 3;
            int lg  = idx & 7;
            uint4 w4 = *(const uint4*)&yb[(((size_t)(b * DCH + n0 + dn)) << 13) + l0 + c * 64 + lg * 8];
            int lb = lg * 8;
            ysc[lb+0][dn] = bflo(w4.x); ysc[lb+1][dn] = bfhi(w4.x);
            ysc[lb+2][dn] = bflo(w4.y); ysc[lb+3][dn] = bfhi(w4.y);
            ysc[lb+4][dn] = bflo(w4.z); ysc[lb+5][dn] = bfhi(w4.z);
            ysc[lb+6][dn] = bflo(w4.w); ysc[lb+7][dn] = bfhi(w4.w);
        }
        __syncthreads();
        if (wr == c) {
#pragma unroll
            for (int mf = 0; mf < 4; ++mf)
#pragma unroll
                for (int i = 0; i < 4; ++i) {
                    int lrow = mf * 16 + (lane >> 4) * 4 + i;
                    int m = m0 + c * 64 + lrow;
#pragma unroll
                    for (int nf = 0; nf < 4; ++nf) {
                        int nl = wc * 64 + nf * 16 + (lane & 15);
                        int n = n0 + nl;
                        float proj = acc[mf][nf][i] + pbv[nf];
                        out[(size_t)m * DCH + n] = ysc[lrow][nl] * proj + u[(size_t)m * DCH + n];
                    }
                }
        }
    }
#undef LOADT
#undef WRITET
}

extern "C" void kernel_launch(void* const* d_in, const int* in_sizes, int n_in,
                              void* d_out, int out_size, void* d_ws, size_t ws_size,
                              hipStream_t stream) {
    const float* u  = (const float*)d_in[0];
    const float* z  = (const float*)d_in[1];
    const float* w1 = (const float*)d_in[2];
    const float* b1 = (const float*)d_in[3];
    const float* w2 = (const float*)d_in[4];
    const float* b2 = (const float*)d_in[5];
    const float* pw = (const float*)d_in[6];
    const float* pb = (const float*)d_in[7];
    float* out = (float*)d_out;

    float* h   = (float*)d_ws;                           // 256 KB
    float* uty = (float*)((char*)d_ws + 262144);         // 64 MB (ut f32; y bf16 in-place per row)
    // scratch inside d_out (fully overwritten by gemm at the end):
    cf* kf  = (cf*)d_out;                                // 1024*4097*8B = 33.5 MB
    cf* tw4 = (cf*)((char*)d_out + (40u << 20));         // 32 KB
    cf* tw8 = tw4 + 4096;                                // 32 KB

    twiddle_init<<<dim3(16), dim3(256), 0, stream>>>(tw4, tw8);
    mlp_kernel<<<dim3(16), dim3(256), 0, stream>>>(z, w1, b1, h);
    transpose_kernel<<<dim3(SEQL / 32, DCH / 32, BATCH), dim3(32, 8), 0, stream>>>(u, uty);
    filt_fft_kernel<<<dim3(DCH), dim3(256), 0, stream>>>(h, w2, b2, tw4, tw8, kf);
    conv_kernel<<<dim3(BATCH * DCH), dim3(256), 0, stream>>>(uty, tw4, tw8, kf);
    gemm_mfma_kernel<<<dim3(128, 8), dim3(256), 0, stream>>>(u, pw, pb, (const unsigned short*)uty, out);
}

// Round 9
// 275.622 us; speedup vs baseline: 1.2560x; 1.0348x over previous
//
#include <hip/hip_runtime.h>
#include <hip/hip_bf16.h>

#define SEQL 4096
#define DCH  1024
#define BATCH 4
#define KH   4097        // stored half-spectrum entries per channel

typedef float2 cf;
__device__ __forceinline__ cf mkc(float x, float y){ return make_float2(x,y); }
__device__ __forceinline__ cf cadd(cf a, cf b){ return mkc(a.x+b.x, a.y+b.y); }
__device__ __forceinline__ cf csub(cf a, cf b){ return mkc(a.x-b.x, a.y-b.y); }
__device__ __forceinline__ cf cmul(cf a, cf b){ return mkc(a.x*b.x - a.y*b.y, a.x*b.y + a.y*b.x); }
__device__ __forceinline__ cf cconjf(cf a){ return mkc(a.x, -a.y); }
__device__ __forceinline__ cf addi(cf a, cf b){ return mkc(a.x - b.y, a.y + b.x); }  // a + i*b
__device__ __forceinline__ cf subi(cf a, cf b){ return mkc(a.x + b.y, a.y - b.x); }  // a - i*b
__device__ __forceinline__ int cpad(int i){ return i + (i >> 4); }                   // +1 cplx per 16
__device__ __forceinline__ int drev(int i){                                          // reverse 6 base-4 digits
    return ((i>>10)&3) | (((i>>8)&3)<<2) | (((i>>6)&3)<<4)
         | (((i>>4)&3)<<6) | (((i>>2)&3)<<8) | ((i&3)<<10);
}

// register-stage twiddles (compile-time constants)
__device__ __forceinline__ cf W1c(int j){   // e^{-2*pi*i*j/16}
    const float cs[4] = {1.f, 0.92387953f, 0.70710678f, 0.38268343f};
    const float sn[4] = {0.f, -0.38268343f, -0.70710678f, -0.92387953f};
    return mkc(cs[j], sn[j]);
}
__device__ __forceinline__ cf W2c(int j){   // e^{-2*pi*i*j/8}
    const float cs[4] = {1.f, 0.70710678f, 0.f, -0.70710678f};
    const float sn[4] = {0.f, -0.70710678f, -1.f, -0.70710678f};
    return mkc(cs[j], sn[j]);
}
__device__ __forceinline__ cf W3c(int j){   // e^{-2*pi*i*3j/16}
    const float cs[4] = {1.f, 0.38268343f, -0.70710678f, -0.92387953f};
    const float sn[4] = {0.f, -0.92387953f, -0.70710678f, 0.38268343f};
    return mkc(cs[j], sn[j]);
}

__device__ __forceinline__ unsigned pack2bf(float a, float b){
    unsigned r;
    asm("v_cvt_pk_bf16_f32 %0, %1, %2" : "=v"(r) : "v"(a), "v"(b));
    return r;   // lo = bf16(a), hi = bf16(b)
}
__device__ __forceinline__ float bflo(unsigned u){ return __uint_as_float(u << 16); }
__device__ __forceinline__ float bfhi(unsigned u){ return __uint_as_float(u & 0xffff0000u); }

__device__ __forceinline__ void gload16(const void* g, void* l){
    __builtin_amdgcn_global_load_lds((const __attribute__((address_space(1))) void*)g,
                                     (__attribute__((address_space(3))) void*)l, 16, 0, 0);
}

// ---------------- twiddle tables ----------------
__global__ __launch_bounds__(256) void twiddle_init(cf* __restrict__ tw4, cf* __restrict__ tw8){
    int i = blockIdx.x*256 + threadIdx.x;   // 4096 total
    const double TWO_PI = 6.283185307179586476925286766559;
    double a4 = -TWO_PI * (double)i / 4096.0;
    double a8 = -TWO_PI * (double)i / 8192.0;
    tw4[i] = mkc((float)cos(a4), (float)sin(a4));
    tw8[i] = mkc((float)cos(a8), (float)sin(a8));
}

// ---------------- MLP: h[l][16] ----------------
__global__ __launch_bounds__(256) void mlp_kernel(
        const float* __restrict__ z, const float* __restrict__ w1,
        const float* __restrict__ b1, float* __restrict__ h) {
    int l = blockIdx.x * blockDim.x + threadIdx.x;
    if (l >= SEQL) return;
    float pe0 = z[l * 3 + 0], pe1 = z[l * 3 + 1], pe2 = z[l * 3 + 2];
#pragma unroll
    for (int j = 0; j < 16; ++j) {
        float v = pe0 * w1[j * 3 + 0] + pe1 * w1[j * 3 + 1] + pe2 * w1[j * 3 + 2] + b1[j];
        h[l * 16 + j] = v > 0.f ? v : 0.f;
    }
}

// ---------------- transpose u (B,L,D) -> ut (B,D,L), optional ub = bf16(u) ----------------
__global__ __launch_bounds__(256) void transpose_kernel(
        const float* __restrict__ u, float* __restrict__ ut,
        unsigned short* __restrict__ ub) {
    __shared__ float tile[32][33];
    int b = blockIdx.z;
    int l0 = blockIdx.x * 32;
    int d0 = blockIdx.y * 32;
    int tx = threadIdx.x, ty = threadIdx.y;  // 32 x 8
    const float* up = u + (size_t)b * SEQL * DCH;
    unsigned short* ubp = ub ? ub + (size_t)b * SEQL * DCH : (unsigned short*)0;
#pragma unroll
    for (int i = 0; i < 32; i += 8) {
        size_t idx = (size_t)(l0 + ty + i) * DCH + d0 + tx;
        float v = up[idx];
        tile[ty + i][tx] = v;
        if (ub) ubp[idx] = (unsigned short)pack2bf(v, v);
    }
    __syncthreads();
    float* utp = ut + (size_t)b * DCH * SEQL;
#pragma unroll
    for (int i = 0; i < 32; i += 8)
        utp[(size_t)(d0 + ty + i) * SEQL + l0 + tx] = tile[tx][ty + i];
}

// ---------------- pw -> bf16 ----------------
__global__ __launch_bounds__(256) void pw2bf_kernel(
        const float* __restrict__ pw, unsigned short* __restrict__ pwb) {
    int t = blockIdx.x * 256 + threadIdx.x;
    float4 a = *(const float4*)&pw[(size_t)t * 8];
    float4 b = *(const float4*)&pw[(size_t)t * 8 + 4];
    uint4 o;
    o.x = pack2bf(a.x, a.y); o.y = pack2bf(a.z, a.w);
    o.z = pack2bf(b.x, b.y); o.w = pack2bf(b.z, b.w);
    *(uint4*)&pwb[(size_t)t * 8] = o;
}

// ---- shared middle DIF passes (m=256,64,16), fwd chunk pass (m=4,m=1) ----
__device__ void dif_mid_and_chunk(cf* lds, const cf* __restrict__ tw){
    const int tid = threadIdx.x;
#pragma unroll
    for (int p = 1; p < 4; ++p) {
        const int lm = 10 - 2*p;          // 8,6,4
        const int m  = 1 << lm;
        const int step = 1024 >> lm;
#pragma unroll
        for (int it = 0; it < 4; ++it) {
            int j = tid + (it << 8);
            int k = j & (m-1);
            int g = j >> lm;
            int i0 = (g << (lm+2)) + k;
            cf x0 = lds[cpad(i0)];
            cf x1 = lds[cpad(i0+m)];
            cf x2 = lds[cpad(i0+2*m)];
            cf x3 = lds[cpad(i0+3*m)];
            cf b0 = cadd(x0,x2), b1 = csub(x0,x2);
            cf b2 = cadd(x1,x3), b3 = csub(x1,x3);
            cf u0 = cadd(b0,b2);
            cf u2 = csub(b0,b2);
            cf u1 = subi(b1,b3);
            cf u3 = addi(b1,b3);
            int t1 = k*step;
            lds[cpad(i0)]     = u0;
            lds[cpad(i0+m)]   = cmul(u1, tw[t1]);
            lds[cpad(i0+2*m)] = cmul(u2, tw[2*t1]);
            lds[cpad(i0+3*m)] = cmul(u3, tw[3*t1]);
        }
        __syncthreads();
    }
    {
        int base = 17*tid;
        cf v[16];
#pragma unroll
        for (int j=0;j<16;++j) v[j] = lds[base+j];
#pragma unroll
        for (int j=0;j<4;++j){
            cf x0=v[j], x1=v[j+4], x2=v[j+8], x3=v[j+12];
            cf b0=cadd(x0,x2), b1=csub(x0,x2), b2=cadd(x1,x3), b3=csub(x1,x3);
            cf u0=cadd(b0,b2), u2=csub(b0,b2), u1=subi(b1,b3), u3=addi(b1,b3);
            v[j]    = u0;
            v[j+4]  = cmul(u1, W1c(j));
            v[j+8]  = cmul(u2, W2c(j));
            v[j+12] = cmul(u3, W3c(j));
        }
#pragma unroll
        for (int c=0;c<4;++c){
            cf x0=v[4*c], x1=v[4*c+1], x2=v[4*c+2], x3=v[4*c+3];
            cf b0=cadd(x0,x2), b1=csub(x0,x2), b2=cadd(x1,x3), b3=csub(x1,x3);
            v[4*c]   = cadd(b0,b2);
            v[4*c+1] = subi(b1,b3);
            v[4*c+2] = csub(b0,b2);
            v[4*c+3] = addi(b1,b3);
        }
#pragma unroll
        for (int j=0;j<16;++j) lds[base+j] = v[j];
        __syncthreads();
    }
}

// ---- inverse: chunk pass (m=1,m=4) + middle DIT passes (m=16,64,256) ----
__device__ void dit_chunk_and_mid(cf* lds, const cf* __restrict__ tw){
    const int tid = threadIdx.x;
    {
        int base = 17*tid;
        cf v[16];
#pragma unroll
        for (int j=0;j<16;++j) v[j] = lds[base+j];
#pragma unroll
        for (int c=0;c<4;++c){
            cf a0=v[4*c], a1=v[4*c+1], a2=v[4*c+2], a3=v[4*c+3];
            cf b0=cadd(a0,a2), b1=csub(a0,a2), b2=cadd(a1,a3), b3=csub(a1,a3);
            v[4*c]   = cadd(b0,b2);
            v[4*c+1] = addi(b1,b3);
            v[4*c+2] = csub(b0,b2);
            v[4*c+3] = subi(b1,b3);
        }
#pragma unroll
        for (int j=0;j<4;++j){
            cf a0=v[j];
            cf a1=cmul(v[j+4],  cconjf(W1c(j)));
            cf a2=cmul(v[j+8],  cconjf(W2c(j)));
            cf a3=cmul(v[j+12], cconjf(W3c(j)));
            cf b0=cadd(a0,a2), b1=csub(a0,a2), b2=cadd(a1,a3), b3=csub(a1,a3);
            v[j]    = cadd(b0,b2);
            v[j+4]  = addi(b1,b3);
            v[j+8]  = csub(b0,b2);
            v[j+12] = subi(b1,b3);
        }
#pragma unroll
        for (int j=0;j<16;++j) lds[base+j] = v[j];
        __syncthreads();
    }
#pragma unroll
    for (int p = 0; p < 3; ++p) {
        const int lm = 4 + 2*p;           // 16,64,256
        const int m  = 1 << lm;
        const int step = 1024 >> lm;
#pragma unroll
        for (int it = 0; it < 4; ++it) {
            int j = tid + (it << 8);
            int k = j & (m-1);
            int g = j >> lm;
            int i0 = (g << (lm+2)) + k;
            int t1 = k*step;
            cf a0 = lds[cpad(i0)];
            cf a1 = cmul(lds[cpad(i0+m)],   cconjf(tw[t1]));
            cf a2 = cmul(lds[cpad(i0+2*m)], cconjf(tw[2*t1]));
            cf a3 = cmul(lds[cpad(i0+3*m)], cconjf(tw[3*t1]));
            cf b0=cadd(a0,a2), b1=csub(a0,a2), b2=cadd(a1,a3), b3=csub(a1,a3);
            lds[cpad(i0)]     = cadd(b0,b2);
            lds[cpad(i0+m)]   = addi(b1,b3);
            lds[cpad(i0+2*m)] = csub(b0,b2);
            lds[cpad(i0+3*m)] = subi(b1,b3);
        }
        __syncthreads();
    }
}

// ---------------- filter row -> packed FFT -> H[d][0..4096] (scaled 1/8192) ----------------
__global__ __launch_bounds__(256) void filt_fft_kernel(
        const float* __restrict__ h, const float* __restrict__ w2,
        const float* __restrict__ b2, const cf* __restrict__ tw4,
        const cf* __restrict__ tw8, cf* __restrict__ kf) {
    __shared__ cf lds[4352];
    const int d = blockIdx.x;
    const int tid = threadIdx.x;
    float wv[16];
#pragma unroll
    for (int j = 0; j < 16; ++j) wv[j] = w2[d * 16 + j];
    const float bb = b2[d];
#pragma unroll
    for (int it = 0; it < 4; ++it) {
        int j = tid + (it << 8);
        const float* h0 = h + (size_t)(2*j) * 16;
        const float* h1 = h + (size_t)(2*(j+1024)) * 16;
        float f0 = bb, f1 = bb, f2 = bb, f3 = bb;
#pragma unroll
        for (int i = 0; i < 16; ++i) {
            f0 += h0[i] * wv[i];  f1 += h0[16+i] * wv[i];
            f2 += h1[i] * wv[i];  f3 += h1[16+i] * wv[i];
        }
        cf x0 = mkc(f0, f1), x1 = mkc(f2, f3);
        cf u0 = cadd(x0,x1);
        cf u2 = csub(x0,x1);
        cf u1 = subi(x0,x1);
        cf u3 = addi(x0,x1);
        lds[cpad(j)]      = u0;
        lds[cpad(j+1024)] = cmul(u1, tw4[j]);
        lds[cpad(j+2048)] = cmul(u2, tw4[2*j]);
        lds[cpad(j+3072)] = cmul(u3, tw4[3*j]);
    }
    __syncthreads();
    dif_mid_and_chunk(lds, tw4);
    const float s = 1.f / 8192.f;
    cf* Hrow = kf + (size_t)d * KH;
    const int lane  = tid & 63;
    const int kbase = ((lane & 31) << 6) | ((lane >> 5) << 5) | ((tid >> 6) << 3);
#pragma unroll
    for (int it = 0; it < 8; ++it) {
        int k = kbase + it;
        if (k == 0) {
            cf c0 = lds[cpad(0)];
            Hrow[0]    = mkc((c0.x + c0.y) * s, 0.f);
            Hrow[4096] = mkc((c0.x - c0.y) * s, 0.f);
            cf c2 = lds[cpad(drev(2048))];
            Hrow[2048] = mkc(c2.x * s, -c2.y * s);
        } else {
            int kk = 4096 - k;
            cf ck  = lds[cpad(drev(k))];
            cf ckk = lds[cpad(drev(kk))];
            cf cc = cconjf(ckk);
            cf E  = mkc(0.5f*(ck.x+cc.x), 0.5f*(ck.y+cc.y));
            cf Dd = csub(ck, cc);
            cf O  = mkc(0.5f*Dd.y, -0.5f*Dd.x);
            cf wvv = tw8[k];
            cf Xk  = cadd(E, cmul(wvv, O));
            cf wp  = mkc(-wvv.x, wvv.y);
            cf Xkk = cadd(cconjf(E), cmul(wp, cconjf(O)));
            Hrow[k]  = mkc(Xk.x * s, Xk.y * s);
            Hrow[kk] = mkc(Xkk.x * s, Xkk.y * s);
        }
    }
}

// ---------------- conv: packed fwd FFT -> spectral multiply -> packed inv FFT -> bf16 y ----------------
__global__ __launch_bounds__(256) void conv_kernel(
        float* __restrict__ uty, const cf* __restrict__ tw4,
        const cf* __restrict__ tw8, const cf* __restrict__ kf) {
    __shared__ cf lds[4352];
    const int row = blockIdx.x;            // b*DCH + d
    const int d = row & (DCH - 1);
    const int tid = threadIdx.x;
    float* rp = uty + (size_t)row * SEQL;
#pragma unroll
    for (int it = 0; it < 4; ++it) {
        int j = tid + (it << 8);
        cf x0 = *(const cf*)&rp[2*j];
        cf x1 = *(const cf*)&rp[2*(j+1024)];
        cf u0 = cadd(x0,x1);
        cf u2 = csub(x0,x1);
        cf u1 = subi(x0,x1);
        cf u3 = addi(x0,x1);
        lds[cpad(j)]      = u0;
        lds[cpad(j+1024)] = cmul(u1, tw4[j]);
        lds[cpad(j+2048)] = cmul(u2, tw4[2*j]);
        lds[cpad(j+3072)] = cmul(u3, tw4[3*j]);
    }
    __syncthreads();
    dif_mid_and_chunk(lds, tw4);
    const cf* Hrow = kf + (size_t)d * KH;
    {
        const int lane  = tid & 63;
        const int kbase = ((lane & 31) << 6) | ((lane >> 5) << 5) | ((tid >> 6) << 3);
#pragma unroll
        for (int it = 0; it < 8; ++it) {
            int k = kbase + it;
            if (k == 0) {
                cf c0 = lds[cpad(0)];
                float X0 = c0.x + c0.y, X4 = c0.x - c0.y;
                cf H0 = Hrow[0], H4 = Hrow[4096];
                cf Y0 = mkc(X0 * H0.x, X0 * H0.y);
                cf Y4 = mkc(X4 * H4.x, X4 * H4.y);
                cf S  = cadd(Y0, Y4), Dd = csub(Y0, Y4);
                lds[cpad(0)] = addi(S, Dd);
                int s2 = cpad(drev(2048));
                cf c2 = lds[s2];
                cf Y2 = cmul(cconjf(c2), Hrow[2048]);
                lds[s2] = mkc(2.f * Y2.x, -2.f * Y2.y);
            } else {
                int kk = 4096 - k;
                int sk = cpad(drev(k)), skk = cpad(drev(kk));
                cf ck = lds[sk], ckk = lds[skk];
                cf cc = cconjf(ckk);
                cf E  = mkc(0.5f*(ck.x+cc.x), 0.5f*(ck.y+cc.y));
                cf Dd = csub(ck, cc);
                cf O  = mkc(0.5f*Dd.y, -0.5f*Dd.x);
                cf wv = tw8[k];
                cf Xk  = cadd(E, cmul(wv, O));
                cf wp  = mkc(-wv.x, wv.y);
                cf Xkk = cadd(cconjf(E), cmul(wp, cconjf(O)));
                cf Yk  = cmul(Xk,  Hrow[k]);
                cf Ykk = cmul(Xkk, Hrow[kk]);
                cf cy = cconjf(Ykk);
                cf S  = cadd(Yk, cy), D2 = csub(Yk, cy);
                cf Zk = addi(S, cmul(cconjf(wv), D2));
                cf cy2 = cconjf(Yk);
                cf S2  = cadd(Ykk, cy2), D3 = csub(Ykk, cy2);
                cf Zkk = subi(S2, cmul(wv, D3));
                lds[sk] = Zk; lds[skk] = Zkk;
            }
        }
    }
    __syncthreads();
    dit_chunk_and_mid(lds, tw4);
    unsigned short* yb = (unsigned short*)rp;
#pragma unroll
    for (int it = 0; it < 4; ++it) {
        int j = tid + (it << 8);
        cf a0 = lds[cpad(j)];
        cf a1 = cmul(lds[cpad(j+1024)], cconjf(tw4[j]));
        cf a2 = cmul(lds[cpad(j+2048)], cconjf(tw4[2*j]));
        cf a3 = cmul(lds[cpad(j+3072)], cconjf(tw4[3*j]));
        cf b0 = cadd(a0,a2), b1 = csub(a0,a2);
        cf b2 = cadd(a1,a3), b3 = csub(a1,a3);
        cf o0 = cadd(b0,b2);
        cf o1 = addi(b1,b3);
        *(unsigned*)&yb[2*j]          = pack2bf(o0.x, o0.y);
        *(unsigned*)&yb[2*(j+1024)]   = pack2bf(o1.x, o1.y);
    }
}

typedef __attribute__((ext_vector_type(8))) short short8;
typedef __attribute__((ext_vector_type(4))) float f32x4;

// ---------------- gemm v2: global_load_lds from bf16 ub/pwb ----------------
__global__ __launch_bounds__(256, 4) void gemm_mfma_v2(
        const unsigned short* __restrict__ ub, const unsigned short* __restrict__ pwb,
        const float* __restrict__ pb, const unsigned short* __restrict__ yb,
        float* __restrict__ out) {
    __shared__ char lds_raw[34816];          // dbuf: A@0/B@8192, A@16384/B@24576; epilogue ysc overlay
    float (*ysc)[132] = (float(*)[132])lds_raw;

    const int tid  = threadIdx.x;
    const int lane = tid & 63;
    const int wid  = tid >> 6;
    const int wr   = wid >> 1;
    const int wc   = wid & 1;
    const int m0   = blockIdx.x * 128;       // m-major grid: n-blocks of same m share an XCD
    const int n0   = blockIdx.y * 128;

    f32x4 acc[4][4] = {};

    // staging: chunk c (16 rows); lane covers row c*16 + lane/4, 16B at pre-swizzled col
    const int srow = lane >> 2;
    const int scol = 16 * ((lane & 3) ^ ((lane >> 2) & 3));   // inverse-swizzled source col

#define STAGE2(bufbase, kt)                                                                   \
    {                                                                                         \
        _Pragma("unroll")                                                                     \
        for (int i = 0; i < 2; ++i) {                                                         \
            int c = wid * 2 + i;                                                              \
            const char* gA = (const char*)ub  + (size_t)(m0 + c * 16 + srow) * 2048 + (kt) * 2 + scol; \
            const char* gB = (const char*)pwb + (size_t)(n0 + c * 16 + srow) * 2048 + (kt) * 2 + scol; \
            gload16(gA, lds_raw + (bufbase) + c * 1024);                                      \
            gload16(gB, lds_raw + (bufbase) + 8192 + c * 1024);                               \
        }                                                                                     \
    }

    STAGE2(0, 0);
    __syncthreads();

    for (int t = 0; t < 32; ++t) {
        const int cur = (t & 1) << 14;
        if (t < 31) STAGE2(cur ^ 16384, (t + 1) * 32);
        short8 af[4], bfr[4];
#pragma unroll
        for (int f = 0; f < 4; ++f) {
            int rowA = wr * 64 + f * 16 + (lane & 15);
            int rowB = wc * 64 + f * 16 + (lane & 15);
            int offA = cur + rowA * 64 + (((lane >> 4) * 16) ^ ((rowA & 3) << 4));
            int offB = cur + 8192 + rowB * 64 + (((lane >> 4) * 16) ^ ((rowB & 3) << 4));
            af[f]  = *(short8*)(lds_raw + offA);
            bfr[f] = *(short8*)(lds_raw + offB);
        }
#pragma unroll
        for (int mf = 0; mf < 4; ++mf)
#pragma unroll
            for (int nf = 0; nf < 4; ++nf)
                acc[mf][nf] = __builtin_amdgcn_mfma_f32_16x16x32_bf16(
                    af[mf], bfr[nf], acc[mf][nf], 0, 0, 0);
        __syncthreads();
    }

    // ---- fused epilogue: out = y * (acc + pb) + u  (y, u residual from bf16) ----
    const int b  = m0 >> 12;
    const int l0 = m0 & (SEQL - 1);
    float pbv[4];
#pragma unroll
    for (int nf = 0; nf < 4; ++nf)
        pbv[nf] = pb[n0 + wc * 64 + nf * 16 + (lane & 15)];

    for (int c = 0; c < 2; ++c) {
        __syncthreads();
#pragma unroll
        for (int j = 0; j < 4; ++j) {
            int idx = j * 256 + tid;
            int dn  = idx >> 3;
            int lg  = idx & 7;
            uint4 w4 = *(const uint4*)&yb[(((size_t)(b * DCH + n0 + dn)) << 13) + l0 + c * 64 + lg * 8];
            int lb = lg * 8;
            ysc[lb+0][dn] = bflo(w4.x); ysc[lb+1][dn] = bfhi(w4.x);
            ysc[lb+2][dn] = bflo(w4.y); ysc[lb+3][dn] = bfhi(w4.y);
            ysc[lb+4][dn] = bflo(w4.z); ysc[lb+5][dn] = bfhi(w4.z);
            ysc[lb+6][dn] = bflo(w4.w); ysc[lb+7][dn] = bfhi(w4.w);
        }
        __syncthreads();
        if (wr == c) {
#pragma unroll
            for (int mf = 0; mf < 4; ++mf)
#pragma unroll
                for (int i = 0; i < 4; ++i) {
                    int lrow = mf * 16 + (lane >> 4) * 4 + i;
                    int m = m0 + c * 64 + lrow;
#pragma unroll
                    for (int nf = 0; nf < 4; ++nf) {
                        int nl = wc * 64 + nf * 16 + (lane & 15);
                        int n = n0 + nl;
                        float proj = acc[mf][nf][i] + pbv[nf];
                        float ures = __uint_as_float((unsigned)ub[(size_t)m * DCH + n] << 16);
                        out[(size_t)m * DCH + n] = ysc[lrow][nl] * proj + ures;
                    }
                }
        }
    }
#undef STAGE2
}

// ---------------- gemm fallback (round-8 reg-staged): used when ws too small ----------------
__global__ __launch_bounds__(256, 3) void gemm_mfma_fb(
        const float* __restrict__ u, const float* __restrict__ pw,
        const float* __restrict__ pb, const unsigned short* __restrict__ yb,
        float* __restrict__ out) {
    __shared__ char lds_raw[34816];
    float (*ysc)[132] = (float(*)[132])lds_raw;
    const int tid  = threadIdx.x;
    const int lane = tid & 63;
    const int wid  = tid >> 6;
    const int wr   = wid >> 1;
    const int wc   = wid & 1;
    const int m0   = blockIdx.x * 128;
    const int n0   = blockIdx.y * 128;
    f32x4 acc[4][4] = {};
    float4 ra[4], rb[4];
    int s_row[4], s_f4[4];
#pragma unroll
    for (int j = 0; j < 4; ++j) {
        int idx = j * 256 + tid;
        s_row[j] = idx >> 3;
        s_f4[j]  = idx & 7;
    }
#define LOADT(kt)                                                                     \
    {                                                                                 \
        _Pragma("unroll")                                                             \
        for (int j = 0; j < 4; ++j) {                                                 \
            ra[j] = *(const float4*)&u [(size_t)(m0 + s_row[j]) * DCH + (kt) + s_f4[j] * 4]; \
            rb[j] = *(const float4*)&pw[(size_t)(n0 + s_row[j]) * DCH + (kt) + s_f4[j] * 4]; \
        }                                                                             \
    }
#define WRITET(base)                                                                  \
    {                                                                                 \
        _Pragma("unroll")                                                             \
        for (int j = 0; j < 4; ++j) {                                                 \
            int off = (base) + ((s_row[j] * 64 + s_f4[j] * 8) ^ ((s_row[j] & 3) << 4)); \
            uint2 pa, pbv2;                                                           \
            pa.x   = pack2bf(ra[j].x, ra[j].y);  pa.y   = pack2bf(ra[j].z, ra[j].w);  \
            pbv2.x = pack2bf(rb[j].x, rb[j].y);  pbv2.y = pack2bf(rb[j].z, rb[j].w);  \
            *(uint2*)(lds_raw + off)        = pa;                                     \
            *(uint2*)(lds_raw + off + 8192) = pbv2;                                   \
        }                                                                             \
    }
    LOADT(0);
    WRITET(0);
    LOADT(32);
    __syncthreads();
    for (int t = 0; t < 32; ++t) {
        const int cur = (t & 1) << 14;
        short8 af[4], bfr[4];
#pragma unroll
        for (int f = 0; f < 4; ++f) {
            int rowA = wr * 64 + f * 16 + (lane & 15);
            int rowB = wc * 64 + f * 16 + (lane & 15);
            int offA = cur + ((rowA * 64 + ((lane >> 4) * 16)) ^ ((rowA & 3) << 4));
            int offB = cur + 8192 + ((rowB * 64 + ((lane >> 4) * 16)) ^ ((rowB & 3) << 4));
            af[f]  = *(short8*)(lds_raw + offA);
            bfr[f] = *(short8*)(lds_raw + offB);
        }
        if (t < 31) WRITET(cur ^ 16384);
        if (t < 30) LOADT((t + 2) * 32);
#pragma unroll
        for (int mf = 0; mf < 4; ++mf)
#pragma unroll
            for (int nf = 0; nf < 4; ++nf)
                acc[mf][nf] = __builtin_amdgcn_mfma_f32_16x16x32_bf16(
                    af[mf], bfr[nf], acc[mf][nf], 0, 0, 0);
        __syncthreads();
    }
    const int b  = m0 >> 12;
    const int l0 = m0 & (SEQL - 1);
    float pbv[4];
#pragma unroll
    for (int nf = 0; nf < 4; ++nf)
        pbv[nf] = pb[n0 + wc * 64 + nf * 16 + (lane & 15)];
    for (int c = 0; c < 2; ++c) {
        __syncthreads();
#pragma unroll
        for (int j = 0; j < 4; ++j) {
            int idx = j * 256 + tid;
            int dn  = idx >> 3;
            int lg  = idx & 7;
            uint4 w4 = *(const uint4*)&yb[(((size_t)(b * DCH + n0 + dn)) << 13) + l0 + c * 64 + lg * 8];
            int lb = lg * 8;
            ysc[lb+0][dn] = bflo(w4.x); ysc[lb+1][dn] = bfhi(w4.x);
            ysc[lb+2][dn] = bflo(w4.y); ysc[lb+3][dn] = bfhi(w4.y);
            ysc[lb+4][dn] = bflo(w4.z); ysc[lb+5][dn] = bfhi(w4.z);
            ysc[lb+6][dn] = bflo(w4.w); ysc[lb+7][dn] = bfhi(w4.w);
        }
        __syncthreads();
        if (wr == c) {
#pragma unroll
            for (int mf = 0; mf < 4; ++mf)
#pragma unroll
                for (int i = 0; i < 4; ++i) {
                    int lrow = mf * 16 + (lane >> 4) * 4 + i;
                    int m = m0 + c * 64 + lrow;
#pragma unroll
                    for (int nf = 0; nf < 4; ++nf) {
                        int nl = wc * 64 + nf * 16 + (lane & 15);
                        int n = n0 + nl;
                        float proj = acc[mf][nf][i] + pbv[nf];
                        out[(size_t)m * DCH + n] = ysc[lrow][nl] * proj + u[(size_t)m * DCH + n];
                    }
                }
        }
    }
#undef LOADT
#undef WRITET
}

extern "C" void kernel_launch(void* const* d_in, const int* in_sizes, int n_in,
                              void* d_out, int out_size, void* d_ws, size_t ws_size,
                              hipStream_t stream) {
    const float* u  = (const float*)d_in[0];
    const float* z  = (const float*)d_in[1];
    const float* w1 = (const float*)d_in[2];
    const float* b1 = (const float*)d_in[3];
    const float* w2 = (const float*)d_in[4];
    const float* b2 = (const float*)d_in[5];
    const float* pw = (const float*)d_in[6];
    const float* pb = (const float*)d_in[7];
    float* out = (float*)d_out;

    float* h   = (float*)d_ws;                           // 256 KB
    float* uty = (float*)((char*)d_ws + 262144);         // 64 MB (ut f32; y bf16 in-place per row)
    cf* kf = (cf*)d_out;                                 // 33.5 MB scratch (overwritten by gemm)

    // big-ws extras: ub (32 MB), pwb (2 MB), twiddles (64 KB) in the ws tail
    const size_t ub_off  = 262144 + (size_t)BATCH * DCH * SEQL * sizeof(float);
    const size_t pwb_off = ub_off + (size_t)BATCH * SEQL * DCH * sizeof(unsigned short);
    const size_t tw_off  = pwb_off + (size_t)DCH * DCH * sizeof(unsigned short);
    const size_t need    = tw_off + 2 * 4096 * sizeof(cf);
    const bool   big     = ws_size >= need;

    cf* tw4 = big ? (cf*)((char*)d_ws + tw_off) : (cf*)((char*)d_out + (40u << 20));
    cf* tw8 = tw4 + 4096;
    unsigned short* ub  = big ? (unsigned short*)((char*)d_ws + ub_off)  : (unsigned short*)0;
    unsigned short* pwb = big ? (unsigned short*)((char*)d_ws + pwb_off) : (unsigned short*)0;

    twiddle_init<<<dim3(16), dim3(256), 0, stream>>>(tw4, tw8);
    mlp_kernel<<<dim3(16), dim3(256), 0, stream>>>(z, w1, b1, h);
    transpose_kernel<<<dim3(SEQL / 32, DCH / 32, BATCH), dim3(32, 8), 0, stream>>>(u, uty, ub);
    if (big) pw2bf_kernel<<<dim3(512), dim3(256), 0, stream>>>(pw, pwb);
    filt_fft_kernel<<<dim3(DCH), dim3(256), 0, stream>>>(h, w2, b2, tw4, tw8, kf);
    conv_kernel<<<dim3(BATCH * DCH), dim3(256), 0, stream>>>(uty, tw4, tw8, kf);
    if (big)
        gemm_mfma_v2<<<dim3(128, 8), dim3(256), 0, stream>>>(ub, pwb, pb, (const unsigned short*)uty, out);
    else
        gemm_mfma_fb<<<dim3(128, 8), dim3(256), 0, stream>>>(u, pw, pb, (const unsigned short*)uty, out);
}

// Round 10
// 273.689 us; speedup vs baseline: 1.2649x; 1.0071x over previous
//
#include <hip/hip_runtime.h>
#include <hip/hip_bf16.h>

#define SEQL 4096
#define DCH  1024
#define BATCH 4
#define KH   4097        // stored half-spectrum entries per channel

// packed complex: one VGPR pair, arithmetic maps to VOP3P v_pk_* f32 ops
typedef __attribute__((ext_vector_type(2))) float cf;
__device__ __forceinline__ cf mkc(float x, float y){ cf r; r.x = x; r.y = y; return r; }
__device__ __forceinline__ cf cadd(cf a, cf b){ return a + b; }
__device__ __forceinline__ cf csub(cf a, cf b){ return a - b; }
__device__ __forceinline__ cf cmul(cf a, cf b){ return a.xx * b + mkc(-a.y, a.y) * b.yx; }
__device__ __forceinline__ cf cconjf(cf a){ return mkc(a.x, -a.y); }
__device__ __forceinline__ cf addi(cf a, cf b){ return a + mkc(-b.y, b.x); }  // a + i*b
__device__ __forceinline__ cf subi(cf a, cf b){ return a - mkc(-b.y, b.x); }  // a - i*b
__device__ __forceinline__ int cpad(int i){ return i + (i >> 4); }                   // +1 cplx per 16
__device__ __forceinline__ int drev(int i){                                          // reverse 6 base-4 digits
    return ((i>>10)&3) | (((i>>8)&3)<<2) | (((i>>6)&3)<<4)
         | (((i>>4)&3)<<6) | (((i>>2)&3)<<8) | ((i&3)<<10);
}

// register-stage twiddles (compile-time constants)
__device__ __forceinline__ cf W1c(int j){   // e^{-2*pi*i*j/16}
    const float cs[4] = {1.f, 0.92387953f, 0.70710678f, 0.38268343f};
    const float sn[4] = {0.f, -0.38268343f, -0.70710678f, -0.92387953f};
    return mkc(cs[j], sn[j]);
}
__device__ __forceinline__ cf W2c(int j){   // e^{-2*pi*i*j/8}
    const float cs[4] = {1.f, 0.70710678f, 0.f, -0.70710678f};
    const float sn[4] = {0.f, -0.70710678f, -1.f, -0.70710678f};
    return mkc(cs[j], sn[j]);
}
__device__ __forceinline__ cf W3c(int j){   // e^{-2*pi*i*3j/16}
    const float cs[4] = {1.f, 0.38268343f, -0.70710678f, -0.92387953f};
    const float sn[4] = {0.f, -0.92387953f, -0.70710678f, 0.38268343f};
    return mkc(cs[j], sn[j]);
}

__device__ __forceinline__ unsigned pack2bf(float a, float b){
    unsigned r;
    asm("v_cvt_pk_bf16_f32 %0, %1, %2" : "=v"(r) : "v"(a), "v"(b));
    return r;   // lo = bf16(a), hi = bf16(b)
}
__device__ __forceinline__ float bflo(unsigned u){ return __uint_as_float(u << 16); }
__device__ __forceinline__ float bfhi(unsigned u){ return __uint_as_float(u & 0xffff0000u); }

__device__ __forceinline__ void gload16(const void* g, void* l){
    __builtin_amdgcn_global_load_lds((const __attribute__((address_space(1))) void*)g,
                                     (__attribute__((address_space(3))) void*)l, 16, 0, 0);
}

// ---------------- twiddle tables ----------------
__global__ __launch_bounds__(256) void twiddle_init(cf* __restrict__ tw4, cf* __restrict__ tw8){
    int i = blockIdx.x*256 + threadIdx.x;   // 4096 total
    const double TWO_PI = 6.283185307179586476925286766559;
    double a4 = -TWO_PI * (double)i / 4096.0;
    double a8 = -TWO_PI * (double)i / 8192.0;
    tw4[i] = mkc((float)cos(a4), (float)sin(a4));
    tw8[i] = mkc((float)cos(a8), (float)sin(a8));
}

// ---------------- MLP: h[l][16] ----------------
__global__ __launch_bounds__(256) void mlp_kernel(
        const float* __restrict__ z, const float* __restrict__ w1,
        const float* __restrict__ b1, float* __restrict__ h) {
    int l = blockIdx.x * blockDim.x + threadIdx.x;
    if (l >= SEQL) return;
    float pe0 = z[l * 3 + 0], pe1 = z[l * 3 + 1], pe2 = z[l * 3 + 2];
#pragma unroll
    for (int j = 0; j < 16; ++j) {
        float v = pe0 * w1[j * 3 + 0] + pe1 * w1[j * 3 + 1] + pe2 * w1[j * 3 + 2] + b1[j];
        h[l * 16 + j] = v > 0.f ? v : 0.f;
    }
}

// ---------------- transpose u (B,L,D) -> ut (B,D,L), optional ub = bf16(u) ----------------
__global__ __launch_bounds__(256) void transpose_kernel(
        const float* __restrict__ u, float* __restrict__ ut,
        unsigned short* __restrict__ ub) {
    __shared__ float tile[32][33];
    int b = blockIdx.z;
    int l0 = blockIdx.x * 32;
    int d0 = blockIdx.y * 32;
    int tx = threadIdx.x, ty = threadIdx.y;  // 32 x 8
    const float* up = u + (size_t)b * SEQL * DCH;
    unsigned short* ubp = ub ? ub + (size_t)b * SEQL * DCH : (unsigned short*)0;
#pragma unroll
    for (int i = 0; i < 32; i += 8) {
        size_t idx = (size_t)(l0 + ty + i) * DCH + d0 + tx;
        float v = up[idx];
        tile[ty + i][tx] = v;
        if (ub) ubp[idx] = (unsigned short)pack2bf(v, v);
    }
    __syncthreads();
    float* utp = ut + (size_t)b * DCH * SEQL;
#pragma unroll
    for (int i = 0; i < 32; i += 8)
        utp[(size_t)(d0 + ty + i) * SEQL + l0 + tx] = tile[tx][ty + i];
}

// ---------------- pw -> bf16 ----------------
__global__ __launch_bounds__(256) void pw2bf_kernel(
        const float* __restrict__ pw, unsigned short* __restrict__ pwb) {
    int t = blockIdx.x * 256 + threadIdx.x;
    float4 a = *(const float4*)&pw[(size_t)t * 8];
    float4 b = *(const float4*)&pw[(size_t)t * 8 + 4];
    uint4 o;
    o.x = pack2bf(a.x, a.y); o.y = pack2bf(a.z, a.w);
    o.z = pack2bf(b.x, b.y); o.w = pack2bf(b.z, b.w);
    *(uint4*)&pwb[(size_t)t * 8] = o;
}

// ---- shared middle DIF passes (m=256,64,16), fwd chunk pass (m=4,m=1) ----
__device__ void dif_mid_and_chunk(cf* lds, const cf* __restrict__ tw){
    const int tid = threadIdx.x;
#pragma unroll
    for (int p = 1; p < 4; ++p) {
        const int lm = 10 - 2*p;          // 8,6,4
        const int m  = 1 << lm;
        const int step = 1024 >> lm;
#pragma unroll
        for (int it = 0; it < 4; ++it) {
            int j = tid + (it << 8);
            int k = j & (m-1);
            int g = j >> lm;
            int i0 = (g << (lm+2)) + k;
            cf x0 = lds[cpad(i0)];
            cf x1 = lds[cpad(i0+m)];
            cf x2 = lds[cpad(i0+2*m)];
            cf x3 = lds[cpad(i0+3*m)];
            cf b0 = cadd(x0,x2), b1 = csub(x0,x2);
            cf b2 = cadd(x1,x3), b3 = csub(x1,x3);
            cf u0 = cadd(b0,b2);
            cf u2 = csub(b0,b2);
            cf u1 = subi(b1,b3);
            cf u3 = addi(b1,b3);
            int t1 = k*step;
            lds[cpad(i0)]     = u0;
            lds[cpad(i0+m)]   = cmul(u1, tw[t1]);
            lds[cpad(i0+2*m)] = cmul(u2, tw[2*t1]);
            lds[cpad(i0+3*m)] = cmul(u3, tw[3*t1]);
        }
        __syncthreads();
    }
    {
        int base = 17*tid;
        cf v[16];
#pragma unroll
        for (int j=0;j<16;++j) v[j] = lds[base+j];
#pragma unroll
        for (int j=0;j<4;++j){
            cf x0=v[j], x1=v[j+4], x2=v[j+8], x3=v[j+12];
            cf b0=cadd(x0,x2), b1=csub(x0,x2), b2=cadd(x1,x3), b3=csub(x1,x3);
            cf u0=cadd(b0,b2), u2=csub(b0,b2), u1=subi(b1,b3), u3=addi(b1,b3);
            v[j]    = u0;
            v[j+4]  = cmul(u1, W1c(j));
            v[j+8]  = cmul(u2, W2c(j));
            v[j+12] = cmul(u3, W3c(j));
        }
#pragma unroll
        for (int c=0;c<4;++c){
            cf x0=v[4*c], x1=v[4*c+1], x2=v[4*c+2], x3=v[4*c+3];
            cf b0=cadd(x0,x2), b1=csub(x0,x2), b2=cadd(x1,x3), b3=csub(x1,x3);
            v[4*c]   = cadd(b0,b2);
            v[4*c+1] = subi(b1,b3);
            v[4*c+2] = csub(b0,b2);
            v[4*c+3] = addi(b1,b3);
        }
#pragma unroll
        for (int j=0;j<16;++j) lds[base+j] = v[j];
        __syncthreads();
    }
}

// ---- inverse: chunk pass (m=1,m=4) + middle DIT passes (m=16,64,256) ----
__device__ void dit_chunk_and_mid(cf* lds, const cf* __restrict__ tw){
    const int tid = threadIdx.x;
    {
        int base = 17*tid;
        cf v[16];
#pragma unroll
        for (int j=0;j<16;++j) v[j] = lds[base+j];
#pragma unroll
        for (int c=0;c<4;++c){
            cf a0=v[4*c], a1=v[4*c+1], a2=v[4*c+2], a3=v[4*c+3];
            cf b0=cadd(a0,a2), b1=csub(a0,a2), b2=cadd(a1,a3), b3=csub(a1,a3);
            v[4*c]   = cadd(b0,b2);
            v[4*c+1] = addi(b1,b3);
            v[4*c+2] = csub(b0,b2);
            v[4*c+3] = subi(b1,b3);
        }
#pragma unroll
        for (int j=0;j<4;++j){
            cf a0=v[j];
            cf a1=cmul(v[j+4],  cconjf(W1c(j)));
            cf a2=cmul(v[j+8],  cconjf(W2c(j)));
            cf a3=cmul(v[j+12], cconjf(W3c(j)));
            cf b0=cadd(a0,a2), b1=csub(a0,a2), b2=cadd(a1,a3), b3=csub(a1,a3);
            v[j]    = cadd(b0,b2);
            v[j+4]  = addi(b1,b3);
            v[j+8]  = csub(b0,b2);
            v[j+12] = subi(b1,b3);
        }
#pragma unroll
        for (int j=0;j<16;++j) lds[base+j] = v[j];
        __syncthreads();
    }
#pragma unroll
    for (int p = 0; p < 3; ++p) {
        const int lm = 4 + 2*p;           // 16,64,256
        const int m  = 1 << lm;
        const int step = 1024 >> lm;
#pragma unroll
        for (int it = 0; it < 4; ++it) {
            int j = tid + (it << 8);
            int k = j & (m-1);
            int g = j >> lm;
            int i0 = (g << (lm+2)) + k;
            int t1 = k*step;
            cf a0 = lds[cpad(i0)];
            cf a1 = cmul(lds[cpad(i0+m)],   cconjf(tw[t1]));
            cf a2 = cmul(lds[cpad(i0+2*m)], cconjf(tw[2*t1]));
            cf a3 = cmul(lds[cpad(i0+3*m)], cconjf(tw[3*t1]));
            cf b0=cadd(a0,a2), b1=csub(a0,a2), b2=cadd(a1,a3), b3=csub(a1,a3);
            lds[cpad(i0)]     = cadd(b0,b2);
            lds[cpad(i0+m)]   = addi(b1,b3);
            lds[cpad(i0+2*m)] = csub(b0,b2);
            lds[cpad(i0+3*m)] = subi(b1,b3);
        }
        __syncthreads();
    }
}

// ---------------- filter row -> packed FFT -> H[d][0..4096] (scaled 1/8192) ----------------
__global__ __launch_bounds__(256) void filt_fft_kernel(
        const float* __restrict__ h, const float* __restrict__ w2,
        const float* __restrict__ b2, const cf* __restrict__ tw4,
        const cf* __restrict__ tw8, cf* __restrict__ kf) {
    __shared__ cf lds[4352];
    const int d = blockIdx.x;
    const int tid = threadIdx.x;
    float wv[16];
#pragma unroll
    for (int j = 0; j < 16; ++j) wv[j] = w2[d * 16 + j];
    const float bb = b2[d];
#pragma unroll
    for (int it = 0; it < 4; ++it) {
        int j = tid + (it << 8);
        const float* h0 = h + (size_t)(2*j) * 16;
        const float* h1 = h + (size_t)(2*(j+1024)) * 16;
        float f0 = bb, f1 = bb, f2 = bb, f3 = bb;
#pragma unroll
        for (int i = 0; i < 16; ++i) {
            f0 += h0[i] * wv[i];  f1 += h0[16+i] * wv[i];
            f2 += h1[i] * wv[i];  f3 += h1[16+i] * wv[i];
        }
        cf x0 = mkc(f0, f1), x1 = mkc(f2, f3);
        cf u0 = cadd(x0,x1);
        cf u2 = csub(x0,x1);
        cf u1 = subi(x0,x1);
        cf u3 = addi(x0,x1);
        lds[cpad(j)]      = u0;
        lds[cpad(j+1024)] = cmul(u1, tw4[j]);
        lds[cpad(j+2048)] = cmul(u2, tw4[2*j]);
        lds[cpad(j+3072)] = cmul(u3, tw4[3*j]);
    }
    __syncthreads();
    dif_mid_and_chunk(lds, tw4);
    const float s = 1.f / 8192.f;
    cf* Hrow = kf + (size_t)d * KH;
    const int lane  = tid & 63;
    const int kbase = ((lane & 31) << 6) | ((lane >> 5) << 5) | ((tid >> 6) << 3);
#pragma unroll
    for (int it = 0; it < 8; ++it) {
        int k = kbase + it;
        if (k == 0) {
            cf c0 = lds[cpad(0)];
            Hrow[0]    = mkc((c0.x + c0.y) * s, 0.f);
            Hrow[4096] = mkc((c0.x - c0.y) * s, 0.f);
            cf c2 = lds[cpad(drev(2048))];
            Hrow[2048] = mkc(c2.x * s, -c2.y * s);
        } else {
            int kk = 4096 - k;
            cf ck  = lds[cpad(drev(k))];
            cf ckk = lds[cpad(drev(kk))];
            cf cc = cconjf(ckk);
            cf E  = (ck + cc) * 0.5f;
            cf Dd = csub(ck, cc);
            cf O  = mkc(Dd.y, -Dd.x) * 0.5f;
            cf wvv = tw8[k];
            cf Xk  = cadd(E, cmul(wvv, O));
            cf wp  = mkc(-wvv.x, wvv.y);
            cf Xkk = cadd(cconjf(E), cmul(wp, cconjf(O)));
            Hrow[k]  = Xk * s;
            Hrow[kk] = Xkk * s;
        }
    }
}

// ---------------- conv: packed fwd FFT -> spectral multiply -> packed inv FFT -> bf16 y ----------------
__global__ __launch_bounds__(256) void conv_kernel(
        float* __restrict__ uty, const cf* __restrict__ tw4,
        const cf* __restrict__ tw8, const cf* __restrict__ kf) {
    __shared__ cf lds[4352];
    const int row = blockIdx.x;            // b*DCH + d
    const int d = row & (DCH - 1);
    const int tid = threadIdx.x;
    float* rp = uty + (size_t)row * SEQL;
#pragma unroll
    for (int it = 0; it < 4; ++it) {
        int j = tid + (it << 8);
        cf x0 = *(const cf*)&rp[2*j];
        cf x1 = *(const cf*)&rp[2*(j+1024)];
        cf u0 = cadd(x0,x1);
        cf u2 = csub(x0,x1);
        cf u1 = subi(x0,x1);
        cf u3 = addi(x0,x1);
        lds[cpad(j)]      = u0;
        lds[cpad(j+1024)] = cmul(u1, tw4[j]);
        lds[cpad(j+2048)] = cmul(u2, tw4[2*j]);
        lds[cpad(j+3072)] = cmul(u3, tw4[3*j]);
    }
    __syncthreads();
    dif_mid_and_chunk(lds, tw4);
    const cf* Hrow = kf + (size_t)d * KH;
    {
        const int lane  = tid & 63;
        const int kbase = ((lane & 31) << 6) | ((lane >> 5) << 5) | ((tid >> 6) << 3);
#pragma unroll
        for (int it = 0; it < 8; ++it) {
            int k = kbase + it;
            if (k == 0) {
                cf c0 = lds[cpad(0)];
                float X0 = c0.x + c0.y, X4 = c0.x - c0.y;
                cf H0 = Hrow[0], H4 = Hrow[4096];
                cf Y0 = H0 * X0;
                cf Y4 = H4 * X4;
                cf S  = cadd(Y0, Y4), Dd = csub(Y0, Y4);
                lds[cpad(0)] = addi(S, Dd);
                int s2 = cpad(drev(2048));
                cf c2 = lds[s2];
                cf Y2 = cmul(cconjf(c2), Hrow[2048]);
                lds[s2] = mkc(2.f * Y2.x, -2.f * Y2.y);
            } else {
                int kk = 4096 - k;
                int sk = cpad(drev(k)), skk = cpad(drev(kk));
                cf ck = lds[sk], ckk = lds[skk];
                cf cc = cconjf(ckk);
                cf E  = (ck + cc) * 0.5f;
                cf Dd = csub(ck, cc);
                cf O  = mkc(Dd.y, -Dd.x) * 0.5f;
                cf wv = tw8[k];
                cf Xk  = cadd(E, cmul(wv, O));
                cf wp  = mkc(-wv.x, wv.y);
                cf Xkk = cadd(cconjf(E), cmul(wp, cconjf(O)));
                cf Yk  = cmul(Xk,  Hrow[k]);
                cf Ykk = cmul(Xkk, Hrow[kk]);
                cf cy = cconjf(Ykk);
                cf S  = cadd(Yk, cy), D2 = csub(Yk, cy);
                cf Zk = addi(S, cmul(cconjf(wv), D2));
                cf cy2 = cconjf(Yk);
                cf S2  = cadd(Ykk, cy2), D3 = csub(Ykk, cy2);
                cf Zkk = subi(S2, cmul(wv, D3));
                lds[sk] = Zk; lds[skk] = Zkk;
            }
        }
    }
    __syncthreads();
    dit_chunk_and_mid(lds, tw4);
    unsigned short* yb = (unsigned short*)rp;
#pragma unroll
    for (int it = 0; it < 4; ++it) {
        int j = tid + (it << 8);
        cf a0 = lds[cpad(j)];
        cf a1 = cmul(lds[cpad(j+1024)], cconjf(tw4[j]));
        cf a2 = cmul(lds[cpad(j+2048)], cconjf(tw4[2*j]));
        cf a3 = cmul(lds[cpad(j+3072)], cconjf(tw4[3*j]));
        cf b0 = cadd(a0,a2), b1 = csub(a0,a2);
        cf b2 = cadd(a1,a3), b3 = csub(a1,a3);
        cf o0 = cadd(b0,b2);
        cf o1 = addi(b1,b3);
        *(unsigned*)&yb[2*j]          = pack2bf(o0.x, o0.y);
        *(unsigned*)&yb[2*(j+1024)]   = pack2bf(o1.x, o1.y);
    }
}

typedef __attribute__((ext_vector_type(8))) short short8;
typedef __attribute__((ext_vector_type(4))) float f32x4;

// ---------------- gemm v2: global_load_lds from bf16 ub/pwb ----------------
__global__ __launch_bounds__(256, 4) void gemm_mfma_v2(
        const unsigned short* __restrict__ ub, const unsigned short* __restrict__ pwb,
        const float* __restrict__ pb, const unsigned short* __restrict__ yb,
        float* __restrict__ out) {
    __shared__ char lds_raw[34816];          // dbuf: A@0/B@8192, A@16384/B@24576; epilogue ysc overlay
    float (*ysc)[132] = (float(*)[132])lds_raw;

    const int tid  = threadIdx.x;
    const int lane = tid & 63;
    const int wid  = tid >> 6;
    const int wr   = wid >> 1;
    const int wc   = wid & 1;
    const int m0   = blockIdx.x * 128;       // m-major grid: n-blocks of same m share an XCD
    const int n0   = blockIdx.y * 128;

    f32x4 acc[4][4] = {};

    const int srow = lane >> 2;
    const int scol = 16 * ((lane & 3) ^ ((lane >> 2) & 3));   // inverse-swizzled source col

#define STAGE2(bufbase, kt)                                                                   \
    {                                                                                         \
        _Pragma("unroll")                                                                     \
        for (int i = 0; i < 2; ++i) {                                                         \
            int c = wid * 2 + i;                                                              \
            const char* gA = (const char*)ub  + (size_t)(m0 + c * 16 + srow) * 2048 + (kt) * 2 + scol; \
            const char* gB = (const char*)pwb + (size_t)(n0 + c * 16 + srow) * 2048 + (kt) * 2 + scol; \
            gload16(gA, lds_raw + (bufbase) + c * 1024);                                      \
            gload16(gB, lds_raw + (bufbase) + 8192 + c * 1024);                               \
        }                                                                                     \
    }

    STAGE2(0, 0);
    __syncthreads();

    for (int t = 0; t < 32; ++t) {
        const int cur = (t & 1) << 14;
        if (t < 31) STAGE2(cur ^ 16384, (t + 1) * 32);
        short8 af[4], bfr[4];
#pragma unroll
        for (int f = 0; f < 4; ++f) {
            int rowA = wr * 64 + f * 16 + (lane & 15);
            int rowB = wc * 64 + f * 16 + (lane & 15);
            int offA = cur + rowA * 64 + (((lane >> 4) * 16) ^ ((rowA & 3) << 4));
            int offB = cur + 8192 + rowB * 64 + (((lane >> 4) * 16) ^ ((rowB & 3) << 4));
            af[f]  = *(short8*)(lds_raw + offA);
            bfr[f] = *(short8*)(lds_raw + offB);
        }
#pragma unroll
        for (int mf = 0; mf < 4; ++mf)
#pragma unroll
            for (int nf = 0; nf < 4; ++nf)
                acc[mf][nf] = __builtin_amdgcn_mfma_f32_16x16x32_bf16(
                    af[mf], bfr[nf], acc[mf][nf], 0, 0, 0);
        __syncthreads();
    }

    const int b  = m0 >> 12;
    const int l0 = m0 & (SEQL - 1);
    float pbv[4];
#pragma unroll
    for (int nf = 0; nf < 4; ++nf)
        pbv[nf] = pb[n0 + wc * 64 + nf * 16 + (lane & 15)];

    for (int c = 0; c < 2; ++c) {
        __syncthreads();
#pragma unroll
        for (int j = 0; j < 4; ++j) {
            int idx = j * 256 + tid;
            int dn  = idx >> 3;
            int lg  = idx & 7;
            uint4 w4 = *(const uint4*)&yb[(((size_t)(b * DCH + n0 + dn)) << 13) + l0 + c * 64 + lg * 8];
            int lb = lg * 8;
            ysc[lb+0][dn] = bflo(w4.x); ysc[lb+1][dn] = bfhi(w4.x);
            ysc[lb+2][dn] = bflo(w4.y); ysc[lb+3][dn] = bfhi(w4.y);
            ysc[lb+4][dn] = bflo(w4.z); ysc[lb+5][dn] = bfhi(w4.z);
            ysc[lb+6][dn] = bflo(w4.w); ysc[lb+7][dn] = bfhi(w4.w);
        }
        __syncthreads();
        if (wr == c) {
#pragma unroll
            for (int mf = 0; mf < 4; ++mf)
#pragma unroll
                for (int i = 0; i < 4; ++i) {
                    int lrow = mf * 16 + (lane >> 4) * 4 + i;
                    int m = m0 + c * 64 + lrow;
#pragma unroll
                    for (int nf = 0; nf < 4; ++nf) {
                        int nl = wc * 64 + nf * 16 + (lane & 15);
                        int n = n0 + nl;
                        float proj = acc[mf][nf][i] + pbv[nf];
                        float ures = __uint_as_float((unsigned)ub[(size_t)m * DCH + n] << 16);
                        out[(size_t)m * DCH + n] = ysc[lrow][nl] * proj + ures;
                    }
                }
        }
    }
#undef STAGE2
}

// ---------------- gemm fallback (reg-staged): used when ws too small ----------------
__global__ __launch_bounds__(256, 3) void gemm_mfma_fb(
        const float* __restrict__ u, const float* __restrict__ pw,
        const float* __restrict__ pb, const unsigned short* __restrict__ yb,
        float* __restrict__ out) {
    __shared__ char lds_raw[34816];
    float (*ysc)[132] = (float(*)[132])lds_raw;
    const int tid  = threadIdx.x;
    const int lane = tid & 63;
    const int wid  = tid >> 6;
    const int wr   = wid >> 1;
    const int wc   = wid & 1;
    const int m0   = blockIdx.x * 128;
    const int n0   = blockIdx.y * 128;
    f32x4 acc[4][4] = {};
    float4 ra[4], rb[4];
    int s_row[4], s_f4[4];
#pragma unroll
    for (int j = 0; j < 4; ++j) {
        int idx = j * 256 + tid;
        s_row[j] = idx >> 3;
        s_f4[j]  = idx & 7;
    }
#define LOADT(kt)                                                                     \
    {                                                                                 \
        _Pragma("unroll")                                                             \
        for (int j = 0; j < 4; ++j) {                                                 \
            ra[j] = *(const float4*)&u [(size_t)(m0 + s_row[j]) * DCH + (kt) + s_f4[j] * 4]; \
            rb[j] = *(const float4*)&pw[(size_t)(n0 + s_row[j]) * DCH + (kt) + s_f4[j] * 4]; \
        }                                                                             \
    }
#define WRITET(base)                                                                  \
    {                                                                                 \
        _Pragma("unroll")                                                             \
        for (int j = 0; j < 4; ++j) {                                                 \
            int off = (base) + ((s_row[j] * 64 + s_f4[j] * 8) ^ ((s_row[j] & 3) << 4)); \
            uint2 pa, pbv2;                                                           \
            pa.x   = pack2bf(ra[j].x, ra[j].y);  pa.y   = pack2bf(ra[j].z, ra[j].w);  \
            pbv2.x = pack2bf(rb[j].x, rb[j].y);  pbv2.y = pack2bf(rb[j].z, rb[j].w);  \
            *(uint2*)(lds_raw + off)        = pa;                                     \
            *(uint2*)(lds_raw + off + 8192) = pbv2;                                   \
        }                                                                             \
    }
    LOADT(0);
    WRITET(0);
    LOADT(32);
    __syncthreads();
    for (int t = 0; t < 32; ++t) {
        const int cur = (t & 1) << 14;
        short8 af[4], bfr[4];
#pragma unroll
        for (int f = 0; f < 4; ++f) {
            int rowA = wr * 64 + f * 16 + (lane & 15);
            int rowB = wc * 64 + f * 16 + (lane & 15);
            int offA = cur + ((rowA * 64 + ((lane >> 4) * 16)) ^ ((rowA & 3) << 4));
            int offB = cur + 8192 + ((rowB * 64 + ((lane >> 4) * 16)) ^ ((rowB & 3) << 4));
            af[f]  = *(short8*)(lds_raw + offA);
            bfr[f] = *(short8*)(lds_raw + offB);
        }
        if (t < 31) WRITET(cur ^ 16384);
        if (t < 30) LOADT((t + 2) * 32);
#pragma unroll
        for (int mf = 0; mf < 4; ++mf)
#pragma unroll
            for (int nf = 0; nf < 4; ++nf)
                acc[mf][nf] = __builtin_amdgcn_mfma_f32_16x16x32_bf16(
                    af[mf], bfr[nf], acc[mf][nf], 0, 0, 0);
        __syncthreads();
    }
    const int b  = m0 >> 12;
    const int l0 = m0 & (SEQL - 1);
    float pbv[4];
#pragma unroll
    for (int nf = 0; nf < 4; ++nf)
        pbv[nf] = pb[n0 + wc * 64 + nf * 16 + (lane & 15)];
    for (int c = 0; c < 2; ++c) {
        __syncthreads();
#pragma unroll
        for (int j = 0; j < 4; ++j) {
            int idx = j * 256 + tid;
            int dn  = idx >> 3;
            int lg  = idx & 7;
            uint4 w4 = *(const uint4*)&yb[(((size_t)(b * DCH + n0 + dn)) << 13) + l0 + c * 64 + lg * 8];
            int lb = lg * 8;
            ysc[lb+0][dn] = bflo(w4.x); ysc[lb+1][dn] = bfhi(w4.x);
            ysc[lb+2][dn] = bflo(w4.y); ysc[lb+3][dn] = bfhi(w4.y);
            ysc[lb+4][dn] = bflo(w4.z); ysc[lb+5][dn] = bfhi(w4.z);
            ysc[lb+6][dn] = bflo(w4.w); ysc[lb+7][dn] = bfhi(w4.w);
        }
        __syncthreads();
        if (wr == c) {
#pragma unroll
            for (int mf = 0; mf < 4; ++mf)
#pragma unroll
                for (int i = 0; i < 4; ++i) {
                    int lrow = mf * 16 + (lane >> 4) * 4 + i;
                    int m = m0 + c * 64 + lrow;
#pragma unroll
                    for (int nf = 0; nf < 4; ++nf) {
                        int nl = wc * 64 + nf * 16 + (lane & 15);
                        int n = n0 + nl;
                        float proj = acc[mf][nf][i] + pbv[nf];
                        out[(size_t)m * DCH + n] = ysc[lrow][nl] * proj + u[(size_t)m * DCH + n];
                    }
                }
        }
    }
#undef LOADT
#undef WRITET
}

extern "C" void kernel_launch(void* const* d_in, const int* in_sizes, int n_in,
                              void* d_out, int out_size, void* d_ws, size_t ws_size,
                              hipStream_t stream) {
    const float* u  = (const float*)d_in[0];
    const float* z  = (const float*)d_in[1];
    const float* w1 = (const float*)d_in[2];
    const float* b1 = (const float*)d_in[3];
    const float* w2 = (const float*)d_in[4];
    const float* b2 = (const float*)d_in[5];
    const float* pw = (const float*)d_in[6];
    const float* pb = (const float*)d_in[7];
    float* out = (float*)d_out;

    float* h   = (float*)d_ws;                           // 256 KB
    float* uty = (float*)((char*)d_ws + 262144);         // 64 MB (ut f32; y bf16 in-place per row)
    cf* kf = (cf*)d_out;                                 // 33.5 MB scratch (overwritten by gemm)

    const size_t ub_off  = 262144 + (size_t)BATCH * DCH * SEQL * sizeof(float);
    const size_t pwb_off = ub_off + (size_t)BATCH * SEQL * DCH * sizeof(unsigned short);
    const size_t tw_off  = pwb_off + (size_t)DCH * DCH * sizeof(unsigned short);
    const size_t need    = tw_off + 2 * 4096 * sizeof(cf);
    const bool   big     = ws_size >= need;

    cf* tw4 = big ? (cf*)((char*)d_ws + tw_off) : (cf*)((char*)d_out + (40u << 20));
    cf* tw8 = tw4 + 4096;
    unsigned short* ub  = big ? (unsigned short*)((char*)d_ws + ub_off)  : (unsigned short*)0;
    unsigned short* pwb = big ? (unsigned short*)((char*)d_ws + pwb_off) : (unsigned short*)0;

    twiddle_init<<<dim3(16), dim3(256), 0, stream>>>(tw4, tw8);
    mlp_kernel<<<dim3(16), dim3(256), 0, stream>>>(z, w1, b1, h);
    transpose_kernel<<<dim3(SEQL / 32, DCH / 32, BATCH), dim3(32, 8), 0, stream>>>(u, uty, ub);
    if (big) pw2bf_kernel<<<dim3(512), dim3(256), 0, stream>>>(pw, pwb);
    filt_fft_kernel<<<dim3(DCH), dim3(256), 0, stream>>>(h, w2, b2, tw4, tw8, kf);
    conv_kernel<<<dim3(BATCH * DCH), dim3(256), 0, stream>>>(uty, tw4, tw8, kf);
    if (big)
        gemm_mfma_v2<<<dim3(128, 8), dim3(256), 0, stream>>>(ub, pwb, pb, (const unsigned short*)uty, out);
    else
        gemm_mfma_fb<<<dim3(128, 8), dim3(256), 0, stream>>>(u, pw, pb, (const unsigned short*)uty, out);
}

// Round 11
// 266.405 us; speedup vs baseline: 1.2995x; 1.0273x over previous
//
#include <hip/hip_runtime.h>
#include <hip/hip_bf16.h>

#define SEQL 4096
#define DCH  1024
#define BATCH 4
#define KH   4097        // stored half-spectrum entries per channel

// packed complex: one VGPR pair
typedef __attribute__((ext_vector_type(2))) float cf;
__device__ __forceinline__ cf mkc(float x, float y){ cf r; r.x = x; r.y = y; return r; }
__device__ __forceinline__ cf cadd(cf a, cf b){ return a + b; }
__device__ __forceinline__ cf csub(cf a, cf b){ return a - b; }
__device__ __forceinline__ cf cmul(cf a, cf b){ return a.xx * b + mkc(-a.y, a.y) * b.yx; }
__device__ __forceinline__ cf cconjf(cf a){ return mkc(a.x, -a.y); }
__device__ __forceinline__ cf addi(cf a, cf b){ return a + mkc(-b.y, b.x); }  // a + i*b
__device__ __forceinline__ cf subi(cf a, cf b){ return a - mkc(-b.y, b.x); }  // a - i*b
// LDS index swizzle: XOR high nibble into low nibble (bijective; replaces +1/16 pad,
// keeps uniform 4-lanes-per-bank-pair for all FFT passes; LDS stays exactly 32 KiB)
__device__ __forceinline__ int phi(int c){ return c ^ ((c >> 4) & 15); }
__device__ __forceinline__ int drev(int i){                                          // reverse 6 base-4 digits
    return ((i>>10)&3) | (((i>>8)&3)<<2) | (((i>>6)&3)<<4)
         | (((i>>4)&3)<<6) | (((i>>2)&3)<<8) | ((i&3)<<10);
}

// register-stage twiddles (compile-time constants)
__device__ __forceinline__ cf W1c(int j){   // e^{-2*pi*i*j/16}
    const float cs[4] = {1.f, 0.92387953f, 0.70710678f, 0.38268343f};
    const float sn[4] = {0.f, -0.38268343f, -0.70710678f, -0.92387953f};
    return mkc(cs[j], sn[j]);
}
__device__ __forceinline__ cf W2c(int j){   // e^{-2*pi*i*j/8}
    const float cs[4] = {1.f, 0.70710678f, 0.f, -0.70710678f};
    const float sn[4] = {0.f, -0.70710678f, -1.f, -0.70710678f};
    return mkc(cs[j], sn[j]);
}
__device__ __forceinline__ cf W3c(int j){   // e^{-2*pi*i*3j/16}
    const float cs[4] = {1.f, 0.38268343f, -0.70710678f, -0.92387953f};
    const float sn[4] = {0.f, -0.92387953f, -0.70710678f, 0.38268343f};
    return mkc(cs[j], sn[j]);
}

__device__ __forceinline__ unsigned pack2bf(float a, float b){
    unsigned r;
    asm("v_cvt_pk_bf16_f32 %0, %1, %2" : "=v"(r) : "v"(a), "v"(b));
    return r;   // lo = bf16(a), hi = bf16(b)
}
__device__ __forceinline__ float bflo(unsigned u){ return __uint_as_float(u << 16); }
__device__ __forceinline__ float bfhi(unsigned u){ return __uint_as_float(u & 0xffff0000u); }

__device__ __forceinline__ void gload16(const void* g, void* l){
    __builtin_amdgcn_global_load_lds((const __attribute__((address_space(1))) void*)g,
                                     (__attribute__((address_space(3))) void*)l, 16, 0, 0);
}

// ---------------- twiddle tables ----------------
__global__ __launch_bounds__(256) void twiddle_init(cf* __restrict__ tw4, cf* __restrict__ tw8){
    int i = blockIdx.x*256 + threadIdx.x;   // 4096 total
    const double TWO_PI = 6.283185307179586476925286766559;
    double a4 = -TWO_PI * (double)i / 4096.0;
    double a8 = -TWO_PI * (double)i / 8192.0;
    tw4[i] = mkc((float)cos(a4), (float)sin(a4));
    tw8[i] = mkc((float)cos(a8), (float)sin(a8));
}

// ---------------- MLP: h[l][16] ----------------
__global__ __launch_bounds__(256) void mlp_kernel(
        const float* __restrict__ z, const float* __restrict__ w1,
        const float* __restrict__ b1, float* __restrict__ h) {
    int l = blockIdx.x * blockDim.x + threadIdx.x;
    if (l >= SEQL) return;
    float pe0 = z[l * 3 + 0], pe1 = z[l * 3 + 1], pe2 = z[l * 3 + 2];
#pragma unroll
    for (int j = 0; j < 16; ++j) {
        float v = pe0 * w1[j * 3 + 0] + pe1 * w1[j * 3 + 1] + pe2 * w1[j * 3 + 2] + b1[j];
        h[l * 16 + j] = v > 0.f ? v : 0.f;
    }
}

// ---------------- transpose u (B,L,D) -> utb (B,D,L/2 uint of bf16 pairs) + ub = bf16(u) ----------------
__global__ __launch_bounds__(256) void transpose_kernel(
        const float* __restrict__ u, unsigned* __restrict__ utb,
        unsigned short* __restrict__ ub) {
    __shared__ float tile[32][33];
    int b = blockIdx.z;
    int l0 = blockIdx.x * 32;
    int d0 = blockIdx.y * 32;
    int tx = threadIdx.x, ty = threadIdx.y;  // 32 x 8
    const float* up = u + (size_t)b * SEQL * DCH;
    unsigned short* ubp = ub ? ub + (size_t)b * SEQL * DCH : (unsigned short*)0;
#pragma unroll
    for (int i = 0; i < 32; i += 8) {
        size_t idx = (size_t)(l0 + ty + i) * DCH + d0 + tx;
        float v = up[idx];
        tile[ty + i][tx] = v;
        if (ub) ubp[idx] = (unsigned short)pack2bf(v, v);
    }
    __syncthreads();
    unsigned* utp = utb + (size_t)b * DCH * (SEQL / 2);
    int t  = ty * 32 + tx;          // 0..255
    int dl = t >> 4;                // 0..15
    int lp = t & 15;                // l-pair index: l = 2lp, 2lp+1
#pragma unroll
    for (int p = 0; p < 2; ++p) {
        int dd = dl + p * 16;
        unsigned v = pack2bf(tile[2 * lp][dd], tile[2 * lp + 1][dd]);
        utp[(size_t)(d0 + dd) * (SEQL / 2) + (l0 >> 1) + lp] = v;
    }
}

// ---------------- pw -> bf16 ----------------
__global__ __launch_bounds__(256) void pw2bf_kernel(
        const float* __restrict__ pw, unsigned short* __restrict__ pwb) {
    int t = blockIdx.x * 256 + threadIdx.x;
    float4 a = *(const float4*)&pw[(size_t)t * 8];
    float4 b = *(const float4*)&pw[(size_t)t * 8 + 4];
    uint4 o;
    o.x = pack2bf(a.x, a.y); o.y = pack2bf(a.z, a.w);
    o.z = pack2bf(b.x, b.y); o.w = pack2bf(b.z, b.w);
    *(uint4*)&pwb[(size_t)t * 8] = o;
}

// ---- shared middle DIF passes (m=256,64,16), fwd chunk pass (m=4,m=1) ----
__device__ void dif_mid_and_chunk(cf* lds, const cf* __restrict__ tw){
    const int tid = threadIdx.x;
#pragma unroll
    for (int p = 1; p < 4; ++p) {
        const int lm = 10 - 2*p;          // 8,6,4
        const int m  = 1 << lm;
        const int step = 1024 >> lm;
#pragma unroll
        for (int it = 0; it < 4; ++it) {
            int j = tid + (it << 8);
            int k = j & (m-1);
            int g = j >> lm;
            int i0 = (g << (lm+2)) + k;
            cf x0 = lds[phi(i0)];
            cf x1 = lds[phi(i0+m)];
            cf x2 = lds[phi(i0+2*m)];
            cf x3 = lds[phi(i0+3*m)];
            cf b0 = cadd(x0,x2), b1 = csub(x0,x2);
            cf b2 = cadd(x1,x3), b3 = csub(x1,x3);
            cf u0 = cadd(b0,b2);
            cf u2 = csub(b0,b2);
            cf u1 = subi(b1,b3);
            cf u3 = addi(b1,b3);
            int t1 = k*step;
            lds[phi(i0)]     = u0;
            lds[phi(i0+m)]   = cmul(u1, tw[t1]);
            lds[phi(i0+2*m)] = cmul(u2, tw[2*t1]);
            lds[phi(i0+3*m)] = cmul(u3, tw[3*t1]);
        }
        __syncthreads();
    }
    {   // fused m=4 / m=1 register pass; thread owns complexes [16t,16t+16)
        const int b0 = tid << 4;
        const int xr = tid & 15;
        cf v[16];
#pragma unroll
        for (int j=0;j<16;++j) v[j] = lds[b0 + (j ^ xr)];
#pragma unroll
        for (int j=0;j<4;++j){
            cf x0=v[j], x1=v[j+4], x2=v[j+8], x3=v[j+12];
            cf b0v=cadd(x0,x2), b1=csub(x0,x2), b2=cadd(x1,x3), b3=csub(x1,x3);
            cf u0=cadd(b0v,b2), u2=csub(b0v,b2), u1=subi(b1,b3), u3=addi(b1,b3);
            v[j]    = u0;
            v[j+4]  = cmul(u1, W1c(j));
            v[j+8]  = cmul(u2, W2c(j));
            v[j+12] = cmul(u3, W3c(j));
        }
#pragma unroll
        for (int c=0;c<4;++c){
            cf x0=v[4*c], x1=v[4*c+1], x2=v[4*c+2], x3=v[4*c+3];
            cf b0v=cadd(x0,x2), b1=csub(x0,x2), b2=cadd(x1,x3), b3=csub(x1,x3);
            v[4*c]   = cadd(b0v,b2);
            v[4*c+1] = subi(b1,b3);
            v[4*c+2] = csub(b0v,b2);
            v[4*c+3] = addi(b1,b3);
        }
#pragma unroll
        for (int j=0;j<16;++j) lds[b0 + (j ^ xr)] = v[j];
        __syncthreads();
    }
}

// ---- inverse: chunk pass (m=1,m=4) + middle DIT passes (m=16,64,256) ----
__device__ void dit_chunk_and_mid(cf* lds, const cf* __restrict__ tw){
    const int tid = threadIdx.x;
    {
        const int b0 = tid << 4;
        const int xr = tid & 15;
        cf v[16];
#pragma unroll
        for (int j=0;j<16;++j) v[j] = lds[b0 + (j ^ xr)];
#pragma unroll
        for (int c=0;c<4;++c){
            cf a0=v[4*c], a1=v[4*c+1], a2=v[4*c+2], a3=v[4*c+3];
            cf b0v=cadd(a0,a2), b1=csub(a0,a2), b2=cadd(a1,a3), b3=csub(a1,a3);
            v[4*c]   = cadd(b0v,b2);
            v[4*c+1] = addi(b1,b3);
            v[4*c+2] = csub(b0v,b2);
            v[4*c+3] = subi(b1,b3);
        }
#pragma unroll
        for (int j=0;j<4;++j){
            cf a0=v[j];
            cf a1=cmul(v[j+4],  cconjf(W1c(j)));
            cf a2=cmul(v[j+8],  cconjf(W2c(j)));
            cf a3=cmul(v[j+12], cconjf(W3c(j)));
            cf b0v=cadd(a0,a2), b1=csub(a0,a2), b2=cadd(a1,a3), b3=csub(a1,a3);
            v[j]    = cadd(b0v,b2);
            v[j+4]  = addi(b1,b3);
            v[j+8]  = csub(b0v,b2);
            v[j+12] = subi(b1,b3);
        }
#pragma unroll
        for (int j=0;j<16;++j) lds[b0 + (j ^ xr)] = v[j];
        __syncthreads();
    }
#pragma unroll
    for (int p = 0; p < 3; ++p) {
        const int lm = 4 + 2*p;           // 16,64,256
        const int m  = 1 << lm;
        const int step = 1024 >> lm;
#pragma unroll
        for (int it = 0; it < 4; ++it) {
            int j = tid + (it << 8);
            int k = j & (m-1);
            int g = j >> lm;
            int i0 = (g << (lm+2)) + k;
            int t1 = k*step;
            cf a0 = lds[phi(i0)];
            cf a1 = cmul(lds[phi(i0+m)],   cconjf(tw[t1]));
            cf a2 = cmul(lds[phi(i0+2*m)], cconjf(tw[2*t1]));
            cf a3 = cmul(lds[phi(i0+3*m)], cconjf(tw[3*t1]));
            cf b0=cadd(a0,a2), b1=csub(a0,a2), b2=cadd(a1,a3), b3=csub(a1,a3);
            lds[phi(i0)]     = cadd(b0,b2);
            lds[phi(i0+m)]   = addi(b1,b3);
            lds[phi(i0+2*m)] = csub(b0,b2);
            lds[phi(i0+3*m)] = subi(b1,b3);
        }
        __syncthreads();
    }
}

// ---------------- filter row -> packed FFT -> H[d][0..4096] (scaled 1/8192) ----------------
__global__ __launch_bounds__(256) void filt_fft_kernel(
        const float* __restrict__ h, const float* __restrict__ w2,
        const float* __restrict__ b2, const cf* __restrict__ tw4,
        const cf* __restrict__ tw8, cf* __restrict__ kf) {
    __shared__ cf lds[4096];
    const int d = blockIdx.x;
    const int tid = threadIdx.x;
    float wv[16];
#pragma unroll
    for (int j = 0; j < 16; ++j) wv[j] = w2[d * 16 + j];
    const float bb = b2[d];
#pragma unroll
    for (int it = 0; it < 4; ++it) {
        int j = tid + (it << 8);
        const float* h0 = h + (size_t)(2*j) * 16;
        const float* h1 = h + (size_t)(2*(j+1024)) * 16;
        float f0 = bb, f1 = bb, f2 = bb, f3 = bb;
#pragma unroll
        for (int i = 0; i < 16; ++i) {
            f0 += h0[i] * wv[i];  f1 += h0[16+i] * wv[i];
            f2 += h1[i] * wv[i];  f3 += h1[16+i] * wv[i];
        }
        cf x0 = mkc(f0, f1), x1 = mkc(f2, f3);
        cf u0 = cadd(x0,x1);
        cf u2 = csub(x0,x1);
        cf u1 = subi(x0,x1);
        cf u3 = addi(x0,x1);
        lds[phi(j)]      = u0;
        lds[phi(j+1024)] = cmul(u1, tw4[j]);
        lds[phi(j+2048)] = cmul(u2, tw4[2*j]);
        lds[phi(j+3072)] = cmul(u3, tw4[3*j]);
    }
    __syncthreads();
    dif_mid_and_chunk(lds, tw4);
    const float s = 1.f / 8192.f;
    cf* Hrow = kf + (size_t)d * KH;
    const int lane  = tid & 63;
    const int kbase = ((lane & 31) << 6) | ((lane >> 5) << 5) | ((tid >> 6) << 3);
#pragma unroll
    for (int it = 0; it < 8; ++it) {
        int k = kbase + it;
        if (k == 0) {
            cf c0 = lds[0];
            Hrow[0]    = mkc((c0.x + c0.y) * s, 0.f);
            Hrow[4096] = mkc((c0.x - c0.y) * s, 0.f);
            cf c2 = lds[phi(drev(2048))];
            Hrow[2048] = mkc(c2.x * s, -c2.y * s);
        } else {
            int kk = 4096 - k;
            cf ck  = lds[phi(drev(k))];
            cf ckk = lds[phi(drev(kk))];
            cf cc = cconjf(ckk);
            cf E  = (ck + cc) * 0.5f;
            cf Dd = csub(ck, cc);
            cf O  = mkc(Dd.y, -Dd.x) * 0.5f;
            cf wvv = tw8[k];
            cf Xk  = cadd(E, cmul(wvv, O));
            cf wp  = mkc(-wvv.x, wvv.y);
            cf Xkk = cadd(cconjf(E), cmul(wp, cconjf(O)));
            Hrow[k]  = Xk * s;
            Hrow[kk] = Xkk * s;
        }
    }
}

// ---------------- conv: bf16 in -> packed fwd FFT -> multiply -> inv FFT -> bf16 y (in place) ----------------
__global__ __launch_bounds__(256) void conv_kernel(
        unsigned* __restrict__ utyb, const cf* __restrict__ tw4,
        const cf* __restrict__ tw8, const cf* __restrict__ kf) {
    __shared__ cf lds[4096];
    const int row = blockIdx.x;            // b*DCH + d
    const int d = row & (DCH - 1);
    const int tid = threadIdx.x;
    unsigned* rp = utyb + (size_t)row * (SEQL / 2);
#pragma unroll
    for (int it = 0; it < 4; ++it) {
        int j = tid + (it << 8);
        unsigned q0 = rp[j], q1 = rp[j + 1024];
        cf x0 = mkc(bflo(q0), bfhi(q0));
        cf x1 = mkc(bflo(q1), bfhi(q1));
        cf u0 = cadd(x0,x1);
        cf u2 = csub(x0,x1);
        cf u1 = subi(x0,x1);
        cf u3 = addi(x0,x1);
        lds[phi(j)]      = u0;
        lds[phi(j+1024)] = cmul(u1, tw4[j]);
        lds[phi(j+2048)] = cmul(u2, tw4[2*j]);
        lds[phi(j+3072)] = cmul(u3, tw4[3*j]);
    }
    __syncthreads();
    dif_mid_and_chunk(lds, tw4);
    const cf* Hrow = kf + (size_t)d * KH;
    {
        const int lane  = tid & 63;
        const int kbase = ((lane & 31) << 6) | ((lane >> 5) << 5) | ((tid >> 6) << 3);
#pragma unroll
        for (int it = 0; it < 8; ++it) {
            int k = kbase + it;
            if (k == 0) {
                cf c0 = lds[0];
                float X0 = c0.x + c0.y, X4 = c0.x - c0.y;
                cf H0 = Hrow[0], H4 = Hrow[4096];
                cf Y0 = H0 * X0;
                cf Y4 = H4 * X4;
                cf S  = cadd(Y0, Y4), Dd = csub(Y0, Y4);
                lds[0] = addi(S, Dd);
                int s2 = phi(drev(2048));
                cf c2 = lds[s2];
                cf Y2 = cmul(cconjf(c2), Hrow[2048]);
                lds[s2] = mkc(2.f * Y2.x, -2.f * Y2.y);
            } else {
                int kk = 4096 - k;
                int sk = phi(drev(k)), skk = phi(drev(kk));
                cf ck = lds[sk], ckk = lds[skk];
                cf cc = cconjf(ckk);
                cf E  = (ck + cc) * 0.5f;
                cf Dd = csub(ck, cc);
                cf O  = mkc(Dd.y, -Dd.x) * 0.5f;
                cf wv = tw8[k];
                cf Xk  = cadd(E, cmul(wv, O));
                cf wp  = mkc(-wv.x, wv.y);
                cf Xkk = cadd(cconjf(E), cmul(wp, cconjf(O)));
                cf Yk  = cmul(Xk,  Hrow[k]);
                cf Ykk = cmul(Xkk, Hrow[kk]);
                cf cy = cconjf(Ykk);
                cf S  = cadd(Yk, cy), D2 = csub(Yk, cy);
                cf Zk = addi(S, cmul(cconjf(wv), D2));
                cf cy2 = cconjf(Yk);
                cf S2  = cadd(Ykk, cy2), D3 = csub(Ykk, cy2);
                cf Zkk = subi(S2, cmul(wv, D3));
                lds[sk] = Zk; lds[skk] = Zkk;
            }
        }
    }
    __syncthreads();
    dit_chunk_and_mid(lds, tw4);
#pragma unroll
    for (int it = 0; it < 4; ++it) {
        int j = tid + (it << 8);
        cf a0 = lds[phi(j)];
        cf a1 = cmul(lds[phi(j+1024)], cconjf(tw4[j]));
        cf a2 = cmul(lds[phi(j+2048)], cconjf(tw4[2*j]));
        cf a3 = cmul(lds[phi(j+3072)], cconjf(tw4[3*j]));
        cf b0 = cadd(a0,a2), b1 = csub(a0,a2);
        cf b2 = cadd(a1,a3), b3 = csub(a1,a3);
        cf o0 = cadd(b0,b2);           // n = j
        cf o1 = addi(b1,b3);           // n = j+1024
        rp[j]        = pack2bf(o0.x, o0.y);
        rp[j + 1024] = pack2bf(o1.x, o1.y);
    }
}

typedef __attribute__((ext_vector_type(8))) short short8;
typedef __attribute__((ext_vector_type(4))) float f32x4;

// ---------------- gemm v2: global_load_lds from bf16 ub/pwb ----------------
__global__ __launch_bounds__(256, 4) void gemm_mfma_v2(
        const unsigned short* __restrict__ ub, const unsigned short* __restrict__ pwb,
        const float* __restrict__ pb, const unsigned short* __restrict__ yb,
        float* __restrict__ out) {
    __shared__ char lds_raw[34816];
    float (*ysc)[132] = (float(*)[132])lds_raw;

    const int tid  = threadIdx.x;
    const int lane = tid & 63;
    const int wid  = tid >> 6;
    const int wr   = wid >> 1;
    const int wc   = wid & 1;
    const int m0   = blockIdx.x * 128;
    const int n0   = blockIdx.y * 128;

    f32x4 acc[4][4] = {};

    const int srow = lane >> 2;
    const int scol = 16 * ((lane & 3) ^ ((lane >> 2) & 3));

#define STAGE2(bufbase, kt)                                                                   \
    {                                                                                         \
        _Pragma("unroll")                                                                     \
        for (int i = 0; i < 2; ++i) {                                                         \
            int c = wid * 2 + i;                                                              \
            const char* gA = (const char*)ub  + (size_t)(m0 + c * 16 + srow) * 2048 + (kt) * 2 + scol; \
            const char* gB = (const char*)pwb + (size_t)(n0 + c * 16 + srow) * 2048 + (kt) * 2 + scol; \
            gload16(gA, lds_raw + (bufbase) + c * 1024);                                      \
            gload16(gB, lds_raw + (bufbase) + 8192 + c * 1024);                               \
        }                                                                                     \
    }

    STAGE2(0, 0);
    __syncthreads();

    for (int t = 0; t < 32; ++t) {
        const int cur = (t & 1) << 14;
        if (t < 31) STAGE2(cur ^ 16384, (t + 1) * 32);
        short8 af[4], bfr[4];
#pragma unroll
        for (int f = 0; f < 4; ++f) {
            int rowA = wr * 64 + f * 16 + (lane & 15);
            int rowB = wc * 64 + f * 16 + (lane & 15);
            int offA = cur + rowA * 64 + (((lane >> 4) * 16) ^ ((rowA & 3) << 4));
            int offB = cur + 8192 + rowB * 64 + (((lane >> 4) * 16) ^ ((rowB & 3) << 4));
            af[f]  = *(short8*)(lds_raw + offA);
            bfr[f] = *(short8*)(lds_raw + offB);
        }
#pragma unroll
        for (int mf = 0; mf < 4; ++mf)
#pragma unroll
            for (int nf = 0; nf < 4; ++nf)
                acc[mf][nf] = __builtin_amdgcn_mfma_f32_16x16x32_bf16(
                    af[mf], bfr[nf], acc[mf][nf], 0, 0, 0);
        __syncthreads();
    }

    const int b  = m0 >> 12;
    const int l0 = m0 & (SEQL - 1);
    float pbv[4];
#pragma unroll
    for (int nf = 0; nf < 4; ++nf)
        pbv[nf] = pb[n0 + wc * 64 + nf * 16 + (lane & 15)];

    for (int c = 0; c < 2; ++c) {
        __syncthreads();
#pragma unroll
        for (int j = 0; j < 4; ++j) {
            int idx = j * 256 + tid;
            int dn  = idx >> 3;
            int lg  = idx & 7;
            uint4 w4 = *(const uint4*)&yb[(((size_t)(b * DCH + n0 + dn)) << 12) + l0 + c * 64 + lg * 8];
            int lb = lg * 8;
            ysc[lb+0][dn] = bflo(w4.x); ysc[lb+1][dn] = bfhi(w4.x);
            ysc[lb+2][dn] = bflo(w4.y); ysc[lb+3][dn] = bfhi(w4.y);
            ysc[lb+4][dn] = bflo(w4.z); ysc[lb+5][dn] = bfhi(w4.z);
            ysc[lb+6][dn] = bflo(w4.w); ysc[lb+7][dn] = bfhi(w4.w);
        }
        __syncthreads();
        if (wr == c) {
#pragma unroll
            for (int mf = 0; mf < 4; ++mf)
#pragma unroll
                for (int i = 0; i < 4; ++i) {
                    int lrow = mf * 16 + (lane >> 4) * 4 + i;
                    int m = m0 + c * 64 + lrow;
#pragma unroll
                    for (int nf = 0; nf < 4; ++nf) {
                        int nl = wc * 64 + nf * 16 + (lane & 15);
                        int n = n0 + nl;
                        float proj = acc[mf][nf][i] + pbv[nf];
                        float ures = __uint_as_float((unsigned)ub[(size_t)m * DCH + n] << 16);
                        out[(size_t)m * DCH + n] = ysc[lrow][nl] * proj + ures;
                    }
                }
        }
    }
#undef STAGE2
}

// ---------------- gemm fallback (reg-staged): used when ws too small ----------------
__global__ __launch_bounds__(256, 3) void gemm_mfma_fb(
        const float* __restrict__ u, const float* __restrict__ pw,
        const float* __restrict__ pb, const unsigned short* __restrict__ yb,
        float* __restrict__ out) {
    __shared__ char lds_raw[34816];
    float (*ysc)[132] = (float(*)[132])lds_raw;
    const int tid  = threadIdx.x;
    const int lane = tid & 63;
    const int wid  = tid >> 6;
    const int wr   = wid >> 1;
    const int wc   = wid & 1;
    const int m0   = blockIdx.x * 128;
    const int n0   = blockIdx.y * 128;
    f32x4 acc[4][4] = {};
    float4 ra[4], rb[4];
    int s_row[4], s_f4[4];
#pragma unroll
    for (int j = 0; j < 4; ++j) {
        int idx = j * 256 + tid;
        s_row[j] = idx >> 3;
        s_f4[j]  = idx & 7;
    }
#define LOADT(kt)                                                                     \
    {                                                                                 \
        _Pragma("unroll")                                                             \
        for (int j = 0; j < 4; ++j) {                                                 \
            ra[j] = *(const float4*)&u [(size_t)(m0 + s_row[j]) * DCH + (kt) + s_f4[j] * 4]; \
            rb[j] = *(const float4*)&pw[(size_t)(n0 + s_row[j]) * DCH + (kt) + s_f4[j] * 4]; \
        }                                                                             \
    }
#define WRITET(base)                                                                  \
    {                                                                                 \
        _Pragma("unroll")                                                             \
        for (int j = 0; j < 4; ++j) {                                                 \
            int off = (base) + ((s_row[j] * 64 + s_f4[j] * 8) ^ ((s_row[j] & 3) << 4)); \
            uint2 pa, pbv2;                                                           \
            pa.x   = pack2bf(ra[j].x, ra[j].y);  pa.y   = pack2bf(ra[j].z, ra[j].w);  \
            pbv2.x = pack2bf(rb[j].x, rb[j].y);  pbv2.y = pack2bf(rb[j].z, rb[j].w);  \
            *(uint2*)(lds_raw + off)        = pa;                                     \
            *(uint2*)(lds_raw + off + 8192) = pbv2;                                   \
        }                                                                             \
    }
    LOADT(0);
    WRITET(0);
    LOADT(32);
    __syncthreads();
    for (int t = 0; t < 32; ++t) {
        const int cur = (t & 1) << 14;
        short8 af[4], bfr[4];
#pragma unroll
        for (int f = 0; f < 4; ++f) {
            int rowA = wr * 64 + f * 16 + (lane & 15);
            int rowB = wc * 64 + f * 16 + (lane & 15);
            int offA = cur + ((rowA * 64 + ((lane >> 4) * 16)) ^ ((rowA & 3) << 4));
            int offB = cur + 8192 + ((rowB * 64 + ((lane >> 4) * 16)) ^ ((rowB & 3) << 4));
            af[f]  = *(short8*)(lds_raw + offA);
            bfr[f] = *(short8*)(lds_raw + offB);
        }
        if (t < 31) WRITET(cur ^ 16384);
        if (t < 30) LOADT((t + 2) * 32);
#pragma unroll
        for (int mf = 0; mf < 4; ++mf)
#pragma unroll
            for (int nf = 0; nf < 4; ++nf)
                acc[mf][nf] = __builtin_amdgcn_mfma_f32_16x16x32_bf16(
                    af[mf], bfr[nf], acc[mf][nf], 0, 0, 0);
        __syncthreads();
    }
    const int b  = m0 >> 12;
    const int l0 = m0 & (SEQL - 1);
    float pbv[4];
#pragma unroll
    for (int nf = 0; nf < 4; ++nf)
        pbv[nf] = pb[n0 + wc * 64 + nf * 16 + (lane & 15)];
    for (int c = 0; c < 2; ++c) {
        __syncthreads();
#pragma unroll
        for (int j = 0; j < 4; ++j) {
            int idx = j * 256 + tid;
            int dn  = idx >> 3;
            int lg  = idx & 7;
            uint4 w4 = *(const uint4*)&yb[(((size_t)(b * DCH + n0 + dn)) << 12) + l0 + c * 64 + lg * 8];
            int lb = lg * 8;
            ysc[lb+0][dn] = bflo(w4.x); ysc[lb+1][dn] = bfhi(w4.x);
            ysc[lb+2][dn] = bflo(w4.y); ysc[lb+3][dn] = bfhi(w4.y);
            ysc[lb+4][dn] = bflo(w4.z); ysc[lb+5][dn] = bfhi(w4.z);
            ysc[lb+6][dn] = bflo(w4.w); ysc[lb+7][dn] = bfhi(w4.w);
        }
        __syncthreads();
        if (wr == c) {
#pragma unroll
            for (int mf = 0; mf < 4; ++mf)
#pragma unroll
                for (int i = 0; i < 4; ++i) {
                    int lrow = mf * 16 + (lane >> 4) * 4 + i;
                    int m = m0 + c * 64 + lrow;
#pragma unroll
                    for (int nf = 0; nf < 4; ++nf) {
                        int nl = wc * 64 + nf * 16 + (lane & 15);
                        int n = n0 + nl;
                        float proj = acc[mf][nf][i] + pbv[nf];
                        out[(size_t)m * DCH + n] = ysc[lrow][nl] * proj + u[(size_t)m * DCH + n];
                    }
                }
        }
    }
#undef LOADT
#undef WRITET
}

extern "C" void kernel_launch(void* const* d_in, const int* in_sizes, int n_in,
                              void* d_out, int out_size, void* d_ws, size_t ws_size,
                              hipStream_t stream) {
    const float* u  = (const float*)d_in[0];
    const float* z  = (const float*)d_in[1];
    const float* w1 = (const float*)d_in[2];
    const float* b1 = (const float*)d_in[3];
    const float* w2 = (const float*)d_in[4];
    const float* b2 = (const float*)d_in[5];
    const float* pw = (const float*)d_in[6];
    const float* pb = (const float*)d_in[7];
    float* out = (float*)d_out;

    float*    h    = (float*)d_ws;                        // 256 KB
    unsigned* utyb = (unsigned*)((char*)d_ws + 262144);   // 32 MB (bf16-pair rows; y bf16 in place)
    cf* kf = (cf*)d_out;                                  // 33.5 MB scratch (overwritten by gemm)

    const size_t ub_off  = 262144 + (size_t)BATCH * DCH * (SEQL / 2) * sizeof(unsigned);
    const size_t pwb_off = ub_off + (size_t)BATCH * SEQL * DCH * sizeof(unsigned short);
    const size_t tw_off  = pwb_off + (size_t)DCH * DCH * sizeof(unsigned short);
    const size_t need    = tw_off + 2 * 4096 * sizeof(cf);
    const bool   big     = ws_size >= need;

    cf* tw4 = big ? (cf*)((char*)d_ws + tw_off) : (cf*)((char*)d_out + (40u << 20));
    cf* tw8 = tw4 + 4096;
    unsigned short* ub  = big ? (unsigned short*)((char*)d_ws + ub_off)  : (unsigned short*)0;
    unsigned short* pwb = big ? (unsigned short*)((char*)d_ws + pwb_off) : (unsigned short*)0;

    twiddle_init<<<dim3(16), dim3(256), 0, stream>>>(tw4, tw8);
    mlp_kernel<<<dim3(16), dim3(256), 0, stream>>>(z, w1, b1, h);
    transpose_kernel<<<dim3(SEQL / 32, DCH / 32, BATCH), dim3(32, 8), 0, stream>>>(u, utyb, ub);
    if (big) pw2bf_kernel<<<dim3(512), dim3(256), 0, stream>>>(pw, pwb);
    filt_fft_kernel<<<dim3(DCH), dim3(256), 0, stream>>>(h, w2, b2, tw4, tw8, kf);
    conv_kernel<<<dim3(BATCH * DCH), dim3(256), 0, stream>>>(utyb, tw4, tw8, kf);
    if (big)
        gemm_mfma_v2<<<dim3(128, 8), dim3(256), 0, stream>>>(ub, pwb, pb, (const unsigned short*)utyb, out);
    else
        gemm_mfma_fb<<<dim3(128, 8), dim3(256), 0, stream>>>(u, pw, pb, (const unsigned short*)utyb, out);
}

// Round 12
// 263.212 us; speedup vs baseline: 1.3153x; 1.0121x over previous
//
#include <hip/hip_runtime.h>
#include <hip/hip_bf16.h>

#define SEQL 4096
#define DCH  1024
#define BATCH 4
#define KH   4097        // stored half-spectrum entries per channel

// packed complex: one VGPR pair
typedef __attribute__((ext_vector_type(2))) float cf;
__device__ __forceinline__ cf mkc(float x, float y){ cf r; r.x = x; r.y = y; return r; }
__device__ __forceinline__ cf cadd(cf a, cf b){ return a + b; }
__device__ __forceinline__ cf csub(cf a, cf b){ return a - b; }
__device__ __forceinline__ cf cmul(cf a, cf b){ return a.xx * b + mkc(-a.y, a.y) * b.yx; }
__device__ __forceinline__ cf cconjf(cf a){ return mkc(a.x, -a.y); }
__device__ __forceinline__ cf addi(cf a, cf b){ return a + mkc(-b.y, b.x); }  // a + i*b
__device__ __forceinline__ cf subi(cf a, cf b){ return a - mkc(-b.y, b.x); }  // a - i*b
// LDS index swizzle: XOR high nibble into low nibble (bijective; replaces +1/16 pad)
__device__ __forceinline__ int phi(int c){ return c ^ ((c >> 4) & 15); }
__device__ __forceinline__ int drev(int i){                                          // reverse 6 base-4 digits
    return ((i>>10)&3) | (((i>>8)&3)<<2) | (((i>>6)&3)<<4)
         | (((i>>4)&3)<<6) | (((i>>2)&3)<<8) | ((i&3)<<10);
}

// register-stage twiddles (compile-time constants)
__device__ __forceinline__ cf W1c(int j){   // e^{-2*pi*i*j/16}
    const float cs[4] = {1.f, 0.92387953f, 0.70710678f, 0.38268343f};
    const float sn[4] = {0.f, -0.38268343f, -0.70710678f, -0.92387953f};
    return mkc(cs[j], sn[j]);
}
__device__ __forceinline__ cf W2c(int j){   // e^{-2*pi*i*j/8}
    const float cs[4] = {1.f, 0.70710678f, 0.f, -0.70710678f};
    const float sn[4] = {0.f, -0.70710678f, -1.f, -0.70710678f};
    return mkc(cs[j], sn[j]);
}
__device__ __forceinline__ cf W3c(int j){   // e^{-2*pi*i*3j/16}
    const float cs[4] = {1.f, 0.38268343f, -0.70710678f, -0.92387953f};
    const float sn[4] = {0.f, -0.92387953f, -0.70710678f, 0.38268343f};
    return mkc(cs[j], sn[j]);
}

__device__ __forceinline__ unsigned pack2bf(float a, float b){
    unsigned r;
    asm("v_cvt_pk_bf16_f32 %0, %1, %2" : "=v"(r) : "v"(a), "v"(b));
    return r;   // lo = bf16(a), hi = bf16(b)
}
__device__ __forceinline__ float bflo(unsigned u){ return __uint_as_float(u << 16); }
__device__ __forceinline__ float bfhi(unsigned u){ return __uint_as_float(u & 0xffff0000u); }

__device__ __forceinline__ void gload16(const void* g, void* l){
    __builtin_amdgcn_global_load_lds((const __attribute__((address_space(1))) void*)g,
                                     (__attribute__((address_space(3))) void*)l, 16, 0, 0);
}

// ---------------- twiddle tables ----------------
__global__ __launch_bounds__(256) void twiddle_init(cf* __restrict__ tw4, cf* __restrict__ tw8){
    int i = blockIdx.x*256 + threadIdx.x;   // 4096 total
    const double TWO_PI = 6.283185307179586476925286766559;
    double a4 = -TWO_PI * (double)i / 4096.0;
    double a8 = -TWO_PI * (double)i / 8192.0;
    tw4[i] = mkc((float)cos(a4), (float)sin(a4));
    tw8[i] = mkc((float)cos(a8), (float)sin(a8));
}

// ---------------- MLP: h[l][16] ----------------
__global__ __launch_bounds__(256) void mlp_kernel(
        const float* __restrict__ z, const float* __restrict__ w1,
        const float* __restrict__ b1, float* __restrict__ h) {
    int l = blockIdx.x * blockDim.x + threadIdx.x;
    if (l >= SEQL) return;
    float pe0 = z[l * 3 + 0], pe1 = z[l * 3 + 1], pe2 = z[l * 3 + 2];
#pragma unroll
    for (int j = 0; j < 16; ++j) {
        float v = pe0 * w1[j * 3 + 0] + pe1 * w1[j * 3 + 1] + pe2 * w1[j * 3 + 2] + b1[j];
        h[l * 16 + j] = v > 0.f ? v : 0.f;
    }
}

// ---------------- transpose u (B,L,D) -> utb (B,D,L/2 uint of bf16 pairs) + ub = bf16(u) ----------------
__global__ __launch_bounds__(256) void transpose_kernel(
        const float* __restrict__ u, unsigned* __restrict__ utb,
        unsigned short* __restrict__ ub) {
    __shared__ float tile[32][33];
    int b = blockIdx.z;
    int l0 = blockIdx.x * 32;
    int d0 = blockIdx.y * 32;
    int tx = threadIdx.x, ty = threadIdx.y;  // 32 x 8
    const float* up = u + (size_t)b * SEQL * DCH;
    unsigned short* ubp = ub ? ub + (size_t)b * SEQL * DCH : (unsigned short*)0;
#pragma unroll
    for (int i = 0; i < 32; i += 8) {
        size_t idx = (size_t)(l0 + ty + i) * DCH + d0 + tx;
        float v = up[idx];
        tile[ty + i][tx] = v;
        if (ub) ubp[idx] = (unsigned short)pack2bf(v, v);
    }
    __syncthreads();
    unsigned* utp = utb + (size_t)b * DCH * (SEQL / 2);
    int t  = ty * 32 + tx;          // 0..255
    int dl = t >> 4;                // 0..15
    int lp = t & 15;                // l-pair index: l = 2lp, 2lp+1
#pragma unroll
    for (int p = 0; p < 2; ++p) {
        int dd = dl + p * 16;
        unsigned v = pack2bf(tile[2 * lp][dd], tile[2 * lp + 1][dd]);
        utp[(size_t)(d0 + dd) * (SEQL / 2) + (l0 >> 1) + lp] = v;
    }
}

// ---------------- pw -> bf16 ----------------
__global__ __launch_bounds__(256) void pw2bf_kernel(
        const float* __restrict__ pw, unsigned short* __restrict__ pwb) {
    int t = blockIdx.x * 256 + threadIdx.x;
    float4 a = *(const float4*)&pw[(size_t)t * 8];
    float4 b = *(const float4*)&pw[(size_t)t * 8 + 4];
    uint4 o;
    o.x = pack2bf(a.x, a.y); o.y = pack2bf(a.z, a.w);
    o.z = pack2bf(b.x, b.y); o.w = pack2bf(b.z, b.w);
    *(uint4*)&pwb[(size_t)t * 8] = o;
}

// ---- shared middle DIF passes (m=256,64,16), fwd chunk pass (m=4,m=1) ----
__device__ void dif_mid_and_chunk(cf* lds, const cf* __restrict__ tw){
    const int tid = threadIdx.x;
#pragma unroll
    for (int p = 1; p < 4; ++p) {
        const int lm = 10 - 2*p;          // 8,6,4
        const int m  = 1 << lm;
        const int step = 1024 >> lm;
#pragma unroll
        for (int it = 0; it < 4; ++it) {
            int j = tid + (it << 8);
            int k = j & (m-1);
            int g = j >> lm;
            int i0 = (g << (lm+2)) + k;
            cf x0 = lds[phi(i0)];
            cf x1 = lds[phi(i0+m)];
            cf x2 = lds[phi(i0+2*m)];
            cf x3 = lds[phi(i0+3*m)];
            cf b0 = cadd(x0,x2), b1 = csub(x0,x2);
            cf b2 = cadd(x1,x3), b3 = csub(x1,x3);
            cf u0 = cadd(b0,b2);
            cf u2 = csub(b0,b2);
            cf u1 = subi(b1,b3);
            cf u3 = addi(b1,b3);
            int t1 = k*step;
            lds[phi(i0)]     = u0;
            lds[phi(i0+m)]   = cmul(u1, tw[t1]);
            lds[phi(i0+2*m)] = cmul(u2, tw[2*t1]);
            lds[phi(i0+3*m)] = cmul(u3, tw[3*t1]);
        }
        __syncthreads();
    }
    {   // fused m=4 / m=1 register pass; thread owns complexes [16t,16t+16)
        const int b0 = tid << 4;
        const int xr = tid & 15;
        cf v[16];
#pragma unroll
        for (int j=0;j<16;++j) v[j] = lds[b0 + (j ^ xr)];
#pragma unroll
        for (int j=0;j<4;++j){
            cf x0=v[j], x1=v[j+4], x2=v[j+8], x3=v[j+12];
            cf b0v=cadd(x0,x2), b1=csub(x0,x2), b2=cadd(x1,x3), b3=csub(x1,x3);
            cf u0=cadd(b0v,b2), u2=csub(b0v,b2), u1=subi(b1,b3), u3=addi(b1,b3);
            v[j]    = u0;
            v[j+4]  = cmul(u1, W1c(j));
            v[j+8]  = cmul(u2, W2c(j));
            v[j+12] = cmul(u3, W3c(j));
        }
#pragma unroll
        for (int c=0;c<4;++c){
            cf x0=v[4*c], x1=v[4*c+1], x2=v[4*c+2], x3=v[4*c+3];
            cf b0v=cadd(x0,x2), b1=csub(x0,x2), b2=cadd(x1,x3), b3=csub(x1,x3);
            v[4*c]   = cadd(b0v,b2);
            v[4*c+1] = subi(b1,b3);
            v[4*c+2] = csub(b0v,b2);
            v[4*c+3] = addi(b1,b3);
        }
#pragma unroll
        for (int j=0;j<16;++j) lds[b0 + (j ^ xr)] = v[j];
        __syncthreads();
    }
}

// ---- inverse: chunk pass (m=1,m=4) + middle DIT passes (m=16,64,256) ----
__device__ void dit_chunk_and_mid(cf* lds, const cf* __restrict__ tw){
    const int tid = threadIdx.x;
    {
        const int b0 = tid << 4;
        const int xr = tid & 15;
        cf v[16];
#pragma unroll
        for (int j=0;j<16;++j) v[j] = lds[b0 + (j ^ xr)];
#pragma unroll
        for (int c=0;c<4;++c){
            cf a0=v[4*c], a1=v[4*c+1], a2=v[4*c+2], a3=v[4*c+3];
            cf b0v=cadd(a0,a2), b1=csub(a0,a2), b2=cadd(a1,a3), b3=csub(a1,a3);
            v[4*c]   = cadd(b0v,b2);
            v[4*c+1] = addi(b1,b3);
            v[4*c+2] = csub(b0v,b2);
            v[4*c+3] = subi(b1,b3);
        }
#pragma unroll
        for (int j=0;j<4;++j){
            cf a0=v[j];
            cf a1=cmul(v[j+4],  cconjf(W1c(j)));
            cf a2=cmul(v[j+8],  cconjf(W2c(j)));
            cf a3=cmul(v[j+12], cconjf(W3c(j)));
            cf b0v=cadd(a0,a2), b1=csub(a0,a2), b2=cadd(a1,a3), b3=csub(a1,a3);
            v[j]    = cadd(b0v,b2);
            v[j+4]  = addi(b1,b3);
            v[j+8]  = csub(b0v,b2);
            v[j+12] = subi(b1,b3);
        }
#pragma unroll
        for (int j=0;j<16;++j) lds[b0 + (j ^ xr)] = v[j];
        __syncthreads();
    }
#pragma unroll
    for (int p = 0; p < 3; ++p) {
        const int lm = 4 + 2*p;           // 16,64,256
        const int m  = 1 << lm;
        const int step = 1024 >> lm;
#pragma unroll
        for (int it = 0; it < 4; ++it) {
            int j = tid + (it << 8);
            int k = j & (m-1);
            int g = j >> lm;
            int i0 = (g << (lm+2)) + k;
            int t1 = k*step;
            cf a0 = lds[phi(i0)];
            cf a1 = cmul(lds[phi(i0+m)],   cconjf(tw[t1]));
            cf a2 = cmul(lds[phi(i0+2*m)], cconjf(tw[2*t1]));
            cf a3 = cmul(lds[phi(i0+3*m)], cconjf(tw[3*t1]));
            cf b0=cadd(a0,a2), b1=csub(a0,a2), b2=cadd(a1,a3), b3=csub(a1,a3);
            lds[phi(i0)]     = cadd(b0,b2);
            lds[phi(i0+m)]   = addi(b1,b3);
            lds[phi(i0+2*m)] = csub(b0,b2);
            lds[phi(i0+3*m)] = subi(b1,b3);
        }
        __syncthreads();
    }
}

// ---------------- filter row -> packed FFT -> H[d][0..4096] (scaled 1/8192) ----------------
__global__ __launch_bounds__(256) void filt_fft_kernel(
        const float* __restrict__ h, const float* __restrict__ w2,
        const float* __restrict__ b2, const cf* __restrict__ tw4,
        const cf* __restrict__ tw8, cf* __restrict__ kf) {
    __shared__ cf lds[4096];
    const int d = blockIdx.x;
    const int tid = threadIdx.x;
    float wv[16];
#pragma unroll
    for (int j = 0; j < 16; ++j) wv[j] = w2[d * 16 + j];
    const float bb = b2[d];
#pragma unroll
    for (int it = 0; it < 4; ++it) {
        int j = tid + (it << 8);
        const float* h0 = h + (size_t)(2*j) * 16;
        const float* h1 = h + (size_t)(2*(j+1024)) * 16;
        float f0 = bb, f1 = bb, f2 = bb, f3 = bb;
#pragma unroll
        for (int i = 0; i < 16; ++i) {
            f0 += h0[i] * wv[i];  f1 += h0[16+i] * wv[i];
            f2 += h1[i] * wv[i];  f3 += h1[16+i] * wv[i];
        }
        cf x0 = mkc(f0, f1), x1 = mkc(f2, f3);
        cf u0 = cadd(x0,x1);
        cf u2 = csub(x0,x1);
        cf u1 = subi(x0,x1);
        cf u3 = addi(x0,x1);
        lds[phi(j)]      = u0;
        lds[phi(j+1024)] = cmul(u1, tw4[j]);
        lds[phi(j+2048)] = cmul(u2, tw4[2*j]);
        lds[phi(j+3072)] = cmul(u3, tw4[3*j]);
    }
    __syncthreads();
    dif_mid_and_chunk(lds, tw4);
    const float s = 1.f / 8192.f;
    cf* Hrow = kf + (size_t)d * KH;
    const int lane  = tid & 63;
    const int kbase = ((lane & 31) << 6) | ((lane >> 5) << 5) | ((tid >> 6) << 3);
#pragma unroll
    for (int it = 0; it < 8; ++it) {
        int k = kbase + it;
        if (k == 0) {
            cf c0 = lds[0];
            Hrow[0]    = mkc((c0.x + c0.y) * s, 0.f);
            Hrow[4096] = mkc((c0.x - c0.y) * s, 0.f);
            cf c2 = lds[phi(drev(2048))];
            Hrow[2048] = mkc(c2.x * s, -c2.y * s);
        } else {
            int kk = 4096 - k;
            cf ck  = lds[phi(drev(k))];
            cf ckk = lds[phi(drev(kk))];
            cf cc = cconjf(ckk);
            cf E  = (ck + cc) * 0.5f;
            cf Dd = csub(ck, cc);
            cf O  = mkc(Dd.y, -Dd.x) * 0.5f;
            cf wvv = tw8[k];
            cf Xk  = cadd(E, cmul(wvv, O));
            cf wp  = mkc(-wvv.x, wvv.y);
            cf Xkk = cadd(cconjf(E), cmul(wp, cconjf(O)));
            Hrow[k]  = Xk * s;
            Hrow[kk] = Xkk * s;
        }
    }
}

// ---------------- conv: bf16 in -> packed fwd FFT -> multiply -> inv FFT -> bf16 y (in place) ----------------
__global__ __launch_bounds__(256) void conv_kernel(
        unsigned* __restrict__ utyb, const cf* __restrict__ tw4,
        const cf* __restrict__ tw8, const cf* __restrict__ kf) {
    __shared__ cf lds[4096];
    const int row = blockIdx.x;            // b*DCH + d
    const int d = row & (DCH - 1);
    const int tid = threadIdx.x;
    unsigned* rp = utyb + (size_t)row * (SEQL / 2);
#pragma unroll
    for (int it = 0; it < 4; ++it) {
        int j = tid + (it << 8);
        unsigned q0 = rp[j], q1 = rp[j + 1024];
        cf x0 = mkc(bflo(q0), bfhi(q0));
        cf x1 = mkc(bflo(q1), bfhi(q1));
        cf u0 = cadd(x0,x1);
        cf u2 = csub(x0,x1);
        cf u1 = subi(x0,x1);
        cf u3 = addi(x0,x1);
        lds[phi(j)]      = u0;
        lds[phi(j+1024)] = cmul(u1, tw4[j]);
        lds[phi(j+2048)] = cmul(u2, tw4[2*j]);
        lds[phi(j+3072)] = cmul(u3, tw4[3*j]);
    }
    __syncthreads();
    dif_mid_and_chunk(lds, tw4);
    const cf* Hrow = kf + (size_t)d * KH;
    {
        const int lane  = tid & 63;
        const int kbase = ((lane & 31) << 6) | ((lane >> 5) << 5) | ((tid >> 6) << 3);
#pragma unroll
        for (int it = 0; it < 8; ++it) {
            int k = kbase + it;
            if (k == 0) {
                cf c0 = lds[0];
                float X0 = c0.x + c0.y, X4 = c0.x - c0.y;
                cf H0 = Hrow[0], H4 = Hrow[4096];
                cf Y0 = H0 * X0;
                cf Y4 = H4 * X4;
                cf S  = cadd(Y0, Y4), Dd = csub(Y0, Y4);
                lds[0] = addi(S, Dd);
                int s2 = phi(drev(2048));
                cf c2 = lds[s2];
                cf Y2 = cmul(cconjf(c2), Hrow[2048]);
                lds[s2] = mkc(2.f * Y2.x, -2.f * Y2.y);
            } else {
                int kk = 4096 - k;
                int sk = phi(drev(k)), skk = phi(drev(kk));
                cf ck = lds[sk], ckk = lds[skk];
                cf cc = cconjf(ckk);
                cf E  = (ck + cc) * 0.5f;
                cf Dd = csub(ck, cc);
                cf O  = mkc(Dd.y, -Dd.x) * 0.5f;
                cf wv = tw8[k];
                cf Xk  = cadd(E, cmul(wv, O));
                cf wp  = mkc(-wv.x, wv.y);
                cf Xkk = cadd(cconjf(E), cmul(wp, cconjf(O)));
                cf Yk  = cmul(Xk,  Hrow[k]);
                cf Ykk = cmul(Xkk, Hrow[kk]);
                cf cy = cconjf(Ykk);
                cf S  = cadd(Yk, cy), D2 = csub(Yk, cy);
                cf Zk = addi(S, cmul(cconjf(wv), D2));
                cf cy2 = cconjf(Yk);
                cf S2  = cadd(Ykk, cy2), D3 = csub(Ykk, cy2);
                cf Zkk = subi(S2, cmul(wv, D3));
                lds[sk] = Zk; lds[skk] = Zkk;
            }
        }
    }
    __syncthreads();
    dit_chunk_and_mid(lds, tw4);
#pragma unroll
    for (int it = 0; it < 4; ++it) {
        int j = tid + (it << 8);
        cf a0 = lds[phi(j)];
        cf a1 = cmul(lds[phi(j+1024)], cconjf(tw4[j]));
        cf a2 = cmul(lds[phi(j+2048)], cconjf(tw4[2*j]));
        cf a3 = cmul(lds[phi(j+3072)], cconjf(tw4[3*j]));
        cf b0 = cadd(a0,a2), b1 = csub(a0,a2);
        cf b2 = cadd(a1,a3), b3 = csub(a1,a3);
        cf o0 = cadd(b0,b2);           // n = j
        cf o1 = addi(b1,b3);           // n = j+1024
        rp[j]        = pack2bf(o0.x, o0.y);
        rp[j + 1024] = pack2bf(o1.x, o1.y);
    }
}

typedef __attribute__((ext_vector_type(8))) short short8;
typedef __attribute__((ext_vector_type(4))) float f32x4;

// ---------------- gemm v3: 256x128 tile, BK=64, 3-buffer phase-split pipeline ----------------
// (T3+T4: counted vmcnt(6) across phase barriers; T2: row-XOR swizzle via pre-swizzled
//  global source + swizzled ds_read; T5: setprio around MFMA cluster)
__global__ __launch_bounds__(512, 2) void gemm_mfma_v3(
        const unsigned short* __restrict__ ub, const unsigned short* __restrict__ pwb,
        const float* __restrict__ pb, const unsigned short* __restrict__ yb,
        float* __restrict__ out) {
    __shared__ char lds_raw[147456];   // 3 bufs x (A 32K + B 16K); epilogue overlays [128][132] f32
    float (*ysc)[132] = (float(*)[132])lds_raw;

    const int tid  = threadIdx.x;
    const int lane = tid & 63;
    const int wid  = tid >> 6;          // 0..7
    const int wr   = wid >> 1;          // 0..3  (64 m-rows each)
    const int wc   = wid & 1;           // 0..1  (64 n-cols each)
    const int m0   = blockIdx.x * 256;
    const int n0   = blockIdx.y * 128;

    f32x4 acc[4][4] = {};

    // ---- prologue: stage K-tiles 0,1 into buf0,buf1 (6 units x 2 loads) ----
#pragma unroll
    for (int tt = 0; tt < 2; ++tt) {
#pragma unroll
        for (int un = 0; un < 3; ++un) {
            const unsigned short* gs = (un == 2) ? pwb : ub;
            int growb = (un == 2) ? n0 : (m0 + un * 128);
#pragma unroll
            for (int j = 0; j < 2; ++j) {
                int rr = j * 64 + (tid >> 3);
                int ss = (tid & 7) ^ ((tid >> 3) & 7);
                gload16(gs + (size_t)(growb + rr) * 1024 + tt * 64 + ss * 8,
                        lds_raw + tt * 49152 + un * 16384 + rr * 128 + (tid & 7) * 16);
            }
        }
    }
    asm volatile("s_waitcnt vmcnt(6)" ::: "memory");   // tile 0 landed (tile 1's 6 in flight)
    __builtin_amdgcn_sched_barrier(0);
    __builtin_amdgcn_s_barrier();

    // ---- main loop: 16 K-tiles, 4 phases each ----
    for (int t = 0; t < 16; ++t) {
        const int Ab  = (t % 3) * 49152;
        const int Bb  = Ab + 32768;
        const int sbB = ((t + 2) % 3) * 49152;
        const int kt2 = (t + 2) * 64;
#pragma unroll
        for (int q = 0; q < 4; ++q) {
            const int qr = q >> 1, qc = q & 1;
            short8 af[2][2], bfr[2][2];
#pragma unroll
            for (int f = 0; f < 2; ++f) {
                int arow = wr * 64 + qr * 32 + f * 16 + (lane & 15);
                int brow = wc * 64 + qc * 32 + f * 16 + (lane & 15);
#pragma unroll
                for (int kh = 0; kh < 2; ++kh) {
                    int ks = (lane >> 4) + 4 * kh;
                    af[f][kh]  = *(short8*)(lds_raw + Ab + arow * 128 + (ks ^ (arow & 7)) * 16);
                    bfr[f][kh] = *(short8*)(lds_raw + Bb + brow * 128 + (ks ^ (brow & 7)) * 16);
                }
            }
            if (q < 3 && t < 14) {      // stage unit q of K-tile t+2 into third buffer
                const unsigned short* gs = (q == 2) ? pwb : ub;
                int growb = (q == 2) ? n0 : (m0 + q * 128);
#pragma unroll
                for (int j = 0; j < 2; ++j) {
                    int rr = j * 64 + (tid >> 3);
                    int ss = (tid & 7) ^ ((tid >> 3) & 7);
                    gload16(gs + (size_t)(growb + rr) * 1024 + kt2 + ss * 8,
                            lds_raw + sbB + q * 16384 + rr * 128 + (tid & 7) * 16);
                }
            }
            __builtin_amdgcn_s_barrier();
            asm volatile("s_waitcnt lgkmcnt(0)" ::: "memory");
            __builtin_amdgcn_sched_barrier(0);
            __builtin_amdgcn_s_setprio(1);
#pragma unroll
            for (int fa = 0; fa < 2; ++fa)
#pragma unroll
                for (int fb = 0; fb < 2; ++fb)
#pragma unroll
                    for (int kh = 0; kh < 2; ++kh)
                        acc[qr * 2 + fa][qc * 2 + fb] = __builtin_amdgcn_mfma_f32_16x16x32_bf16(
                            af[fa][kh], bfr[fb][kh], acc[qr * 2 + fa][qc * 2 + fb], 0, 0, 0);
            __builtin_amdgcn_s_setprio(0);
            if (q == 3) {               // once per K-tile: next tile's loads must have landed
                if (t < 14)       asm volatile("s_waitcnt vmcnt(6)" ::: "memory");
                else if (t == 14) asm volatile("s_waitcnt vmcnt(0)" ::: "memory");
                __builtin_amdgcn_sched_barrier(0);
            }
            __builtin_amdgcn_s_barrier();
        }
    }

    // ---- fused epilogue: out = y * (acc + pb) + u  (two 128-row chunks) ----
    __syncthreads();
    const int b  = m0 >> 12;
    const int l0 = m0 & (SEQL - 1);
    float pbv[4];
#pragma unroll
    for (int nf = 0; nf < 4; ++nf)
        pbv[nf] = pb[n0 + wc * 64 + nf * 16 + (lane & 15)];

    for (int c = 0; c < 2; ++c) {
        __syncthreads();
        // stage ysc[l_local(128)][dn(128)] from bf16 y rows (B,D,L)
        {
            int dn = tid >> 2;          // 0..127
            int lq = tid & 3;           // uint4 group
            const uint4* uptr = (const uint4*)(yb + (((size_t)(b * DCH + n0 + dn)) << 12) + l0 + c * 128);
#pragma unroll
            for (int jj = 0; jj < 4; ++jj) {
                uint4 w4 = uptr[lq * 4 + jj];
                int lb = (lq * 4 + jj) * 8;
                ysc[lb+0][dn] = bflo(w4.x); ysc[lb+1][dn] = bfhi(w4.x);
                ysc[lb+2][dn] = bflo(w4.y); ysc[lb+3][dn] = bfhi(w4.y);
                ysc[lb+4][dn] = bflo(w4.z); ysc[lb+5][dn] = bfhi(w4.z);
                ysc[lb+6][dn] = bflo(w4.w); ysc[lb+7][dn] = bfhi(w4.w);
            }
        }
        __syncthreads();
        if ((wr >> 1) == c) {
#pragma unroll
            for (int mf = 0; mf < 4; ++mf)
#pragma unroll
                for (int i = 0; i < 4; ++i) {
                    int lrow = (wr & 1) * 64 + mf * 16 + (lane >> 4) * 4 + i;   // 0..127 in chunk
                    int m = m0 + c * 128 + lrow;
#pragma unroll
                    for (int nf = 0; nf < 4; ++nf) {
                        int nl = wc * 64 + nf * 16 + (lane & 15);
                        int n = n0 + nl;
                        float proj = acc[mf][nf][i] + pbv[nf];
                        float ures = __uint_as_float((unsigned)ub[(size_t)m * DCH + n] << 16);
                        out[(size_t)m * DCH + n] = ysc[lrow][nl] * proj + ures;
                    }
                }
        }
    }
}

// ---------------- gemm fallback (reg-staged): used when ws too small ----------------
__global__ __launch_bounds__(256, 3) void gemm_mfma_fb(
        const float* __restrict__ u, const float* __restrict__ pw,
        const float* __restrict__ pb, const unsigned short* __restrict__ yb,
        float* __restrict__ out) {
    __shared__ char lds_raw[34816];
    float (*ysc)[132] = (float(*)[132])lds_raw;
    const int tid  = threadIdx.x;
    const int lane = tid & 63;
    const int wid  = tid >> 6;
    const int wr   = wid >> 1;
    const int wc   = wid & 1;
    const int m0   = blockIdx.x * 128;
    const int n0   = blockIdx.y * 128;
    f32x4 acc[4][4] = {};
    float4 ra[4], rb[4];
    int s_row[4], s_f4[4];
#pragma unroll
    for (int j = 0; j < 4; ++j) {
        int idx = j * 256 + tid;
        s_row[j] = idx >> 3;
        s_f4[j]  = idx & 7;
    }
#define LOADT(kt)                                                                     \
    {                                                                                 \
        _Pragma("unroll")                                                             \
        for (int j = 0; j < 4; ++j) {                                                 \
            ra[j] = *(const float4*)&u [(size_t)(m0 + s_row[j]) * DCH + (kt) + s_f4[j] * 4]; \
            rb[j] = *(const float4*)&pw[(size_t)(n0 + s_row[j]) * DCH + (kt) + s_f4[j] * 4]; \
        }                                                                             \
    }
#define WRITET(base)                                                                  \
    {                                                                                 \
        _Pragma("unroll")                                                             \
        for (int j = 0; j < 4; ++j) {                                                 \
            int off = (base) + ((s_row[j] * 64 + s_f4[j] * 8) ^ ((s_row[j] & 3) << 4)); \
            uint2 pa, pbv2;                                                           \
            pa.x   = pack2bf(ra[j].x, ra[j].y);  pa.y   = pack2bf(ra[j].z, ra[j].w);  \
            pbv2.x = pack2bf(rb[j].x, rb[j].y);  pbv2.y = pack2bf(rb[j].z, rb[j].w);  \
            *(uint2*)(lds_raw + off)        = pa;                                     \
            *(uint2*)(lds_raw + off + 8192) = pbv2;                                   \
        }                                                                             \
    }
    LOADT(0);
    WRITET(0);
    LOADT(32);
    __syncthreads();
    for (int t = 0; t < 32; ++t) {
        const int cur = (t & 1) << 14;
        short8 af[4], bfr[4];
#pragma unroll
        for (int f = 0; f < 4; ++f) {
            int rowA = wr * 64 + f * 16 + (lane & 15);
            int rowB = wc * 64 + f * 16 + (lane & 15);
            int offA = cur + ((rowA * 64 + ((lane >> 4) * 16)) ^ ((rowA & 3) << 4));
            int offB = cur + 8192 + ((rowB * 64 + ((lane >> 4) * 16)) ^ ((rowB & 3) << 4));
            af[f]  = *(short8*)(lds_raw + offA);
            bfr[f] = *(short8*)(lds_raw + offB);
        }
        if (t < 31) WRITET(cur ^ 16384);
        if (t < 30) LOADT((t + 2) * 32);
#pragma unroll
        for (int mf = 0; mf < 4; ++mf)
#pragma unroll
            for (int nf = 0; nf < 4; ++nf)
                acc[mf][nf] = __builtin_amdgcn_mfma_f32_16x16x32_bf16(
                    af[mf], bfr[nf], acc[mf][nf], 0, 0, 0);
        __syncthreads();
    }
    const int b  = m0 >> 12;
    const int l0 = m0 & (SEQL - 1);
    float pbv[4];
#pragma unroll
    for (int nf = 0; nf < 4; ++nf)
        pbv[nf] = pb[n0 + wc * 64 + nf * 16 + (lane & 15)];
    for (int c = 0; c < 2; ++c) {
        __syncthreads();
#pragma unroll
        for (int j = 0; j < 4; ++j) {
            int idx = j * 256 + tid;
            int dn  = idx >> 3;
            int lg  = idx & 7;
            uint4 w4 = *(const uint4*)&yb[(((size_t)(b * DCH + n0 + dn)) << 12) + l0 + c * 64 + lg * 8];
            int lb = lg * 8;
            ysc[lb+0][dn] = bflo(w4.x); ysc[lb+1][dn] = bfhi(w4.x);
            ysc[lb+2][dn] = bflo(w4.y); ysc[lb+3][dn] = bfhi(w4.y);
            ysc[lb+4][dn] = bflo(w4.z); ysc[lb+5][dn] = bfhi(w4.z);
            ysc[lb+6][dn] = bflo(w4.w); ysc[lb+7][dn] = bfhi(w4.w);
        }
        __syncthreads();
        if (wr == c) {
#pragma unroll
            for (int mf = 0; mf < 4; ++mf)
#pragma unroll
                for (int i = 0; i < 4; ++i) {
                    int lrow = mf * 16 + (lane >> 4) * 4 + i;
                    int m = m0 + c * 64 + lrow;
#pragma unroll
                    for (int nf = 0; nf < 4; ++nf) {
                        int nl = wc * 64 + nf * 16 + (lane & 15);
                        int n = n0 + nl;
                        float proj = acc[mf][nf][i] + pbv[nf];
                        out[(size_t)m * DCH + n] = ysc[lrow][nl] * proj + u[(size_t)m * DCH + n];
                    }
                }
        }
    }
#undef LOADT
#undef WRITET
}

extern "C" void kernel_launch(void* const* d_in, const int* in_sizes, int n_in,
                              void* d_out, int out_size, void* d_ws, size_t ws_size,
                              hipStream_t stream) {
    const float* u  = (const float*)d_in[0];
    const float* z  = (const float*)d_in[1];
    const float* w1 = (const float*)d_in[2];
    const float* b1 = (const float*)d_in[3];
    const float* w2 = (const float*)d_in[4];
    const float* b2 = (const float*)d_in[5];
    const float* pw = (const float*)d_in[6];
    const float* pb = (const float*)d_in[7];
    float* out = (float*)d_out;

    float*    h    = (float*)d_ws;                        // 256 KB
    unsigned* utyb = (unsigned*)((char*)d_ws + 262144);   // 32 MB (bf16-pair rows; y bf16 in place)
    cf* kf = (cf*)d_out;                                  // 33.5 MB scratch (overwritten by gemm)

    const size_t ub_off  = 262144 + (size_t)BATCH * DCH * (SEQL / 2) * sizeof(unsigned);
    const size_t pwb_off = ub_off + (size_t)BATCH * SEQL * DCH * sizeof(unsigned short);
    const size_t tw_off  = pwb_off + (size_t)DCH * DCH * sizeof(unsigned short);
    const size_t need    = tw_off + 2 * 4096 * sizeof(cf);
    const bool   big     = ws_size >= need;

    cf* tw4 = big ? (cf*)((char*)d_ws + tw_off) : (cf*)((char*)d_out + (40u << 20));
    cf* tw8 = tw4 + 4096;
    unsigned short* ub  = big ? (unsigned short*)((char*)d_ws + ub_off)  : (unsigned short*)0;
    unsigned short* pwb = big ? (unsigned short*)((char*)d_ws + pwb_off) : (unsigned short*)0;

    twiddle_init<<<dim3(16), dim3(256), 0, stream>>>(tw4, tw8);
    mlp_kernel<<<dim3(16), dim3(256), 0, stream>>>(z, w1, b1, h);
    transpose_kernel<<<dim3(SEQL / 32, DCH / 32, BATCH), dim3(32, 8), 0, stream>>>(u, utyb, ub);
    if (big) pw2bf_kernel<<<dim3(512), dim3(256), 0, stream>>>(pw, pwb);
    filt_fft_kernel<<<dim3(DCH), dim3(256), 0, stream>>>(h, w2, b2, tw4, tw8, kf);
    conv_kernel<<<dim3(BATCH * DCH), dim3(256), 0, stream>>>(utyb, tw4, tw8, kf);
    if (big)
        gemm_mfma_v3<<<dim3(64, 8), dim3(512), 0, stream>>>(ub, pwb, pb, (const unsigned short*)utyb, out);
    else
        gemm_mfma_fb<<<dim3(128, 8), dim3(256), 0, stream>>>(u, pw, pb, (const unsigned short*)utyb, out);
}